// Round 1
// baseline (405.992 us; speedup 1.0000x reference)
//
#include <hip/hip_runtime.h>
#include <math.h>

#define NN 4096
#define DD 64
#define MAXNB 256
#define BI 16
#define TJ 128

__device__ __forceinline__ float wsum(float v){
#pragma unroll
  for(int o=1;o<64;o<<=1) v += __shfl_xor(v,o,64);
  return v;
}
__device__ __forceinline__ float wmax(float v){
#pragma unroll
  for(int o=1;o<64;o<<=1) v = fmaxf(v, __shfl_xor(v,o,64));
  return v;
}

// ---- reset max_en (graph replays must be deterministic; ws not re-poisoned) ----
__global__ void k_init(float* max_en){ *(int*)max_en = 0; }

// ---- per-node: sq = ||x||^2, en = ||x||, xn = x/max(en,1e-12), global max en ----
__global__ __launch_bounds__(256) void k_pre(const float* __restrict__ x,
                      float* __restrict__ xn, float* __restrict__ sq,
                      float* __restrict__ en, float* __restrict__ max_en){
  int node = blockIdx.x*4 + (threadIdx.x>>6);
  int lane = threadIdx.x & 63;
  float v = x[node*DD + lane];
  float s = wsum(v*v);
  float e = sqrtf(s);
  xn[node*DD+lane] = v / fmaxf(e, 1e-12f);
  if(lane==0){ sq[node]=s; en[node]=e; atomicMax((int*)max_en, __float_as_int(e)); }
}

// ---- column mean of x (for gdev) ----
__global__ __launch_bounds__(256) void k_colmean(const float* __restrict__ x,
                                                 float* __restrict__ mean){
  int d = blockIdx.x;
  float s = 0.f;
  for(int n = threadIdx.x; n < NN; n += 256) s += x[n*DD + d];
  __shared__ float red[256];
  red[threadIdx.x] = s; __syncthreads();
  for(int o=128;o>0;o>>=1){ if(threadIdx.x<o) red[threadIdx.x]+=red[threadIdx.x+o]; __syncthreads(); }
  if(threadIdx.x==0) mean[d] = red[0] * (1.0f/NN);
}

// ---- sparse per-node pass: energy, entropy, centrality, info flow, stability, curvature ----
__global__ __launch_bounds__(256) void k_sparse(
    const float* __restrict__ x, const float* __restrict__ A,
    const float* __restrict__ xn, const float* __restrict__ sq,
    const float* __restrict__ en, const float* __restrict__ max_en,
    float* __restrict__ o_te, float* __restrict__ o_ent, float* __restrict__ o_sc,
    float* __restrict__ o_if, float* __restrict__ o_st, float* __restrict__ o_cv)
{
  __shared__ float xi[DD], xni[DD];
  __shared__ int   nbr[MAXNB];
  __shared__ float Sval[MAXNB];
  __shared__ int   cnts[257];
  __shared__ float nbp[4][DD], ex2p[4][DD], sp[4][DD];
  __shared__ float ssqp[4];

  const int i = blockIdx.x, tid = threadIdx.x;
  const int wave = tid>>6, lane = tid&63;

  if(tid < DD){ xi[tid]=x[(size_t)i*DD+tid]; xni[tid]=xn[(size_t)i*DD+tid]; }

  // scan A row (float4), count + deterministic compaction
  const float4* A4 = (const float4*)(A + (size_t)i*NN);
  float4 av0 = A4[tid];
  float4 av1 = A4[tid+256];
  float4 av2 = A4[tid+512];
  float4 av3 = A4[tid+768];
  int c = 0;
  c += (av0.x>0.f)+(av0.y>0.f)+(av0.z>0.f)+(av0.w>0.f);
  c += (av1.x>0.f)+(av1.y>0.f)+(av1.z>0.f)+(av1.w>0.f);
  c += (av2.x>0.f)+(av2.y>0.f)+(av2.z>0.f)+(av2.w>0.f);
  c += (av3.x>0.f)+(av3.y>0.f)+(av3.z>0.f)+(av3.w>0.f);
  cnts[tid]=c; __syncthreads();
  if(tid==0){ int acc=0; for(int t=0;t<256;t++){ int cc=cnts[t]; cnts[t]=acc; acc+=cc; } cnts[256]=acc; }
  __syncthreads();
  int off = cnts[tid];
  const int deg = cnts[256];
  {
    float4 av[4] = {av0,av1,av2,av3};
#pragma unroll
    for(int k=0;k<4;k++){
      int f = tid + k*256;
      if(av[k].x>0.f){ if(off<MAXNB) nbr[off]=f*4+0; off++; }
      if(av[k].y>0.f){ if(off<MAXNB) nbr[off]=f*4+1; off++; }
      if(av[k].z>0.f){ if(off<MAXNB) nbr[off]=f*4+2; off++; }
      if(av[k].w>0.f){ if(off<MAXNB) nbr[off]=f*4+3; off++; }
    }
  }
  __syncthreads();

  const float xid = xi[lane], xnid = xni[lane];
  float nb_d=0.f, ex2_d=0.f, s_d=0.f, ssq=0.f;
  for(int s=wave; s<deg; s+=4){
    int j = nbr[s];
    float xj  = x[(size_t)j*DD + lane];
    float xnj = xn[(size_t)j*DD + lane];
    float cd = xj - xid;
    float c2 = cd*cd, dt = xnid*xnj;
#pragma unroll
    for(int o=1;o<64;o<<=1){ c2 += __shfl_xor(c2,o,64); dt += __shfl_xor(dt,o,64); }
    float nrm = sqrtf(fmaxf(c2, 1e-12f));
    float inv = 1.0f / fmaxf(nrm, 1e-8f);
    nb_d += xj; ex2_d += xj*xj; s_d += cd*inv; ssq += c2*inv*inv;
    if(lane==0) Sval[s] = dt;
  }
  nbp[wave][lane]=nb_d; ex2p[wave][lane]=ex2_d; sp[wave][lane]=s_d;
  if(lane==0) ssqp[wave]=ssq;
  __syncthreads();

  if(wave==0){
    const float degf = (float)deg;
    float nbv = nbp[0][lane]+nbp[1][lane]+nbp[2][lane]+nbp[3][lane];
    float ex2 = ex2p[0][lane]+ex2p[1][lane]+ex2p[2][lane]+ex2p[3][lane];
    float sv  = sp[0][lane]+sp[1][lane]+sp[2][lane]+sp[3][lane];

    float pot = wsum(xid*nbv);                    // x_i . nb (potential = -pot)
    float m1  = nbv/degf;
    float var = (ex2 - degf*m1*m1)/(degf-1.0f);
    float varm = wsum(var) * (1.0f/DD);
    float s2  = wsum(sv*sv);
    float ssqT = ssqp[0]+ssqp[1]+ssqp[2]+ssqp[3];

    // masked softmax over neighbor cosine sims
    float mx = -1e30f;
    for(int s=lane;s<deg;s+=64) mx = fmaxf(mx, Sval[s]);
    mx = wmax(mx);
    float se=0.f, ssm=0.f;
    for(int s=lane;s<deg;s+=64){ se += expf(Sval[s]-mx); ssm += Sval[s]; }
    se = wsum(se); ssm = wsum(ssm);
    const float ms = ssm/degf;
    float ent=0.f, fl=0.f;
    for(int s=lane;s<deg;s+=64){
      float p = expf(Sval[s]-mx)/se;
      ent -= p*logf(p + 1e-8f);
      float dv = Sval[s]-ms; fl += dv*dv;
    }
    ent = wsum(ent); fl = wsum(fl)/(degf-1.0f);

    if(lane==0){
      o_te[i]  = sq[i] - pot/(degf + 1e-8f);
      o_ent[i] = ent;
      o_sc[i]  = 0.5f*degf/(float)(NN-1) + 0.5f*en[i]/(*max_en);
      o_if[i]  = fl;
      o_st[i]  = 1.0f/(1.0f + varm);
      o_cv[i]  = 1.0f - (s2 - ssqT)/(degf*(degf-1.0f));
    }
  }
}

// ---- dense 5-NN pass -> equilibrium deviation ----
__global__ __launch_bounds__(256) void k_knn(
    const float* __restrict__ x, const float* __restrict__ sq,
    const float* __restrict__ mean, float* __restrict__ o_eq)
{
  __shared__ float4 tile[TJ*17];
  __shared__ float  sqt[TJ];
  __shared__ float  cdist[16*80];
  __shared__ int    cidx[16*80];
  __shared__ int    selj[16][5];

  const int tid = threadIdx.x, g = tid>>4, t = tid&15;
  const int i = blockIdx.x*BI + g;
  const float4* x4 = (const float4*)x;

  float4 xi[16];
#pragma unroll
  for(int r=0;r<16;r++) xi[r] = x4[(size_t)i*16 + r];
  const float sqi = sq[i];

  float bd[5]; int bj[5];
#pragma unroll
  for(int k=0;k<5;k++){ bd[k]=3.4e38f; bj[k]=0x7fffffff; }

  for(int jb=0; jb<NN; jb+=TJ){
    __syncthreads();
    for(int u=tid; u<TJ*16; u+=256){ int r=u>>4, cc=u&15; tile[r*17+cc] = x4[(size_t)(jb+r)*16 + cc]; }
    if(tid < TJ) sqt[tid] = sq[jb+tid];
    __syncthreads();
#pragma unroll
    for(int s=0;s<TJ/16;s++){
      const int jl = t + s*16;
      const int j = jb + jl;
      if(j == i) continue;
      const float4* tp = &tile[jl*17];
      float dot = 0.f;
#pragma unroll
      for(int r=0;r<16;r++){
        float4 b = tp[r];
        dot += xi[r].x*b.x + xi[r].y*b.y + xi[r].z*b.z + xi[r].w*b.w;
      }
      float d2 = sqi + sqt[jl] - 2.0f*dot;
      if(d2 < bd[4] || (d2==bd[4] && j<bj[4])){
        bd[4]=d2; bj[4]=j;
#pragma unroll
        for(int k=3;k>=0;k--){
          bool sw = (bd[k+1] < bd[k]) || (bd[k+1]==bd[k] && bj[k+1]<bj[k]);
          if(sw){
            float td=bd[k]; bd[k]=bd[k+1]; bd[k+1]=td;
            int tj=bj[k]; bj[k]=bj[k+1]; bj[k+1]=tj;
          }
        }
      }
    }
  }
#pragma unroll
  for(int k=0;k<5;k++){ cdist[(g*16+t)*5+k]=bd[k]; cidx[(g*16+t)*5+k]=bj[k]; }
  __syncthreads();

  if(t==0){
    const int base = g*80;
    for(int k=0;k<5;k++){
      float bestd=3.4e38f; int bestj=0x7fffffff; int bu=-1;
      for(int u=0;u<80;u++){
        float dv=cdist[base+u]; int jv=cidx[base+u];
        if(dv<bestd || (dv==bestd && jv<bestj)){ bestd=dv; bestj=jv; bu=u; }
      }
      selj[g][k]=bestj; cdist[base+bu]=3.4e38f; cidx[base+bu]=0x7fffffff;
    }
  }
  __syncthreads();

  // thread t owns float4 chunk t of the 64 dims
  float4 sm = make_float4(0,0,0,0);
#pragma unroll
  for(int k=0;k<5;k++){
    float4 v = x4[(size_t)selj[g][k]*16 + t];
    sm.x+=v.x; sm.y+=v.y; sm.z+=v.z; sm.w+=v.w;
  }
  const float inv5 = 1.0f/5.0f;
  float4 xiv = x4[(size_t)i*16 + t];
  float4 mn4 = ((const float4*)mean)[t];
  float lx=xiv.x-sm.x*inv5, ly=xiv.y-sm.y*inv5, lz=xiv.z-sm.z*inv5, lw=xiv.w-sm.w*inv5;
  float pl = lx*lx+ly*ly+lz*lz+lw*lw;
  float gx=xiv.x-mn4.x, gy=xiv.y-mn4.y, gz=xiv.z-mn4.z, gw=xiv.w-mn4.w;
  float pg = gx*gx+gy*gy+gz*gz+gw*gw;
#pragma unroll
  for(int o=1;o<16;o<<=1){ pl += __shfl_xor(pl,o,64); pg += __shfl_xor(pg,o,64); }
  if(t==0) o_eq[i] = 0.6f*sqrtf(pg) + 0.4f*sqrtf(pl);
}

extern "C" void kernel_launch(void* const* d_in, const int* in_sizes, int n_in,
                              void* d_out, int out_size, void* d_ws, size_t ws_size,
                              hipStream_t stream) {
  const float* x = (const float*)d_in[0];
  const float* A = (const float*)d_in[1];
  float* out = (float*)d_out;
  float* ws  = (float*)d_ws;
  float* xn     = ws;                 // N*D
  float* sq     = xn + NN*DD;         // N
  float* en     = sq + NN;            // N
  float* mean   = en + NN;            // D
  float* max_en = mean + DD;          // 1

  k_init<<<1, 1, 0, stream>>>(max_en);
  k_pre<<<NN/4, 256, 0, stream>>>(x, xn, sq, en, max_en);
  k_colmean<<<DD, 256, 0, stream>>>(x, mean);
  k_sparse<<<NN, 256, 0, stream>>>(x, A, xn, sq, en, max_en,
                                   out, out+NN, out+3*NN, out+4*NN, out+5*NN, out+6*NN);
  k_knn<<<NN/BI, 256, 0, stream>>>(x, sq, mean, out+2*NN);
}

// Round 2
// 253.915 us; speedup vs baseline: 1.5989x; 1.5989x over previous
//
#include <hip/hip_runtime.h>
#include <math.h>

#define NN 4096
#define DD 64
#define MAXNB 256
#define TJ 128

__device__ __forceinline__ float wsum(float v){
#pragma unroll
  for(int o=1;o<64;o<<=1) v += __shfl_xor(v,o,64);
  return v;
}
__device__ __forceinline__ float wmax(float v){
#pragma unroll
  for(int o=1;o<64;o<<=1) v = fmaxf(v, __shfl_xor(v,o,64));
  return v;
}

// ---- reset max_en (graph replays must be deterministic; ws not re-poisoned) ----
__global__ void k_init(float* max_en){ *(int*)max_en = 0; }

// ---- per-node: sq = ||x||^2, en = ||x||, xn = x/max(en,1e-12), global max en ----
__global__ __launch_bounds__(256) void k_pre(const float* __restrict__ x,
                      float* __restrict__ xn, float* __restrict__ sq,
                      float* __restrict__ en, float* __restrict__ max_en){
  int node = blockIdx.x*4 + (threadIdx.x>>6);
  int lane = threadIdx.x & 63;
  float v = x[node*DD + lane];
  float s = wsum(v*v);
  float e = sqrtf(s);
  xn[node*DD+lane] = v / fmaxf(e, 1e-12f);
  if(lane==0){ sq[node]=s; en[node]=e; atomicMax((int*)max_en, __float_as_int(e)); }
}

// ---- column mean of x (for gdev) ----
__global__ __launch_bounds__(256) void k_colmean(const float* __restrict__ x,
                                                 float* __restrict__ mean){
  int d = blockIdx.x;
  float s = 0.f;
  for(int n = threadIdx.x; n < NN; n += 256) s += x[n*DD + d];
  __shared__ float red[256];
  red[threadIdx.x] = s; __syncthreads();
  for(int o=128;o>0;o>>=1){ if(threadIdx.x<o) red[threadIdx.x]+=red[threadIdx.x+o]; __syncthreads(); }
  if(threadIdx.x==0) mean[d] = red[0] * (1.0f/NN);
}

// ---- sparse per-node pass: energy, entropy, centrality, info flow, stability, curvature ----
__global__ __launch_bounds__(256) void k_sparse(
    const float* __restrict__ x, const float* __restrict__ A,
    const float* __restrict__ xn, const float* __restrict__ sq,
    const float* __restrict__ en, const float* __restrict__ max_en,
    float* __restrict__ o_te, float* __restrict__ o_ent, float* __restrict__ o_sc,
    float* __restrict__ o_if, float* __restrict__ o_st, float* __restrict__ o_cv)
{
  __shared__ float xi[DD], xni[DD];
  __shared__ int   nbr[MAXNB];
  __shared__ float Sval[MAXNB];
  __shared__ int   wtot[4];
  __shared__ float nbp[4][DD], ex2p[4][DD], sp[4][DD];
  __shared__ float ssqp[4];

  const int i = blockIdx.x, tid = threadIdx.x;
  const int wave = tid>>6, lane = tid&63;

  if(tid < DD){ xi[tid]=x[(size_t)i*DD+tid]; xni[tid]=xn[(size_t)i*DD+tid]; }

  // scan A row (float4), count + deterministic compaction (wave scan)
  const float4* A4 = (const float4*)(A + (size_t)i*NN);
  float4 av0 = A4[tid];
  float4 av1 = A4[tid+256];
  float4 av2 = A4[tid+512];
  float4 av3 = A4[tid+768];
  int c = 0;
  c += (av0.x>0.f)+(av0.y>0.f)+(av0.z>0.f)+(av0.w>0.f);
  c += (av1.x>0.f)+(av1.y>0.f)+(av1.z>0.f)+(av1.w>0.f);
  c += (av2.x>0.f)+(av2.y>0.f)+(av2.z>0.f)+(av2.w>0.f);
  c += (av3.x>0.f)+(av3.y>0.f)+(av3.z>0.f)+(av3.w>0.f);
  int sc = c;
#pragma unroll
  for(int o=1;o<64;o<<=1){ int v=__shfl_up(sc,o,64); if(lane>=o) sc+=v; }
  if(lane==63) wtot[wave]=sc;
  __syncthreads();
  int base = 0;
#pragma unroll
  for(int ww=0;ww<4;ww++) if(ww<wave) base += wtot[ww];
  int off = base + sc - c;
  const int deg = wtot[0]+wtot[1]+wtot[2]+wtot[3];
  {
    float4 av[4] = {av0,av1,av2,av3};
#pragma unroll
    for(int k=0;k<4;k++){
      int f = tid + k*256;
      if(av[k].x>0.f){ if(off<MAXNB) nbr[off]=f*4+0; off++; }
      if(av[k].y>0.f){ if(off<MAXNB) nbr[off]=f*4+1; off++; }
      if(av[k].z>0.f){ if(off<MAXNB) nbr[off]=f*4+2; off++; }
      if(av[k].w>0.f){ if(off<MAXNB) nbr[off]=f*4+3; off++; }
    }
  }
  __syncthreads();

  const float xid = xi[lane], xnid = xni[lane];
  float nb_d=0.f, ex2_d=0.f, s_d=0.f, ssq=0.f;
  for(int s=wave; s<deg; s+=4){
    int j = nbr[s];
    float xj  = x[(size_t)j*DD + lane];
    float xnj = xn[(size_t)j*DD + lane];
    float cd = xj - xid;
    float c2 = cd*cd, dt = xnid*xnj;
#pragma unroll
    for(int o=1;o<64;o<<=1){ c2 += __shfl_xor(c2,o,64); dt += __shfl_xor(dt,o,64); }
    float nrm = sqrtf(fmaxf(c2, 1e-12f));
    float inv = 1.0f / fmaxf(nrm, 1e-8f);
    nb_d += xj; ex2_d += xj*xj; s_d += cd*inv; ssq += c2*inv*inv;
    if(lane==0) Sval[s] = dt;
  }
  nbp[wave][lane]=nb_d; ex2p[wave][lane]=ex2_d; sp[wave][lane]=s_d;
  if(lane==0) ssqp[wave]=ssq;
  __syncthreads();

  if(wave==0){
    const float degf = (float)deg;
    float nbv = nbp[0][lane]+nbp[1][lane]+nbp[2][lane]+nbp[3][lane];
    float ex2 = ex2p[0][lane]+ex2p[1][lane]+ex2p[2][lane]+ex2p[3][lane];
    float sv  = sp[0][lane]+sp[1][lane]+sp[2][lane]+sp[3][lane];

    float pot = wsum(xid*nbv);                    // x_i . nb (potential = -pot)
    float m1  = nbv/degf;
    float var = (ex2 - degf*m1*m1)/(degf-1.0f);
    float varm = wsum(var) * (1.0f/DD);
    float s2  = wsum(sv*sv);
    float ssqT = ssqp[0]+ssqp[1]+ssqp[2]+ssqp[3];

    // masked softmax over neighbor cosine sims
    float mx = -1e30f;
    for(int s=lane;s<deg;s+=64) mx = fmaxf(mx, Sval[s]);
    mx = wmax(mx);
    float se=0.f, ssm=0.f;
    for(int s=lane;s<deg;s+=64){ se += expf(Sval[s]-mx); ssm += Sval[s]; }
    se = wsum(se); ssm = wsum(ssm);
    const float ms = ssm/degf;
    float ent=0.f, fl=0.f;
    for(int s=lane;s<deg;s+=64){
      float p = expf(Sval[s]-mx)/se;
      ent -= p*logf(p + 1e-8f);
      float dv = Sval[s]-ms; fl += dv*dv;
    }
    ent = wsum(ent); fl = wsum(fl)/(degf-1.0f);

    if(lane==0){
      o_te[i]  = sq[i] - pot/(degf + 1e-8f);
      o_ent[i] = ent;
      o_sc[i]  = 0.5f*degf/(float)(NN-1) + 0.5f*en[i]/(*max_en);
      o_if[i]  = fl;
      o_st[i]  = 1.0f/(1.0f + varm);
      o_cv[i]  = 1.0f - (s2 - ssqT)/(degf*(degf-1.0f));
    }
  }
}

// ---- dense 5-NN pass -> equilibrium deviation ----
__device__ __forceinline__ void ins5(float d2, int j, float bd[5], int bj[5]){
  if(d2 < bd[4] || (d2==bd[4] && j<bj[4])){
    bd[4]=d2; bj[4]=j;
#pragma unroll
    for(int k=3;k>=0;k--){
      bool sw = (bd[k+1]<bd[k]) || (bd[k+1]==bd[k] && bj[k+1]<bj[k]);
      if(sw){ float td=bd[k]; bd[k]=bd[k+1]; bd[k+1]=td;
              int tj=bj[k]; bj[k]=bj[k+1]; bj[k+1]=tj; }
    }
  }
}

__device__ __forceinline__ void knn_out(float bd[5], int bj[5],
    const float* __restrict__ x, const float* __restrict__ mean,
    int i, int t, float* __restrict__ o_eq)
{
  int sel[5];
#pragma unroll
  for(int k=0;k<5;k++){
    float d = bd[0]; int j = bj[0];
#pragma unroll
    for(int o=1;o<64;o<<=1){
      float d2 = __shfl_xor(d,o,64); int j2 = __shfl_xor(j,o,64);
      if(d2<d || (d2==d && j2<j)){ d=d2; j=j2; }
    }
    sel[k]=j;
    if(bj[0]==j){
      bd[0]=bd[1];bj[0]=bj[1]; bd[1]=bd[2];bj[1]=bj[2];
      bd[2]=bd[3];bj[2]=bj[3]; bd[3]=bd[4];bj[3]=bj[4];
      bd[4]=3.4e38f; bj[4]=0x7fffffff;
    }
  }
  float sm = 0.f;
#pragma unroll
  for(int k=0;k<5;k++) sm += x[(size_t)sel[k]*DD + t];
  float xiv = x[(size_t)i*DD + t];
  float lv = xiv - sm*0.2f;
  float gv = xiv - mean[t];
  float pl = lv*lv, pg = gv*gv;
#pragma unroll
  for(int o=1;o<64;o<<=1){ pl += __shfl_xor(pl,o,64); pg += __shfl_xor(pg,o,64); }
  if(t==0) o_eq[i] = 0.6f*sqrtf(pg) + 0.4f*sqrtf(pl);
}

__global__ __launch_bounds__(256, 2) void k_knn(
    const float* __restrict__ x, const float* __restrict__ sq,
    const float* __restrict__ mean, float* __restrict__ o_eq)
{
  __shared__ float4 tile[TJ*17];
  __shared__ float  sqt[TJ];
  const int tid = threadIdx.x, w = tid>>6, t = tid&63;
  const int ia = blockIdx.x*8 + w*2;
  const int ib = ia + 1;
  const float4* x4 = (const float4*)x;

  float4 xa[16], xb[16];
#pragma unroll
  for(int r=0;r<16;r++){ xa[r]=x4[(size_t)ia*16+r]; xb[r]=x4[(size_t)ib*16+r]; }
  const float sqa = sq[ia], sqb = sq[ib];

  float bda[5], bdb[5]; int bja[5], bjb[5];
#pragma unroll
  for(int k=0;k<5;k++){ bda[k]=3.4e38f; bja[k]=0x7fffffff; bdb[k]=3.4e38f; bjb[k]=0x7fffffff; }

  for(int jb=0; jb<NN; jb+=TJ){
    __syncthreads();
    for(int u=tid; u<TJ*16; u+=256){ int r=u>>4, cc=u&15; tile[r*17+cc] = x4[(size_t)(jb+r)*16 + cc]; }
    if(tid < TJ) sqt[tid] = sq[jb+tid];
    __syncthreads();
#pragma unroll
    for(int s=0;s<2;s++){
      const int jl = t + s*64;
      const int j = jb + jl;
      const float4* tp = &tile[jl*17];
      float da=0.f, db=0.f;
#pragma unroll
      for(int r=0;r<16;r++){
        float4 bv = tp[r];
        da += xa[r].x*bv.x + xa[r].y*bv.y + xa[r].z*bv.z + xa[r].w*bv.w;
        db += xb[r].x*bv.x + xb[r].y*bv.y + xb[r].z*bv.z + xb[r].w*bv.w;
      }
      float d2a = sqa + sqt[jl] - 2.0f*da;
      float d2b = sqb + sqt[jl] - 2.0f*db;
      if(j != ia) ins5(d2a, j, bda, bja);
      if(j != ib) ins5(d2b, j, bdb, bjb);
    }
  }
  knn_out(bda, bja, x, mean, ia, t, o_eq);
  knn_out(bdb, bjb, x, mean, ib, t, o_eq);
}

extern "C" void kernel_launch(void* const* d_in, const int* in_sizes, int n_in,
                              void* d_out, int out_size, void* d_ws, size_t ws_size,
                              hipStream_t stream) {
  const float* x = (const float*)d_in[0];
  const float* A = (const float*)d_in[1];
  float* out = (float*)d_out;
  float* ws  = (float*)d_ws;
  float* xn     = ws;                 // N*D
  float* sq     = xn + NN*DD;         // N
  float* en     = sq + NN;            // N
  float* mean   = en + NN;            // D
  float* max_en = mean + DD;          // 1

  k_init<<<1, 1, 0, stream>>>(max_en);
  k_pre<<<NN/4, 256, 0, stream>>>(x, xn, sq, en, max_en);
  k_colmean<<<DD, 256, 0, stream>>>(x, mean);
  k_sparse<<<NN, 256, 0, stream>>>(x, A, xn, sq, en, max_en,
                                   out, out+NN, out+3*NN, out+4*NN, out+5*NN, out+6*NN);
  k_knn<<<NN/8, 256, 0, stream>>>(x, sq, mean, out+2*NN);
}

// Round 3
// 241.797 us; speedup vs baseline: 1.6791x; 1.0501x over previous
//
#include <hip/hip_runtime.h>
#include <math.h>

#define NN 4096
#define DD 64
#define MAXNB 256

__device__ __forceinline__ float wsum(float v){
#pragma unroll
  for(int o=1;o<64;o<<=1) v += __shfl_xor(v,o,64);
  return v;
}
__device__ __forceinline__ float wmax(float v){
#pragma unroll
  for(int o=1;o<64;o<<=1) v = fmaxf(v, __shfl_xor(v,o,64));
  return v;
}

// ---- reset max_en (graph replays must be deterministic; ws not re-poisoned) ----
__global__ void k_init(float* max_en){ *(int*)max_en = 0; }

// ---- per-node: sq = ||x||^2, en = ||x||, xn = x/max(en,1e-12), global max en ----
__global__ __launch_bounds__(256) void k_pre(const float* __restrict__ x,
                      float* __restrict__ xn, float* __restrict__ sq,
                      float* __restrict__ en, float* __restrict__ max_en){
  int node = blockIdx.x*4 + (threadIdx.x>>6);
  int lane = threadIdx.x & 63;
  float v = x[node*DD + lane];
  float s = wsum(v*v);
  float e = sqrtf(s);
  xn[node*DD+lane] = v / fmaxf(e, 1e-12f);
  if(lane==0){ sq[node]=s; en[node]=e; atomicMax((int*)max_en, __float_as_int(e)); }
}

// ---- column mean of x (for gdev) ----
__global__ __launch_bounds__(256) void k_colmean(const float* __restrict__ x,
                                                 float* __restrict__ mean){
  int d = blockIdx.x;
  float s = 0.f;
  for(int n = threadIdx.x; n < NN; n += 256) s += x[n*DD + d];
  __shared__ float red[256];
  red[threadIdx.x] = s; __syncthreads();
  for(int o=128;o>0;o>>=1){ if(threadIdx.x<o) red[threadIdx.x]+=red[threadIdx.x+o]; __syncthreads(); }
  if(threadIdx.x==0) mean[d] = red[0] * (1.0f/NN);
}

// ---- sparse per-node pass: energy, entropy, centrality, info flow, stability, curvature ----
__global__ __launch_bounds__(256) void k_sparse(
    const float* __restrict__ x, const float* __restrict__ A,
    const float* __restrict__ xn, const float* __restrict__ sq,
    const float* __restrict__ en, const float* __restrict__ max_en,
    float* __restrict__ o_te, float* __restrict__ o_ent, float* __restrict__ o_sc,
    float* __restrict__ o_if, float* __restrict__ o_st, float* __restrict__ o_cv)
{
  __shared__ float xi[DD], xni[DD];
  __shared__ int   nbr[MAXNB];
  __shared__ float Sval[MAXNB];
  __shared__ int   wtot[4];
  __shared__ float nbp[4][DD], ex2p[4][DD], sp[4][DD];
  __shared__ float ssqp[4];

  const int i = blockIdx.x, tid = threadIdx.x;
  const int wave = tid>>6, lane = tid&63;

  if(tid < DD){ xi[tid]=x[(size_t)i*DD+tid]; xni[tid]=xn[(size_t)i*DD+tid]; }

  // scan A row (float4), count + deterministic compaction (wave scan)
  const float4* A4 = (const float4*)(A + (size_t)i*NN);
  float4 av0 = A4[tid];
  float4 av1 = A4[tid+256];
  float4 av2 = A4[tid+512];
  float4 av3 = A4[tid+768];
  int c = 0;
  c += (av0.x>0.f)+(av0.y>0.f)+(av0.z>0.f)+(av0.w>0.f);
  c += (av1.x>0.f)+(av1.y>0.f)+(av1.z>0.f)+(av1.w>0.f);
  c += (av2.x>0.f)+(av2.y>0.f)+(av2.z>0.f)+(av2.w>0.f);
  c += (av3.x>0.f)+(av3.y>0.f)+(av3.z>0.f)+(av3.w>0.f);
  int sc = c;
#pragma unroll
  for(int o=1;o<64;o<<=1){ int v=__shfl_up(sc,o,64); if(lane>=o) sc+=v; }
  if(lane==63) wtot[wave]=sc;
  __syncthreads();
  int base = 0;
#pragma unroll
  for(int ww=0;ww<4;ww++) if(ww<wave) base += wtot[ww];
  int off = base + sc - c;
  const int deg = wtot[0]+wtot[1]+wtot[2]+wtot[3];
  {
    float4 av[4] = {av0,av1,av2,av3};
#pragma unroll
    for(int k=0;k<4;k++){
      int f = tid + k*256;
      if(av[k].x>0.f){ if(off<MAXNB) nbr[off]=f*4+0; off++; }
      if(av[k].y>0.f){ if(off<MAXNB) nbr[off]=f*4+1; off++; }
      if(av[k].z>0.f){ if(off<MAXNB) nbr[off]=f*4+2; off++; }
      if(av[k].w>0.f){ if(off<MAXNB) nbr[off]=f*4+3; off++; }
    }
  }
  __syncthreads();

  const float xid = xi[lane], xnid = xni[lane];
  float nb_d=0.f, ex2_d=0.f, s_d=0.f, ssq=0.f;
  for(int s=wave; s<deg; s+=4){
    int j = nbr[s];
    float xj  = x[(size_t)j*DD + lane];
    float xnj = xn[(size_t)j*DD + lane];
    float cd = xj - xid;
    float c2 = cd*cd, dt = xnid*xnj;
#pragma unroll
    for(int o=1;o<64;o<<=1){ c2 += __shfl_xor(c2,o,64); dt += __shfl_xor(dt,o,64); }
    float nrm = sqrtf(fmaxf(c2, 1e-12f));
    float inv = 1.0f / fmaxf(nrm, 1e-8f);
    nb_d += xj; ex2_d += xj*xj; s_d += cd*inv; ssq += c2*inv*inv;
    if(lane==0) Sval[s] = dt;
  }
  nbp[wave][lane]=nb_d; ex2p[wave][lane]=ex2_d; sp[wave][lane]=s_d;
  if(lane==0) ssqp[wave]=ssq;
  __syncthreads();

  if(wave==0){
    const float degf = (float)deg;
    float nbv = nbp[0][lane]+nbp[1][lane]+nbp[2][lane]+nbp[3][lane];
    float ex2 = ex2p[0][lane]+ex2p[1][lane]+ex2p[2][lane]+ex2p[3][lane];
    float sv  = sp[0][lane]+sp[1][lane]+sp[2][lane]+sp[3][lane];

    float pot = wsum(xid*nbv);                    // x_i . nb (potential = -pot)
    float m1  = nbv/degf;
    float var = (ex2 - degf*m1*m1)/(degf-1.0f);
    float varm = wsum(var) * (1.0f/DD);
    float s2  = wsum(sv*sv);
    float ssqT = ssqp[0]+ssqp[1]+ssqp[2]+ssqp[3];

    // masked softmax over neighbor cosine sims
    float mx = -1e30f;
    for(int s=lane;s<deg;s+=64) mx = fmaxf(mx, Sval[s]);
    mx = wmax(mx);
    float se=0.f, ssm=0.f;
    for(int s=lane;s<deg;s+=64){ se += expf(Sval[s]-mx); ssm += Sval[s]; }
    se = wsum(se); ssm = wsum(ssm);
    const float ms = ssm/degf;
    float ent=0.f, fl=0.f;
    for(int s=lane;s<deg;s+=64){
      float p = expf(Sval[s]-mx)/se;
      ent -= p*logf(p + 1e-8f);
      float dv = Sval[s]-ms; fl += dv*dv;
    }
    ent = wsum(ent); fl = wsum(fl)/(degf-1.0f);

    if(lane==0){
      o_te[i]  = sq[i] - pot/(degf + 1e-8f);
      o_ent[i] = ent;
      o_sc[i]  = 0.5f*degf/(float)(NN-1) + 0.5f*en[i]/(*max_en);
      o_if[i]  = fl;
      o_st[i]  = 1.0f/(1.0f + varm);
      o_cv[i]  = 1.0f - (s2 - ssqT)/(degf*(degf-1.0f));
    }
  }
}

// ---- dense 5-NN pass -> equilibrium deviation ----
__device__ __forceinline__ void ins5(float d2, int j, float bd[5], int bj[5]){
  if(d2 < bd[4] || (d2==bd[4] && j<bj[4])){
    bd[4]=d2; bj[4]=j;
#pragma unroll
    for(int k=3;k>=0;k--){
      bool sw = (bd[k+1]<bd[k]) || (bd[k+1]==bd[k] && bj[k+1]<bj[k]);
      if(sw){ float td=bd[k]; bd[k]=bd[k+1]; bd[k+1]=td;
              int tj=bj[k]; bj[k]=bj[k+1]; bj[k+1]=tj; }
    }
  }
}

__device__ __forceinline__ float dot4(float4 a, float4 b){
  return a.x*b.x + a.y*b.y + a.z*b.z + a.w*b.w;
}

// block = 4 waves, owns 4 rows (rowbase=blockIdx*4). Wave w scans j-quarter w.
// lane = dg*16+jg: dg-th 16-dim chunk of all 4 rows in regs; per iter lane
// loads chunk of row j=jq*1024+it*16+jg from L2, 64 FMA, xor-reduce over dg.
__global__ __launch_bounds__(256, 4) void k_knn(
    const float* __restrict__ x, const float* __restrict__ sq,
    const float* __restrict__ mean, float* __restrict__ o_eq)
{
  __shared__ float cd[4][4][5];
  __shared__ int   cj[4][4][5];

  const int tid = threadIdx.x, w = tid>>6, lane = tid&63;
  const int dg = lane>>4, jg = lane&15;
  const int rowbase = blockIdx.x*4;
  const float4* x4 = (const float4*)x;

  float4 xr0[4], xr1[4], xr2[4], xr3[4];
#pragma unroll
  for(int c=0;c<4;c++){
    xr0[c] = x4[(size_t)(rowbase+0)*16 + dg*4 + c];
    xr1[c] = x4[(size_t)(rowbase+1)*16 + dg*4 + c];
    xr2[c] = x4[(size_t)(rowbase+2)*16 + dg*4 + c];
    xr3[c] = x4[(size_t)(rowbase+3)*16 + dg*4 + c];
  }
  const int myrow = rowbase + dg;
  const float sqown = sq[myrow];

  float bd[5]; int bj[5];
#pragma unroll
  for(int k=0;k<5;k++){ bd[k]=3.4e38f; bj[k]=0x7fffffff; }

  const int jstart = w*1024;
  for(int it=0; it<64; ++it){
    const int j = jstart + it*16 + jg;
    const float4* jp = x4 + (size_t)j*16 + dg*4;
    float4 a = jp[0], b = jp[1], cc = jp[2], dd = jp[3];
    float sqj = sq[j];
    float d0 = dot4(xr0[0],a)+dot4(xr0[1],b)+dot4(xr0[2],cc)+dot4(xr0[3],dd);
    float d1 = dot4(xr1[0],a)+dot4(xr1[1],b)+dot4(xr1[2],cc)+dot4(xr1[3],dd);
    float d2 = dot4(xr2[0],a)+dot4(xr2[1],b)+dot4(xr2[2],cc)+dot4(xr2[3],dd);
    float d3 = dot4(xr3[0],a)+dot4(xr3[1],b)+dot4(xr3[2],cc)+dot4(xr3[3],dd);
    // reduce partial dots over the 4 dg groups (lane bits 4,5)
#pragma unroll
    for(int o=16;o<64;o<<=1){
      d0 += __shfl_xor(d0,o,64); d1 += __shfl_xor(d1,o,64);
      d2 += __shfl_xor(d2,o,64); d3 += __shfl_xor(d3,o,64);
    }
    float dot = dg==0 ? d0 : dg==1 ? d1 : dg==2 ? d2 : d3;
    float dist2 = sqown + sqj - 2.0f*dot;
    if(j != myrow) ins5(dist2, j, bd, bj);
  }

  // intra-wave merge: per row r, lanes with dg==r hold candidates; 5 rounds argmin(lex)
#pragma unroll
  for(int r=0;r<4;r++){
#pragma unroll
    for(int k=0;k<5;k++){
      float d = (dg==r) ? bd[0] : 3.4e38f;
      int   j = (dg==r) ? bj[0] : 0x7fffffff;
      float dm = d; int jm = j;
#pragma unroll
      for(int o=1;o<64;o<<=1){
        float d2s = __shfl_xor(dm,o,64); int j2s = __shfl_xor(jm,o,64);
        if(d2s<dm || (d2s==dm && j2s<jm)){ dm=d2s; jm=j2s; }
      }
      if(lane==0){ cd[w][r][k]=dm; cj[w][r][k]=jm; }
      if(dg==r && bj[0]==jm && bd[0]==dm){
        bd[0]=bd[1];bj[0]=bj[1]; bd[1]=bd[2];bj[1]=bj[2];
        bd[2]=bd[3];bj[2]=bj[3]; bd[3]=bd[4];bj[3]=bj[4];
        bd[4]=3.4e38f; bj[4]=0x7fffffff;
      }
    }
  }
  __syncthreads();

  // final merge (wave 0): 4 quarters x 5 cands per row -> top-5 -> epilogue
  if(w==0){
#pragma unroll
    for(int r=0;r<4;r++){
      float d = 3.4e38f; int j = 0x7fffffff;
      if(lane < 32 && (lane&7) < 5){ d = cd[lane>>3][r][lane&7]; j = cj[lane>>3][r][lane&7]; }
      int sel[5];
#pragma unroll
      for(int k=0;k<5;k++){
        float dm = d; int jm = j;
#pragma unroll
        for(int o=1;o<64;o<<=1){
          float d2s = __shfl_xor(dm,o,64); int j2s = __shfl_xor(jm,o,64);
          if(d2s<dm || (d2s==dm && j2s<jm)){ dm=d2s; jm=j2s; }
        }
        sel[k]=jm;
        if(j==jm){ d=3.4e38f; j=0x7fffffff; }
      }
      float smv = 0.f;
#pragma unroll
      for(int k=0;k<5;k++) smv += x[(size_t)sel[k]*DD + lane];
      float xiv = x[(size_t)(rowbase+r)*DD + lane];
      float lv = xiv - smv*0.2f;
      float gv = xiv - mean[lane];
      float pl = wsum(lv*lv), pg = wsum(gv*gv);
      if(lane==0) o_eq[rowbase+r] = 0.6f*sqrtf(pg) + 0.4f*sqrtf(pl);
    }
  }
}

extern "C" void kernel_launch(void* const* d_in, const int* in_sizes, int n_in,
                              void* d_out, int out_size, void* d_ws, size_t ws_size,
                              hipStream_t stream) {
  const float* x = (const float*)d_in[0];
  const float* A = (const float*)d_in[1];
  float* out = (float*)d_out;
  float* ws  = (float*)d_ws;
  float* xn     = ws;                 // N*D
  float* sq     = xn + NN*DD;         // N
  float* en     = sq + NN;            // N
  float* mean   = en + NN;            // D
  float* max_en = mean + DD;          // 1

  k_init<<<1, 1, 0, stream>>>(max_en);
  k_pre<<<NN/4, 256, 0, stream>>>(x, xn, sq, en, max_en);
  k_colmean<<<DD, 256, 0, stream>>>(x, mean);
  k_sparse<<<NN, 256, 0, stream>>>(x, A, xn, sq, en, max_en,
                                   out, out+NN, out+3*NN, out+4*NN, out+5*NN, out+6*NN);
  k_knn<<<NN/4, 256, 0, stream>>>(x, sq, mean, out+2*NN);
}

// Round 4
// 179.800 us; speedup vs baseline: 2.2580x; 1.3448x over previous
//
#include <hip/hip_runtime.h>
#include <math.h>

#define NN 4096
#define DD 64
#define MAXNB 256
#define GI 128            // i-rows per block (phase A)
#define GJ 256            // j-cols per block
#define GC 128            // j chunk staged in LDS
#define NJB (NN/GJ)       // 16 j-blocks

__device__ __forceinline__ float wsum(float v){
#pragma unroll
  for(int o=1;o<64;o<<=1) v += __shfl_xor(v,o,64);
  return v;
}
__device__ __forceinline__ float wmax(float v){
#pragma unroll
  for(int o=1;o<64;o<<=1) v = fmaxf(v, __shfl_xor(v,o,64));
  return v;
}

// ---- reset max_en (graph replays must be deterministic; ws not re-poisoned) ----
__global__ void k_init(float* max_en){ *(int*)max_en = 0; }

// ---- per-node: sq = ||x||^2, en = ||x||, xn = x/max(en,1e-12), global max en ----
__global__ __launch_bounds__(256) void k_pre(const float* __restrict__ x,
                      float* __restrict__ xn, float* __restrict__ sq,
                      float* __restrict__ en, float* __restrict__ max_en){
  int node = blockIdx.x*4 + (threadIdx.x>>6);
  int lane = threadIdx.x & 63;
  float v = x[node*DD + lane];
  float s = wsum(v*v);
  float e = sqrtf(s);
  xn[node*DD+lane] = v / fmaxf(e, 1e-12f);
  if(lane==0){ sq[node]=s; en[node]=e; atomicMax((int*)max_en, __float_as_int(e)); }
}

// ---- column mean of x (for gdev) ----
__global__ __launch_bounds__(256) void k_colmean(const float* __restrict__ x,
                                                 float* __restrict__ mean){
  int d = blockIdx.x;
  float s = 0.f;
  for(int n = threadIdx.x; n < NN; n += 256) s += x[n*DD + d];
  __shared__ float red[256];
  red[threadIdx.x] = s; __syncthreads();
  for(int o=128;o>0;o>>=1){ if(threadIdx.x<o) red[threadIdx.x]+=red[threadIdx.x+o]; __syncthreads(); }
  if(threadIdx.x==0) mean[d] = red[0] * (1.0f/NN);
}

// ---- sparse per-node pass (unchanged) ----
__global__ __launch_bounds__(256) void k_sparse(
    const float* __restrict__ x, const float* __restrict__ A,
    const float* __restrict__ xn, const float* __restrict__ sq,
    const float* __restrict__ en, const float* __restrict__ max_en,
    float* __restrict__ o_te, float* __restrict__ o_ent, float* __restrict__ o_sc,
    float* __restrict__ o_if, float* __restrict__ o_st, float* __restrict__ o_cv)
{
  __shared__ float xi[DD], xni[DD];
  __shared__ int   nbr[MAXNB];
  __shared__ float Sval[MAXNB];
  __shared__ int   wtot[4];
  __shared__ float nbp[4][DD], ex2p[4][DD], sp[4][DD];
  __shared__ float ssqp[4];

  const int i = blockIdx.x, tid = threadIdx.x;
  const int wave = tid>>6, lane = tid&63;

  if(tid < DD){ xi[tid]=x[(size_t)i*DD+tid]; xni[tid]=xn[(size_t)i*DD+tid]; }

  const float4* A4 = (const float4*)(A + (size_t)i*NN);
  float4 av0 = A4[tid];
  float4 av1 = A4[tid+256];
  float4 av2 = A4[tid+512];
  float4 av3 = A4[tid+768];
  int c = 0;
  c += (av0.x>0.f)+(av0.y>0.f)+(av0.z>0.f)+(av0.w>0.f);
  c += (av1.x>0.f)+(av1.y>0.f)+(av1.z>0.f)+(av1.w>0.f);
  c += (av2.x>0.f)+(av2.y>0.f)+(av2.z>0.f)+(av2.w>0.f);
  c += (av3.x>0.f)+(av3.y>0.f)+(av3.z>0.f)+(av3.w>0.f);
  int sc = c;
#pragma unroll
  for(int o=1;o<64;o<<=1){ int v=__shfl_up(sc,o,64); if(lane>=o) sc+=v; }
  if(lane==63) wtot[wave]=sc;
  __syncthreads();
  int base = 0;
#pragma unroll
  for(int ww=0;ww<4;ww++) if(ww<wave) base += wtot[ww];
  int off = base + sc - c;
  const int deg = wtot[0]+wtot[1]+wtot[2]+wtot[3];
  {
    float4 av[4] = {av0,av1,av2,av3};
#pragma unroll
    for(int k=0;k<4;k++){
      int f = tid + k*256;
      if(av[k].x>0.f){ if(off<MAXNB) nbr[off]=f*4+0; off++; }
      if(av[k].y>0.f){ if(off<MAXNB) nbr[off]=f*4+1; off++; }
      if(av[k].z>0.f){ if(off<MAXNB) nbr[off]=f*4+2; off++; }
      if(av[k].w>0.f){ if(off<MAXNB) nbr[off]=f*4+3; off++; }
    }
  }
  __syncthreads();

  const float xid = xi[lane], xnid = xni[lane];
  float nb_d=0.f, ex2_d=0.f, s_d=0.f, ssq=0.f;
  for(int s=wave; s<deg; s+=4){
    int j = nbr[s];
    float xj  = x[(size_t)j*DD + lane];
    float xnj = xn[(size_t)j*DD + lane];
    float cd = xj - xid;
    float c2 = cd*cd, dt = xnid*xnj;
#pragma unroll
    for(int o=1;o<64;o<<=1){ c2 += __shfl_xor(c2,o,64); dt += __shfl_xor(dt,o,64); }
    float nrm = sqrtf(fmaxf(c2, 1e-12f));
    float inv = 1.0f / fmaxf(nrm, 1e-8f);
    nb_d += xj; ex2_d += xj*xj; s_d += cd*inv; ssq += c2*inv*inv;
    if(lane==0) Sval[s] = dt;
  }
  nbp[wave][lane]=nb_d; ex2p[wave][lane]=ex2_d; sp[wave][lane]=s_d;
  if(lane==0) ssqp[wave]=ssq;
  __syncthreads();

  if(wave==0){
    const float degf = (float)deg;
    float nbv = nbp[0][lane]+nbp[1][lane]+nbp[2][lane]+nbp[3][lane];
    float ex2 = ex2p[0][lane]+ex2p[1][lane]+ex2p[2][lane]+ex2p[3][lane];
    float sv  = sp[0][lane]+sp[1][lane]+sp[2][lane]+sp[3][lane];

    float pot = wsum(xid*nbv);
    float m1  = nbv/degf;
    float var = (ex2 - degf*m1*m1)/(degf-1.0f);
    float varm = wsum(var) * (1.0f/DD);
    float s2  = wsum(sv*sv);
    float ssqT = ssqp[0]+ssqp[1]+ssqp[2]+ssqp[3];

    float mx = -1e30f;
    for(int s=lane;s<deg;s+=64) mx = fmaxf(mx, Sval[s]);
    mx = wmax(mx);
    float se=0.f, ssm=0.f;
    for(int s=lane;s<deg;s+=64){ se += expf(Sval[s]-mx); ssm += Sval[s]; }
    se = wsum(se); ssm = wsum(ssm);
    const float ms = ssm/degf;
    float ent=0.f, fl=0.f;
    for(int s=lane;s<deg;s+=64){
      float p = expf(Sval[s]-mx)/se;
      ent -= p*logf(p + 1e-8f);
      float dv = Sval[s]-ms; fl += dv*dv;
    }
    ent = wsum(ent); fl = wsum(fl)/(degf-1.0f);

    if(lane==0){
      o_te[i]  = sq[i] - pot/(degf + 1e-8f);
      o_ent[i] = ent;
      o_sc[i]  = 0.5f*degf/(float)(NN-1) + 0.5f*en[i]/(*max_en);
      o_if[i]  = fl;
      o_st[i]  = 1.0f/(1.0f + varm);
      o_cv[i]  = 1.0f - (s2 - ssqT)/(degf*(degf-1.0f));
    }
  }
}

// ======== 5-NN phase A: register-blocked Gram GEMM + fused top-5 ========
// block: 256 thr, 128i x 256j tile (2 chunks of 128j), thread = 8x8.
// LDS tiles k-major [k][row] with granule swizzle: slot(r) = r ^ (((r>>5)&1)<<2)
__global__ __launch_bounds__(256, 2) void k_knn2(
    const float* __restrict__ x, const float* __restrict__ sq,
    float2* __restrict__ cand)
{
  __shared__ float ldsI[64*128];
  __shared__ float ldsJ[64*128];
  __shared__ float sqiL[GI];
  __shared__ float sqjL[GC];

  const int tid = threadIdx.x;
  const int w = tid>>6, lane = tid&63;
  const int ti = tid&15, tj = tid>>4;
  const int ibase = (blockIdx.x & 31)*GI;
  const int jb = blockIdx.x >> 5;
  const int jbase = jb*GJ;
  const float4* x4 = (const float4*)x;

  // stage xiT (transposed + swizzled)
  {
    int r = tid>>1, half = tid&1;
    int dst = r ^ (((r>>5)&1)<<2);
    const float4* gp = x4 + (size_t)(ibase + r)*16 + half*8;
#pragma unroll
    for(int q=0;q<8;q++){
      float4 v = gp[q];
      int k0 = half*32 + q*4;
      ldsI[(k0+0)*128+dst]=v.x; ldsI[(k0+1)*128+dst]=v.y;
      ldsI[(k0+2)*128+dst]=v.z; ldsI[(k0+3)*128+dst]=v.w;
    }
    if(tid < GI) sqiL[tid] = sq[ibase+tid];
  }

  float bd[8][5]; int bj[8][5];
#pragma unroll
  for(int rr=0;rr<8;rr++)
#pragma unroll
    for(int k=0;k<5;k++){ bd[rr][k]=3.4e38f; bj[rr][k]=0x7fffffff; }

  const int s_i = (ti>>2)&1;
  const int s_j = (tj>>2)&1;

  for(int ch=0; ch<2; ++ch){
    __syncthreads();
    {
      int r = tid>>1, half = tid&1;
      int dst = r ^ (((r>>5)&1)<<2);
      const float4* gp = x4 + (size_t)(jbase + ch*GC + r)*16 + half*8;
#pragma unroll
      for(int q=0;q<8;q++){
        float4 v = gp[q];
        int k0 = half*32 + q*4;
        ldsJ[(k0+0)*128+dst]=v.x; ldsJ[(k0+1)*128+dst]=v.y;
        ldsJ[(k0+2)*128+dst]=v.z; ldsJ[(k0+3)*128+dst]=v.w;
      }
      if(tid < GC) sqjL[tid] = sq[jbase + ch*GC + tid];
    }
    __syncthreads();

    float acc[8][8];
#pragma unroll
    for(int rr=0;rr<8;rr++)
#pragma unroll
      for(int cc=0;cc<8;cc++) acc[rr][cc]=0.f;

    const float4* LI = (const float4*)ldsI;
    const float4* LJ = (const float4*)ldsJ;
    for(int k=0;k<64;k++){
      float4 aA = LI[k*32 + 2*ti + s_i];
      float4 aB = LI[k*32 + 2*ti + 1 - s_i];
      float4 bA = LJ[k*32 + 2*tj + s_j];
      float4 bB = LJ[k*32 + 2*tj + 1 - s_j];
      float a[8] = {aA.x,aA.y,aA.z,aA.w,aB.x,aB.y,aB.z,aB.w};
      float b[8] = {bA.x,bA.y,bA.z,bA.w,bB.x,bB.y,bB.z,bB.w};
#pragma unroll
      for(int rr=0;rr<8;rr++)
#pragma unroll
        for(int cc=0;cc<8;cc++)
          acc[rr][cc] = fmaf(a[rr], b[cc], acc[rr][cc]);
    }

    // fused selection (lexicographic (d2, j) — matches jax top_k ties)
    const int jg0 = jbase + ch*GC + 8*tj;
#pragma unroll
    for(int rr=0;rr<8;rr++){
      const int irow = ibase + 8*ti + rr;
      const float sqa = sqiL[8*ti+rr];
#pragma unroll
      for(int cc=0;cc<8;cc++){
        const int j = jg0 + cc;
        const float d2 = sqa + sqjL[8*tj+cc] - 2.0f*acc[rr][cc];
        if(j != irow && (d2 < bd[rr][4] || (d2==bd[rr][4] && j<bj[rr][4]))){
          bd[rr][4]=d2; bj[rr][4]=j;
#pragma unroll
          for(int k=3;k>=0;k--){
            bool sw = (bd[rr][k+1]<bd[rr][k]) || (bd[rr][k+1]==bd[rr][k] && bj[rr][k+1]<bj[rr][k]);
            if(sw){ float td=bd[rr][k]; bd[rr][k]=bd[rr][k+1]; bd[rr][k+1]=td;
                    int tjj=bj[rr][k]; bj[rr][k]=bj[rr][k+1]; bj[rr][k+1]=tjj; }
          }
        }
      }
    }
  }
  __syncthreads();  // xjT readers done; alias ldsJ as wcand

  float2* wcand = (float2*)ldsJ;  // [4][16][8][5]
#pragma unroll
  for(int rr=0;rr<8;rr++){
#pragma unroll
    for(int k=0;k<5;k++){
      float d = bd[rr][0]; int j = bj[rr][0];
      float ds_; int js_;
      ds_=__shfl_xor(d,16,64); js_=__shfl_xor(j,16,64); if(ds_<d||(ds_==d&&js_<j)){d=ds_;j=js_;}
      ds_=__shfl_xor(d,32,64); js_=__shfl_xor(j,32,64); if(ds_<d||(ds_==d&&js_<j)){d=ds_;j=js_;}
      if(bd[rr][0]==d && bj[rr][0]==j){
        bd[rr][0]=bd[rr][1];bj[rr][0]=bj[rr][1]; bd[rr][1]=bd[rr][2];bj[rr][1]=bj[rr][2];
        bd[rr][2]=bd[rr][3];bj[rr][2]=bj[rr][3]; bd[rr][3]=bd[rr][4];bj[rr][3]=bj[rr][4];
        bd[rr][4]=3.4e38f; bj[rr][4]=0x7fffffff;
      }
      if(lane<16) wcand[((w*16+ti)*8+rr)*5+k] = make_float2(d, __int_as_float(j));
    }
  }
  __syncthreads();

  if(tid < GI){
    const int ti2 = tid>>3, rr2 = tid&7;
    float fd[5]; int fj[5];
#pragma unroll
    for(int k=0;k<5;k++){ fd[k]=3.4e38f; fj[k]=0x7fffffff; }
    for(int w2=0;w2<4;w2++)
      for(int k=0;k<5;k++){
        float2 cc2 = wcand[((w2*16+ti2)*8+rr2)*5+k];
        float d2 = cc2.x; int j = __float_as_int(cc2.y);
        if(d2 < fd[4] || (d2==fd[4] && j<fj[4])){
          fd[4]=d2; fj[4]=j;
#pragma unroll
          for(int kk=3;kk>=0;kk--){
            bool sw = (fd[kk+1]<fd[kk]) || (fd[kk+1]==fd[kk] && fj[kk+1]<fj[kk]);
            if(sw){ float td=fd[kk]; fd[kk]=fd[kk+1]; fd[kk+1]=td;
                    int tjj=fj[kk]; fj[kk]=fj[kk+1]; fj[kk+1]=tjj; }
          }
        }
      }
    const int i = ibase + 8*ti2 + rr2;
#pragma unroll
    for(int k=0;k<5;k++)
      cand[((size_t)i*NJB + jb)*5 + k] = make_float2(fd[k], __int_as_float(fj[k]));
  }
}

// ======== 5-NN phase B: merge 16x5 candidates per row + epilogue ========
__global__ __launch_bounds__(256) void k_nnsel(
    const float* __restrict__ x, const float2* __restrict__ cand,
    const float* __restrict__ mean, float* __restrict__ o_eq)
{
  const int w = threadIdx.x>>6, l = threadIdx.x&63;
  const int i = blockIdx.x*4 + w;
  const float2* cr = cand + (size_t)i*NJB*5;   // 80 entries
  float2 e0 = cr[l];
  float c0d = e0.x; int c0j = __float_as_int(e0.y);
  float c1d = 3.4e38f; int c1j = 0x7fffffff;
  if(l < NJB*5 - 64){ float2 e1 = cr[64+l]; c1d=e1.x; c1j=__float_as_int(e1.y); }

  int sel[5];
#pragma unroll
  for(int k=0;k<5;k++){
    float d = c0d; int j = c0j;
    if(c1d<d || (c1d==d && c1j<j)){ d=c1d; j=c1j; }
#pragma unroll
    for(int o=1;o<64;o<<=1){
      float ds_=__shfl_xor(d,o,64); int js_=__shfl_xor(j,o,64);
      if(ds_<d||(ds_==d&&js_<j)){ d=ds_; j=js_; }
    }
    sel[k]=j;
    if(c0d==d && c0j==j){ c0d=3.4e38f; c0j=0x7fffffff; }
    else if(c1d==d && c1j==j){ c1d=3.4e38f; c1j=0x7fffffff; }
  }

  float smv=0.f;
#pragma unroll
  for(int k=0;k<5;k++) smv += x[(size_t)sel[k]*DD + l];
  float xiv = x[(size_t)i*DD + l];
  float lv = xiv - smv*0.2f;
  float gv = xiv - mean[l];
  float pl = wsum(lv*lv), pg = wsum(gv*gv);
  if(l==0) o_eq[i] = 0.6f*sqrtf(pg) + 0.4f*sqrtf(pl);
}

extern "C" void kernel_launch(void* const* d_in, const int* in_sizes, int n_in,
                              void* d_out, int out_size, void* d_ws, size_t ws_size,
                              hipStream_t stream) {
  const float* x = (const float*)d_in[0];
  const float* A = (const float*)d_in[1];
  float* out = (float*)d_out;
  float* ws  = (float*)d_ws;
  float* xn     = ws;                 // N*D
  float* sq     = xn + NN*DD;         // N
  float* en     = sq + NN;            // N
  float* mean   = en + NN;            // D
  float* max_en = mean + DD;          // 1 (+1 pad for float2 alignment)
  float2* cand  = (float2*)(max_en + 2); // N*NJB*5 float2 = 2.62MB

  k_init<<<1, 1, 0, stream>>>(max_en);
  k_pre<<<NN/4, 256, 0, stream>>>(x, xn, sq, en, max_en);
  k_colmean<<<DD, 256, 0, stream>>>(x, mean);
  k_knn2<<<32*NJB, 256, 0, stream>>>(x, sq, cand);
  k_sparse<<<NN, 256, 0, stream>>>(x, A, xn, sq, en, max_en,
                                   out, out+NN, out+3*NN, out+4*NN, out+5*NN, out+6*NN);
  k_nnsel<<<NN/4, 256, 0, stream>>>(x, cand, mean, out+2*NN);
}

// Round 5
// 157.449 us; speedup vs baseline: 2.5786x; 1.1420x over previous
//
#include <hip/hip_runtime.h>
#include <math.h>

#define NN 4096
#define DD 64

typedef _Float16 half8 __attribute__((ext_vector_type(8)));
typedef float f32x4 __attribute__((ext_vector_type(4)));

__device__ __forceinline__ float wsum(float v){
#pragma unroll
  for(int o=1;o<64;o<<=1) v += __shfl_xor(v,o,64);
  return v;
}
__device__ __forceinline__ float wmax(float v){
#pragma unroll
  for(int o=1;o<64;o<<=1) v = fmaxf(v, __shfl_xor(v,o,64));
  return v;
}

// ---- reset max_sq (graph replays must be deterministic; ws not re-poisoned) ----
__global__ void k_init(float* max_sq){ *(int*)max_sq = 0; }

// ---- per-node: sq=||x||^2, split-f16 hi/lo of x, global max sq ----
__global__ __launch_bounds__(256) void k_pre(const float* __restrict__ x,
                      float* __restrict__ sq, float* __restrict__ max_sq,
                      _Float16* __restrict__ xh, _Float16* __restrict__ xl){
  int node = blockIdx.x*4 + (threadIdx.x>>6);
  int lane = threadIdx.x & 63;
  float v = x[(size_t)node*DD + lane];
  float s = wsum(v*v);
  _Float16 h = (_Float16)v;
  float hf = (float)h;
  _Float16 l = (_Float16)(v - hf);
  xh[(size_t)node*DD+lane] = h;
  xl[(size_t)node*DD+lane] = l;
  if(lane==0){ sq[node]=s; atomicMax((int*)max_sq, __float_as_int(s)); }
}

// ---- column mean of x (for gdev) ----
__global__ __launch_bounds__(256) void k_colmean(const float* __restrict__ x,
                                                 float* __restrict__ mean){
  int d = blockIdx.x;
  float s = 0.f;
  for(int n = threadIdx.x; n < NN; n += 256) s += x[(size_t)n*DD + d];
  __shared__ float red[256];
  red[threadIdx.x] = s; __syncthreads();
  for(int o=128;o>0;o>>=1){ if(threadIdx.x<o) red[threadIdx.x]+=red[threadIdx.x+o]; __syncthreads(); }
  if(threadIdx.x==0) mean[d] = red[0] * (1.0f/NN);
}

// ---- sparse per-node pass: one node per WAVE, barrier-free ----
__global__ __launch_bounds__(256) void k_sparse(
    const float* __restrict__ x, const float* __restrict__ A,
    const float* __restrict__ sq, const float* __restrict__ max_sq,
    float* __restrict__ o_te, float* __restrict__ o_ent, float* __restrict__ o_sc,
    float* __restrict__ o_if, float* __restrict__ o_st, float* __restrict__ o_cv)
{
  __shared__ int   nbr[4][128];
  __shared__ float Sval[4][128];
  const int w = threadIdx.x>>6, lane = threadIdx.x&63;
  const int i = blockIdx.x*4 + w;
  const float xid = x[(size_t)i*DD + lane];
  const float sqi = sq[i];
  const float eni = sqrtf(sqi);
  const float4* A4 = (const float4*)(A + (size_t)i*NN);

  int deg = 0;
  for(int ch=0; ch<4; ++ch){
    float4 av[4];
#pragma unroll
    for(int qq=0; qq<4; ++qq) av[qq] = A4[lane + 64*(ch*4+qq)];
    int c = 0;
#pragma unroll
    for(int qq=0; qq<4; ++qq)
      c += (av[qq].x>0.f)+(av[qq].y>0.f)+(av[qq].z>0.f)+(av[qq].w>0.f);
    int sc = c;
#pragma unroll
    for(int o=1;o<64;o<<=1){ int v=__shfl_up(sc,o,64); if(lane>=o) sc+=v; }
    int off = deg + sc - c;
#pragma unroll
    for(int qq=0; qq<4; ++qq){
      int jb = 4*(lane + 64*(ch*4+qq));
      if(av[qq].x>0.f){ nbr[w][off & 127] = jb+0; off++; }
      if(av[qq].y>0.f){ nbr[w][off & 127] = jb+1; off++; }
      if(av[qq].z>0.f){ nbr[w][off & 127] = jb+2; off++; }
      if(av[qq].w>0.f){ nbr[w][off & 127] = jb+3; off++; }
    }
    deg += __shfl(sc, 63, 64);
  }

  const float degf = (float)deg;
  float nb_d=0.f, ex2_d=0.f, s_d=0.f, ssq=0.f;
  for(int s=0; s<deg; ++s){
    int j = nbr[w][s];
    float xj = x[(size_t)j*DD + lane];
    float dot = wsum(xid*xj);
    float sqj = sq[j];
    float c2 = fmaxf(sqi + sqj - 2.0f*dot, 1e-12f);
    float nrm = sqrtf(c2);
    float inv = 1.0f/fmaxf(nrm, 1e-8f);
    float cd = xj - xid;
    nb_d += xj; ex2_d += xj*xj; s_d += cd*inv; ssq += c2*inv*inv;
    if(lane==0) Sval[w][s] = dot/(eni*sqrtf(sqj));
  }

  float pot = wsum(xid*nb_d);
  float m1  = nb_d/degf;
  float var = (ex2_d - degf*m1*m1)/(degf-1.0f);
  float varm = wsum(var) * (1.0f/DD);
  float s2  = wsum(s_d*s_d);

  float mx = -1e30f;
  for(int s=lane;s<deg;s+=64) mx = fmaxf(mx, Sval[w][s]);
  mx = wmax(mx);
  float se=0.f, ssm=0.f;
  for(int s=lane;s<deg;s+=64){ float v=Sval[w][s]; se += expf(v-mx); ssm += v; }
  se = wsum(se); ssm = wsum(ssm);
  const float ms = ssm/degf;
  float ent=0.f, fl=0.f;
  for(int s=lane;s<deg;s+=64){
    float v = Sval[w][s];
    float p = expf(v-mx)/se;
    ent -= p*logf(p + 1e-8f);
    float dv = v-ms; fl += dv*dv;
  }
  ent = wsum(ent); fl = wsum(fl)/(degf-1.0f);

  if(lane==0){
    o_te[i]  = sqi - pot/(degf + 1e-8f);
    o_ent[i] = ent;
    o_sc[i]  = 0.5f*degf/(float)(NN-1) + 0.5f*eni/sqrtf(*max_sq);
    o_if[i]  = fl;
    o_st[i]  = 1.0f/(1.0f + varm);
    o_cv[i]  = 1.0f - (s2 - ssq)/(degf*(degf-1.0f));
  }
}

// ---- top-5 insert, lexicographic (d2, j) — matches jax top_k tie rule ----
__device__ __forceinline__ void ins5(float d2, int j, float bd[5], int bj[5]){
  if(d2 < bd[4] || (d2==bd[4] && j<bj[4])){
    bd[4]=d2; bj[4]=j;
#pragma unroll
    for(int k=3;k>=0;k--){
      bool sw = (bd[k+1]<bd[k]) || (bd[k+1]==bd[k] && bj[k+1]<bj[k]);
      if(sw){ float td=bd[k]; bd[k]=bd[k+1]; bd[k+1]=td;
              int tj=bj[k]; bj[k]=bj[k+1]; bj[k+1]=tj; }
    }
  }
}

// ======== 5-NN phase A: split-f16 MFMA Gram + fused top-5 ========
// wave = 16-row i-strip x 256-col j-split. block's 4 waves share the j-split
// (consecutive strips) so J-fragments hit L1. No LDS.
__global__ __launch_bounds__(256, 4) void k_knng(
    const _Float16* __restrict__ xh, const _Float16* __restrict__ xl,
    const float* __restrict__ sq, float2* __restrict__ cand)
{
  const int w = threadIdx.x>>6, lane = threadIdx.x&63;
  const int split = blockIdx.x & 15;            // 16 splits x 256 j
  const int strip = (blockIdx.x >> 4)*4 + w;    // 256 strips x 16 i
  const int ibase = strip*16, j0 = split*256;
  const int col = lane & 15, kg = lane >> 4;

  const half8 Ih0 = *(const half8*)(xh + (size_t)(ibase+col)*DD + kg*8);
  const half8 Ih1 = *(const half8*)(xh + (size_t)(ibase+col)*DD + 32 + kg*8);
  const half8 Il0 = *(const half8*)(xl + (size_t)(ibase+col)*DD + kg*8);
  const half8 Il1 = *(const half8*)(xl + (size_t)(ibase+col)*DD + 32 + kg*8);
  float sqi[4];
#pragma unroll
  for(int r=0;r<4;r++) sqi[r] = sq[ibase + kg*4 + r];

  float bd[4][5]; int bj[4][5];
#pragma unroll
  for(int r=0;r<4;r++)
#pragma unroll
    for(int k=0;k<5;k++){ bd[r][k]=3.4e38f; bj[r][k]=0x7fffffff; }

  for(int jt=0; jt<16; ++jt){
    const int jb = j0 + jt*16;
    const half8 Jh0 = *(const half8*)(xh + (size_t)(jb+col)*DD + kg*8);
    const half8 Jh1 = *(const half8*)(xh + (size_t)(jb+col)*DD + 32 + kg*8);
    const half8 Jl0 = *(const half8*)(xl + (size_t)(jb+col)*DD + kg*8);
    const half8 Jl1 = *(const half8*)(xl + (size_t)(jb+col)*DD + 32 + kg*8);
    const float sqj = sq[jb + col];
    f32x4 acc = {0.f,0.f,0.f,0.f};
    acc = __builtin_amdgcn_mfma_f32_16x16x32_f16(Ih0, Jh0, acc, 0,0,0);
    acc = __builtin_amdgcn_mfma_f32_16x16x32_f16(Ih1, Jh1, acc, 0,0,0);
    acc = __builtin_amdgcn_mfma_f32_16x16x32_f16(Ih0, Jl0, acc, 0,0,0);
    acc = __builtin_amdgcn_mfma_f32_16x16x32_f16(Ih1, Jl1, acc, 0,0,0);
    acc = __builtin_amdgcn_mfma_f32_16x16x32_f16(Il0, Jh0, acc, 0,0,0);
    acc = __builtin_amdgcn_mfma_f32_16x16x32_f16(Il1, Jh1, acc, 0,0,0);
    const int j = jb + col;
#pragma unroll
    for(int r=0;r<4;r++){
      const int irow = ibase + kg*4 + r;
      float d2 = sqi[r] + sqj - 2.0f*acc[r];
      if(j != irow) ins5(d2, j, bd[r], bj[r]);
    }
  }

  // merge across the 16 lanes of each kg-group; winners to cand
#pragma unroll
  for(int r=0;r<4;r++){
    const int irow = ibase + kg*4 + r;
#pragma unroll
    for(int k=0;k<5;k++){
      float d = bd[r][0]; int j = bj[r][0];
#pragma unroll
      for(int o=1;o<16;o<<=1){
        float ds_=__shfl_xor(d,o,64); int js_=__shfl_xor(j,o,64);
        if(ds_<d||(ds_==d&&js_<j)){ d=ds_; j=js_; }
      }
      if(bd[r][0]==d && bj[r][0]==j){
        bd[r][0]=bd[r][1];bj[r][0]=bj[r][1]; bd[r][1]=bd[r][2];bj[r][1]=bj[r][2];
        bd[r][2]=bd[r][3];bj[r][2]=bj[r][3]; bd[r][3]=bd[r][4];bj[r][3]=bj[r][4];
        bd[r][4]=3.4e38f; bj[r][4]=0x7fffffff;
      }
      if(col==k) cand[((size_t)irow*16 + split)*5 + k] = make_float2(d, __int_as_float(j));
    }
  }
}

// ======== 5-NN phase B: merge 16x5 candidates per row + epilogue ========
__global__ __launch_bounds__(256) void k_nnsel(
    const float* __restrict__ x, const float2* __restrict__ cand,
    const float* __restrict__ mean, float* __restrict__ o_eq)
{
  const int w = threadIdx.x>>6, l = threadIdx.x&63;
  const int i = blockIdx.x*4 + w;
  const float2* cr = cand + (size_t)i*16*5;   // 80 entries
  float2 e0 = cr[l];
  float c0d = e0.x; int c0j = __float_as_int(e0.y);
  float c1d = 3.4e38f; int c1j = 0x7fffffff;
  if(l < 16){ float2 e1 = cr[64+l]; c1d=e1.x; c1j=__float_as_int(e1.y); }

  int sel[5];
#pragma unroll
  for(int k=0;k<5;k++){
    float d = c0d; int j = c0j;
    if(c1d<d || (c1d==d && c1j<j)){ d=c1d; j=c1j; }
#pragma unroll
    for(int o=1;o<64;o<<=1){
      float ds_=__shfl_xor(d,o,64); int js_=__shfl_xor(j,o,64);
      if(ds_<d||(ds_==d&&js_<j)){ d=ds_; j=js_; }
    }
    sel[k]=j;
    if(c0d==d && c0j==j){ c0d=3.4e38f; c0j=0x7fffffff; }
    else if(c1d==d && c1j==j){ c1d=3.4e38f; c1j=0x7fffffff; }
  }

  float smv=0.f;
#pragma unroll
  for(int k=0;k<5;k++) smv += x[(size_t)sel[k]*DD + l];
  float xiv = x[(size_t)i*DD + l];
  float lv = xiv - smv*0.2f;
  float gv = xiv - mean[l];
  float pl = wsum(lv*lv), pg = wsum(gv*gv);
  if(l==0) o_eq[i] = 0.6f*sqrtf(pg) + 0.4f*sqrtf(pl);
}

extern "C" void kernel_launch(void* const* d_in, const int* in_sizes, int n_in,
                              void* d_out, int out_size, void* d_ws, size_t ws_size,
                              hipStream_t stream) {
  const float* x = (const float*)d_in[0];
  const float* A = (const float*)d_in[1];
  float* out = (float*)d_out;
  float* ws  = (float*)d_ws;
  // ws layout (floats): sq[4096] | mean[64] | max_sq(+pad) | xh | xl | cand
  float*     sq     = ws;                         // 0 .. 4096
  float*     mean   = ws + 4096;                  // 4096 .. 4160
  float*     max_sq = ws + 4160;                  // 4160 (pad to 4224)
  _Float16*  xh     = (_Float16*)(ws + 4224);     // 262144 halves = 131072 floats
  _Float16*  xl     = (_Float16*)(ws + 135296);   // 262144 halves
  float2*    cand   = (float2*)(ws + 266368);     // 4096*16*5 float2 = 655360 floats

  k_init<<<1, 1, 0, stream>>>(max_sq);
  k_pre<<<NN/4, 256, 0, stream>>>(x, sq, max_sq, xh, xl);
  k_colmean<<<DD, 256, 0, stream>>>(x, mean);
  k_knng<<<NN/4, 256, 0, stream>>>(xh, xl, sq, cand);
  k_sparse<<<NN/4, 256, 0, stream>>>(x, A, sq, max_sq,
                                     out, out+NN, out+3*NN, out+4*NN, out+5*NN, out+6*NN);
  k_nnsel<<<NN/4, 256, 0, stream>>>(x, cand, mean, out+2*NN);
}

// Round 6
// 152.321 us; speedup vs baseline: 2.6654x; 1.0337x over previous
//
#include <hip/hip_runtime.h>
#include <math.h>

#define NN 4096
#define DD 64

typedef _Float16 half8 __attribute__((ext_vector_type(8)));
typedef float f32x4 __attribute__((ext_vector_type(4)));

__device__ __forceinline__ float wsum(float v){
#pragma unroll
  for(int o=1;o<64;o<<=1) v += __shfl_xor(v,o,64);
  return v;
}
__device__ __forceinline__ float wmax(float v){
#pragma unroll
  for(int o=1;o<64;o<<=1) v = fmaxf(v, __shfl_xor(v,o,64));
  return v;
}

// ---- reset accumulators (ws not re-poisoned between replays) ----
__global__ void k_init(float* msum, float* max_sq){
  int t = threadIdx.x;
  if(t < 64) msum[t] = 0.f;
  if(t == 64) *(int*)max_sq = 0;
}

// ---- per-node: sq=||x||^2, split-f16 hi/lo of x, global max sq ----
__global__ __launch_bounds__(256) void k_pre(const float* __restrict__ x,
                      float* __restrict__ sq, float* __restrict__ max_sq,
                      _Float16* __restrict__ xh, _Float16* __restrict__ xl){
  int node = blockIdx.x*4 + (threadIdx.x>>6);
  int lane = threadIdx.x & 63;
  float v = x[(size_t)node*DD + lane];
  float s = wsum(v*v);
  _Float16 h = (_Float16)v;
  float hf = (float)h;
  _Float16 l = (_Float16)(v - hf);
  xh[(size_t)node*DD+lane] = h;
  xl[(size_t)node*DD+lane] = l;
  if(lane==0){ sq[node]=s; atomicMax((int*)max_sq, __float_as_int(s)); }
}

// ---- column sum of x (coalesced rows, block partial + atomic) ----
__global__ __launch_bounds__(256) void k_cmean(const float* __restrict__ x,
                                               float* __restrict__ msum){
  __shared__ float part[4][64];
  const int w = threadIdx.x>>6, lane = threadIdx.x&63;
  const int r0 = blockIdx.x*16 + w*4;
  float s = 0.f;
#pragma unroll
  for(int q=0;q<4;q++) s += x[(size_t)(r0+q)*DD + lane];
  part[w][lane] = s; __syncthreads();
  if(w==0){
    float t = part[0][lane]+part[1][lane]+part[2][lane]+part[3][lane];
    atomicAdd(&msum[lane], t);
  }
}

// ---- sparse per-node pass: one node per wave; batched loads, 4-wide nbr loop ----
__global__ __launch_bounds__(256) void k_sparse(
    const float* __restrict__ x, const float* __restrict__ A,
    const float* __restrict__ sq, const float* __restrict__ max_sq,
    float* __restrict__ o_te, float* __restrict__ o_ent, float* __restrict__ o_sc,
    float* __restrict__ o_if, float* __restrict__ o_st, float* __restrict__ o_cv)
{
  __shared__ int   nbr[4][128];
  __shared__ float Sval[4][128];
  const int w = threadIdx.x>>6, lane = threadIdx.x&63;
  const int i = blockIdx.x*4 + w;
  const float xid = x[(size_t)i*DD + lane];
  const float sqi = sq[i];
  const float eni = sqrtf(sqi);
  const float4* A4 = (const float4*)(A + (size_t)i*NN);

  // prefetch entire A row (16 x float4 per lane) so all loads overlap
  float4 av[16];
#pragma unroll
  for(int q=0;q<16;q++) av[q] = A4[lane + 64*q];
  int c = 0;
#pragma unroll
  for(int q=0;q<16;q++)
    c += (av[q].x>0.f)+(av[q].y>0.f)+(av[q].z>0.f)+(av[q].w>0.f);
  int sc = c;
#pragma unroll
  for(int o=1;o<64;o<<=1){ int v=__shfl_up(sc,o,64); if(lane>=o) sc+=v; }
  const int deg = __shfl(sc, 63, 64);
  int off = sc - c;
#pragma unroll
  for(int q=0;q<16;q++){
    int jb = 4*(lane + 64*q);
    if(av[q].x>0.f){ if(off<128) nbr[w][off]=jb+0; off++; }
    if(av[q].y>0.f){ if(off<128) nbr[w][off]=jb+1; off++; }
    if(av[q].z>0.f){ if(off<128) nbr[w][off]=jb+2; off++; }
    if(av[q].w>0.f){ if(off<128) nbr[w][off]=jb+3; off++; }
  }

  const float degf = (float)deg;
  float nb_d=0.f, ex2_d=0.f, s_d=0.f, ssq=0.f;
  for(int s0=0; s0<deg; s0+=4){
    int i0 = s0, i1 = min(s0+1,deg-1), i2 = min(s0+2,deg-1), i3 = min(s0+3,deg-1);
    int j0=nbr[w][i0], j1=nbr[w][i1], j2=nbr[w][i2], j3=nbr[w][i3];
    float a0 = x[(size_t)j0*DD + lane];
    float a1 = x[(size_t)j1*DD + lane];
    float a2 = x[(size_t)j2*DD + lane];
    float a3 = x[(size_t)j3*DD + lane];
    float p0=xid*a0, p1=xid*a1, p2=xid*a2, p3=xid*a3;
#pragma unroll
    for(int o=1;o<64;o<<=1){
      p0 += __shfl_xor(p0,o,64); p1 += __shfl_xor(p1,o,64);
      p2 += __shfl_xor(p2,o,64); p3 += __shfl_xor(p3,o,64);
    }
    float q0=sq[j0], q1=sq[j1], q2=sq[j2], q3=sq[j3];
    float c20 = fmaxf(sqi+q0-2.0f*p0, 1e-12f);
    float c21 = fmaxf(sqi+q1-2.0f*p1, 1e-12f);
    float c22 = fmaxf(sqi+q2-2.0f*p2, 1e-12f);
    float c23 = fmaxf(sqi+q3-2.0f*p3, 1e-12f);
    float v0 = 1.0f/fmaxf(sqrtf(c20),1e-8f);
    float v1 = 1.0f/fmaxf(sqrtf(c21),1e-8f);
    float v2 = 1.0f/fmaxf(sqrtf(c22),1e-8f);
    float v3 = 1.0f/fmaxf(sqrtf(c23),1e-8f);
    bool k1 = (s0+1)<deg, k2 = (s0+2)<deg, k3 = (s0+3)<deg;
    nb_d  += a0 + (k1?a1:0.f) + (k2?a2:0.f) + (k3?a3:0.f);
    ex2_d += a0*a0 + (k1?a1*a1:0.f) + (k2?a2*a2:0.f) + (k3?a3*a3:0.f);
    s_d   += (a0-xid)*v0 + (k1?(a1-xid)*v1:0.f) + (k2?(a2-xid)*v2:0.f) + (k3?(a3-xid)*v3:0.f);
    ssq   += c20*v0*v0 + (k1?c21*v1*v1:0.f) + (k2?c22*v2*v2:0.f) + (k3?c23*v3*v3:0.f);
    float S0 = p0/(eni*sqrtf(q0));
    float S1 = p1/(eni*sqrtf(q1));
    float S2 = p2/(eni*sqrtf(q2));
    float S3 = p3/(eni*sqrtf(q3));
    float selS = lane==0?S0 : lane==1?S1 : lane==2?S2 : S3;
    if(lane<4 && (s0+lane)<deg) Sval[w][s0+lane] = selS;
  }

  float pot = wsum(xid*nb_d);
  float m1  = nb_d/degf;
  float var = (ex2_d - degf*m1*m1)/(degf-1.0f);
  float varm = wsum(var) * (1.0f/DD);
  float s2  = wsum(s_d*s_d);

  float mx = -1e30f;
  for(int s=lane;s<deg;s+=64) mx = fmaxf(mx, Sval[w][s]);
  mx = wmax(mx);
  float se=0.f, ssm=0.f;
  for(int s=lane;s<deg;s+=64){ float v=Sval[w][s]; se += expf(v-mx); ssm += v; }
  se = wsum(se); ssm = wsum(ssm);
  const float ms = ssm/degf;
  float ent=0.f, fl=0.f;
  for(int s=lane;s<deg;s+=64){
    float v = Sval[w][s];
    float p = expf(v-mx)/se;
    ent -= p*logf(p + 1e-8f);
    float dv = v-ms; fl += dv*dv;
  }
  ent = wsum(ent); fl = wsum(fl)/(degf-1.0f);

  if(lane==0){
    o_te[i]  = sqi - pot/(degf + 1e-8f);
    o_ent[i] = ent;
    o_sc[i]  = 0.5f*degf/(float)(NN-1) + 0.5f*eni/sqrtf(*max_sq);
    o_if[i]  = fl;
    o_st[i]  = 1.0f/(1.0f + varm);
    o_cv[i]  = 1.0f - (s2 - ssq)/(degf*(degf-1.0f));
  }
}

// ---- top-5 insert, lexicographic (m, j) — matches jax top_k tie rule ----
__device__ __forceinline__ void ins5(float m, int j, float bd[5], int bj[5]){
  if(m < bd[4] || (m==bd[4] && j<bj[4])){
    bd[4]=m; bj[4]=j;
#pragma unroll
    for(int k=3;k>=0;k--){
      bool sw = (bd[k+1]<bd[k]) || (bd[k+1]==bd[k] && bj[k+1]<bj[k]);
      if(sw){ float td=bd[k]; bd[k]=bd[k+1]; bd[k+1]=td;
              int tj=bj[k]; bj[k]=bj[k+1]; bj[k+1]=tj; }
    }
  }
}

// ======== 5-NN phase A: split-f16 MFMA Gram + fused top-5 ========
// wave = 16-row strip x 256-j split; 2 j-tiles/iter = 4 independent MFMA chains.
// selection key m = sqj - 2*dot (sqi constant per row -> same ordering).
__global__ __launch_bounds__(256, 4) void k_knng(
    const _Float16* __restrict__ xh, const _Float16* __restrict__ xl,
    const float* __restrict__ sq, float2* __restrict__ cand)
{
  const int w = threadIdx.x>>6, lane = threadIdx.x&63;
  const int split = blockIdx.x & 15;
  const int strip = (blockIdx.x >> 4)*4 + w;
  const int ibase = strip*16, j0 = split*256;
  const int col = lane & 15, kg = lane >> 4;
  const int vo = col*DD + kg*8;

  const _Float16* pih = xh + (size_t)ibase*DD + vo;
  const _Float16* pil = xl + (size_t)ibase*DD + vo;
  const half8 Ih0 = *(const half8*)(pih);
  const half8 Ih1 = *(const half8*)(pih+32);
  const half8 Il0 = *(const half8*)(pil);
  const half8 Il1 = *(const half8*)(pil+32);

  const _Float16* pjh = xh + (size_t)j0*DD + vo;
  const _Float16* pjl = xl + (size_t)j0*DD + vo;

  float bm[4][5]; int bj[4][5];
#pragma unroll
  for(int r=0;r<4;r++)
#pragma unroll
    for(int k=0;k<5;k++){ bm[r][k]=3.4e38f; bj[r][k]=0x7fffffff; }

  for(int jt=0; jt<16; jt+=2){
    const _Float16* pah = pjh + jt*16*DD;
    const _Float16* pal = pjl + jt*16*DD;
    half8 Jh0a = *(const half8*)(pah);
    half8 Jh1a = *(const half8*)(pah+32);
    half8 Jl0a = *(const half8*)(pal);
    half8 Jl1a = *(const half8*)(pal+32);
    half8 Jh0b = *(const half8*)(pah+16*DD);
    half8 Jh1b = *(const half8*)(pah+16*DD+32);
    half8 Jl0b = *(const half8*)(pal+16*DD);
    half8 Jl1b = *(const half8*)(pal+16*DD+32);
    const int ja = j0 + jt*16 + col, jb = ja + 16;
    const float sqa = sq[ja], sqb = sq[jb];

    const f32x4 z = {0.f,0.f,0.f,0.f};
    f32x4 a1 = __builtin_amdgcn_mfma_f32_16x16x32_f16(Ih0, Jh0a, z, 0,0,0);
    f32x4 b1 = __builtin_amdgcn_mfma_f32_16x16x32_f16(Ih0, Jh0b, z, 0,0,0);
    f32x4 a2 = __builtin_amdgcn_mfma_f32_16x16x32_f16(Il0, Jh0a, z, 0,0,0);
    f32x4 b2 = __builtin_amdgcn_mfma_f32_16x16x32_f16(Il0, Jh0b, z, 0,0,0);
    a1 = __builtin_amdgcn_mfma_f32_16x16x32_f16(Ih1, Jh1a, a1, 0,0,0);
    b1 = __builtin_amdgcn_mfma_f32_16x16x32_f16(Ih1, Jh1b, b1, 0,0,0);
    a2 = __builtin_amdgcn_mfma_f32_16x16x32_f16(Il1, Jh1a, a2, 0,0,0);
    b2 = __builtin_amdgcn_mfma_f32_16x16x32_f16(Il1, Jh1b, b2, 0,0,0);
    a1 = __builtin_amdgcn_mfma_f32_16x16x32_f16(Ih0, Jl0a, a1, 0,0,0);
    b1 = __builtin_amdgcn_mfma_f32_16x16x32_f16(Ih0, Jl0b, b1, 0,0,0);
    a2 = __builtin_amdgcn_mfma_f32_16x16x32_f16(Ih1, Jl1a, a2, 0,0,0);
    b2 = __builtin_amdgcn_mfma_f32_16x16x32_f16(Ih1, Jl1b, b2, 0,0,0);

#pragma unroll
    for(int r=0;r<4;r++){
      const int irow = ibase + kg*4 + r;
      float ma = sqa - 2.0f*(a1[r]+a2[r]);
      if(ja != irow) ins5(ma, ja, bm[r], bj[r]);
      float mb = sqb - 2.0f*(b1[r]+b2[r]);
      if(jb != irow) ins5(mb, jb, bm[r], bj[r]);
    }
  }

  // merge across the 16 lanes of each kg-group; winners to cand
#pragma unroll
  for(int r=0;r<4;r++){
    const int irow = ibase + kg*4 + r;
#pragma unroll
    for(int k=0;k<5;k++){
      float d = bm[r][0]; int j = bj[r][0];
#pragma unroll
      for(int o=1;o<16;o<<=1){
        float ds_=__shfl_xor(d,o,64); int js_=__shfl_xor(j,o,64);
        if(ds_<d||(ds_==d&&js_<j)){ d=ds_; j=js_; }
      }
      if(bm[r][0]==d && bj[r][0]==j){
        bm[r][0]=bm[r][1];bj[r][0]=bj[r][1]; bm[r][1]=bm[r][2];bj[r][1]=bj[r][2];
        bm[r][2]=bm[r][3];bj[r][2]=bj[r][3]; bm[r][3]=bm[r][4];bj[r][3]=bj[r][4];
        bm[r][4]=3.4e38f; bj[r][4]=0x7fffffff;
      }
      if(col==k) cand[((size_t)irow*16 + split)*5 + k] = make_float2(d, __int_as_float(j));
    }
  }
}

// ======== 5-NN phase B: merge 16x5 candidates per row + epilogue ========
__global__ __launch_bounds__(256) void k_nnsel(
    const float* __restrict__ x, const float2* __restrict__ cand,
    const float* __restrict__ msum, float* __restrict__ o_eq)
{
  const int w = threadIdx.x>>6, l = threadIdx.x&63;
  const int i = blockIdx.x*4 + w;
  const float2* cr = cand + (size_t)i*16*5;   // 80 entries
  float2 e0 = cr[l];
  float c0d = e0.x; int c0j = __float_as_int(e0.y);
  float c1d = 3.4e38f; int c1j = 0x7fffffff;
  if(l < 16){ float2 e1 = cr[64+l]; c1d=e1.x; c1j=__float_as_int(e1.y); }

  int sel[5];
#pragma unroll
  for(int k=0;k<5;k++){
    float d = c0d; int j = c0j;
    if(c1d<d || (c1d==d && c1j<j)){ d=c1d; j=c1j; }
#pragma unroll
    for(int o=1;o<64;o<<=1){
      float ds_=__shfl_xor(d,o,64); int js_=__shfl_xor(j,o,64);
      if(ds_<d||(ds_==d&&js_<j)){ d=ds_; j=js_; }
    }
    sel[k]=j;
    if(c0d==d && c0j==j){ c0d=3.4e38f; c0j=0x7fffffff; }
    else if(c1d==d && c1j==j){ c1d=3.4e38f; c1j=0x7fffffff; }
  }

  float smv=0.f;
#pragma unroll
  for(int k=0;k<5;k++) smv += x[(size_t)sel[k]*DD + l];
  float xiv = x[(size_t)i*DD + l];
  float lv = xiv - smv*0.2f;
  float gv = xiv - msum[l]*(1.0f/NN);
  float pl = wsum(lv*lv), pg = wsum(gv*gv);
  if(l==0) o_eq[i] = 0.6f*sqrtf(pg) + 0.4f*sqrtf(pl);
}

extern "C" void kernel_launch(void* const* d_in, const int* in_sizes, int n_in,
                              void* d_out, int out_size, void* d_ws, size_t ws_size,
                              hipStream_t stream) {
  const float* x = (const float*)d_in[0];
  const float* A = (const float*)d_in[1];
  float* out = (float*)d_out;
  float* ws  = (float*)d_ws;
  // ws layout (floats): sq[4096] | msum[64] | max_sq(+pad) | xh | xl | cand
  float*     sq     = ws;                         // 0 .. 4096
  float*     msum   = ws + 4096;                  // 4096 .. 4160
  float*     max_sq = ws + 4160;                  // 4160 (pad to 4224)
  _Float16*  xh     = (_Float16*)(ws + 4224);     // 262144 halves = 131072 floats
  _Float16*  xl     = (_Float16*)(ws + 135296);   // 262144 halves
  float2*    cand   = (float2*)(ws + 266368);     // 4096*16*5 float2

  k_init<<<1, 128, 0, stream>>>(msum, max_sq);
  k_pre<<<NN/4, 256, 0, stream>>>(x, sq, max_sq, xh, xl);
  k_cmean<<<NN/16, 256, 0, stream>>>(x, msum);
  k_knng<<<NN/4, 256, 0, stream>>>(xh, xl, sq, cand);
  k_sparse<<<NN/4, 256, 0, stream>>>(x, A, sq, max_sq,
                                     out, out+NN, out+3*NN, out+4*NN, out+5*NN, out+6*NN);
  k_nnsel<<<NN/4, 256, 0, stream>>>(x, cand, msum, out+2*NN);
}

// Round 7
// 144.941 us; speedup vs baseline: 2.8011x; 1.0509x over previous
//
#include <hip/hip_runtime.h>
#include <math.h>

#define NN 4096
#define DD 64

typedef _Float16 half8 __attribute__((ext_vector_type(8)));
typedef float f32x4 __attribute__((ext_vector_type(4)));
typedef unsigned long long u64;

__device__ __forceinline__ float wsum(float v){
#pragma unroll
  for(int o=1;o<64;o<<=1) v += __shfl_xor(v,o,64);
  return v;
}

__device__ __forceinline__ u64 sx64(u64 v, int o){
  unsigned lo = (unsigned)v, hi = (unsigned)(v>>32);
  lo = (unsigned)__shfl_xor((int)lo, o, 64);
  hi = (unsigned)__shfl_xor((int)hi, o, 64);
  return ((u64)hi<<32)|lo;
}
__device__ __forceinline__ u64 umin64(u64 a, u64 b){ return a<b?a:b; }
__device__ __forceinline__ u64 umax64(u64 a, u64 b){ return a<b?b:a; }

__device__ __forceinline__ u64 packkey(float m, int j){
  unsigned u = __float_as_uint(m);
  u ^= (unsigned)((int)u>>31) | 0x80000000u;
  return ((u64)u<<32) | (unsigned)j;
}

// branchless sorted-5 insert on u64 keys
__device__ __forceinline__ void ins5u(u64 k, u64 b[5]){
  bool c0=k<b[0], c1=k<b[1], c2=k<b[2], c3=k<b[3], c4=k<b[4];
  b[4] = c3 ? b[3] : (c4 ? k : b[4]);
  b[3] = c2 ? b[2] : (c3 ? k : b[3]);
  b[2] = c1 ? b[1] : (c2 ? k : b[2]);
  b[1] = c0 ? b[0] : (c1 ? k : b[1]);
  b[0] = c0 ? k : b[0];
}

// butterfly merge over the 16-lane group: sorted-5 + partner sorted-5 -> sorted-5
__device__ __forceinline__ void merge16(u64 b[5]){
#pragma unroll
  for(int st=1; st<16; st<<=1){
    u64 p0=sx64(b[0],st),p1=sx64(b[1],st),p2=sx64(b[2],st),p3=sx64(b[3],st),p4=sx64(b[4],st);
    u64 x01=umax64(b[0],p0);
    u64 o0=umin64(b[0],p0);
    u64 o1=umin64(umin64(b[1],p1), x01);
    u64 o2=umin64(umin64(b[2],p2), umin64(umax64(b[0],p1),umax64(b[1],p0)));
    u64 o3=umin64(umin64(b[3],p3), umin64(umax64(b[0],p2), umin64(umax64(b[1],p1),umax64(b[2],p0))));
    u64 o4=umin64(umin64(b[4],p4), umin64(umin64(umax64(b[0],p3),umax64(b[1],p2)),
                                          umin64(umax64(b[2],p1),umax64(b[3],p0))));
    b[0]=o0;b[1]=o1;b[2]=o2;b[3]=o3;b[4]=o4;
  }
}

// ---- reset accumulators (ws not re-poisoned between replays) ----
__global__ void k_init(float* msum, float* max_sq){
  int t = threadIdx.x;
  if(t < 64) msum[t] = 0.f;
  if(t == 64) *(int*)max_sq = 0;
}

// ---- fused: sq=||x||^2, split-f16 hi/lo, global max sq, column sums ----
__global__ __launch_bounds__(256) void k_prec(const float* __restrict__ x,
                      float* __restrict__ sq, float* __restrict__ max_sq,
                      _Float16* __restrict__ xh, _Float16* __restrict__ xl,
                      float* __restrict__ msum){
  __shared__ float part[4][64];
  const int w = threadIdx.x>>6, lane = threadIdx.x&63;
  const int n0 = blockIdx.x*16 + w*4;
  float v0 = x[(size_t)(n0+0)*DD + lane];
  float v1 = x[(size_t)(n0+1)*DD + lane];
  float v2 = x[(size_t)(n0+2)*DD + lane];
  float v3 = x[(size_t)(n0+3)*DD + lane];
  float s0=v0*v0, s1=v1*v1, s2=v2*v2, s3=v3*v3;
#pragma unroll
  for(int o=1;o<64;o<<=1){
    s0 += __shfl_xor(s0,o,64); s1 += __shfl_xor(s1,o,64);
    s2 += __shfl_xor(s2,o,64); s3 += __shfl_xor(s3,o,64);
  }
  float vv[4] = {v0,v1,v2,v3};
  float ss[4] = {s0,s1,s2,s3};
#pragma unroll
  for(int q=0;q<4;q++){
    float v = vv[q];
    _Float16 h = (_Float16)v;
    _Float16 l = (_Float16)(v - (float)h);
    xh[(size_t)(n0+q)*DD+lane] = h;
    xl[(size_t)(n0+q)*DD+lane] = l;
    if(lane==0){ sq[n0+q]=ss[q]; atomicMax((int*)max_sq, __float_as_int(ss[q])); }
  }
  part[w][lane] = v0+v1+v2+v3; __syncthreads();
  if(w==0) atomicAdd(&msum[lane], part[0][lane]+part[1][lane]+part[2][lane]+part[3][lane]);
}

// ---- sparse per-node pass: wave per node, 8-wide chunked neighbor loop ----
__global__ __launch_bounds__(256) void k_sparse(
    const float* __restrict__ x, const float* __restrict__ A,
    const float* __restrict__ sq, const float* __restrict__ max_sq,
    float* __restrict__ o_te, float* __restrict__ o_ent, float* __restrict__ o_sc,
    float* __restrict__ o_if, float* __restrict__ o_st, float* __restrict__ o_cv)
{
  __shared__ int   nbr[4][128];
  __shared__ float Sval[4][128];
  const int w = threadIdx.x>>6, lane = threadIdx.x&63;
  const int i = blockIdx.x*4 + w;
  const float xid = x[(size_t)i*DD + lane];
  const float sqi = sq[i];
  const float eni = sqrtf(sqi);
  const float4* A4 = (const float4*)(A + (size_t)i*NN);

  // prefetch full A row, count, scan, compact
  float4 av[16];
#pragma unroll
  for(int q=0;q<16;q++) av[q] = A4[lane + 64*q];
  int c = 0;
#pragma unroll
  for(int q=0;q<16;q++)
    c += (av[q].x>0.f)+(av[q].y>0.f)+(av[q].z>0.f)+(av[q].w>0.f);
  int sc = c;
#pragma unroll
  for(int o=1;o<64;o<<=1){ int v=__shfl_up(sc,o,64); if(lane>=o) sc+=v; }
  const int deg = __shfl(sc, 63, 64);
  int off = sc - c;
#pragma unroll
  for(int q=0;q<16;q++){
    int jb = 4*(lane + 64*q);
    if(av[q].x>0.f){ if(off<128) nbr[w][off]=jb+0; off++; }
    if(av[q].y>0.f){ if(off<128) nbr[w][off]=jb+1; off++; }
    if(av[q].z>0.f){ if(off<128) nbr[w][off]=jb+2; off++; }
    if(av[q].w>0.f){ if(off<128) nbr[w][off]=jb+3; off++; }
  }

  const float degf = (float)deg;
  const int dmax = min(deg, 128);
  float nb_d=0.f, ex2_d=0.f, s_d=0.f, ssq=0.f;

  for(int c0=0; c0<dmax; c0+=8){
    int jq[8]; float aq[8], qq[8];
#pragma unroll
    for(int q=0;q<8;q++) jq[q] = nbr[w][min(c0+q, dmax-1)];
#pragma unroll
    for(int q=0;q<8;q++) aq[q] = x[(size_t)jq[q]*DD + lane];
#pragma unroll
    for(int q=0;q<8;q++) qq[q] = sq[jq[q]];
    float p[8];
#pragma unroll
    for(int q=0;q<8;q++) p[q] = xid*aq[q];
#pragma unroll
    for(int o=1;o<64;o<<=1){
#pragma unroll
      for(int q=0;q<8;q++) p[q] += __shfl_xor(p[q],o,64);
    }
#pragma unroll
    for(int q=0;q<8;q++){
      const bool valid = (c0+q) < deg;
      float c2 = fmaxf(sqi + qq[q] - 2.0f*p[q], 1e-12f);
      float inv = 1.0f/fmaxf(sqrtf(c2), 1e-8f);
      nb_d  += valid ? aq[q] : 0.f;
      ex2_d += valid ? aq[q]*aq[q] : 0.f;
      s_d   += valid ? (aq[q]-xid)*inv : 0.f;
      ssq   += valid ? c2*inv*inv : 0.f;
      if(valid && lane==q) Sval[w][c0+q] = p[q]/(eni*sqrtf(qq[q]));
    }
  }

  // interleaved 5-wide reduction: pot, var, s2, se, ssm
  float t0 = xid*nb_d;
  float m1 = nb_d/degf;
  float t1 = (ex2_d - degf*m1*m1)/(degf-1.0f);
  float t2 = s_d*s_d;
  float t3 = 0.f, t4 = 0.f;
  for(int s=lane; s<dmax; s+=64){ float v=Sval[w][s]; t3 += expf(v); t4 += v; }
#pragma unroll
  for(int o=1;o<64;o<<=1){
    t0 += __shfl_xor(t0,o,64); t1 += __shfl_xor(t1,o,64); t2 += __shfl_xor(t2,o,64);
    t3 += __shfl_xor(t3,o,64); t4 += __shfl_xor(t4,o,64);
  }
  const float pot = t0, varm = t1*(1.0f/DD), s2 = t2, se = t3, ms = t4/degf;

  float e0=0.f, e1=0.f;
  const float inv_se = 1.0f/se;
  for(int s=lane; s<dmax; s+=64){
    float v = Sval[w][s];
    float pp = expf(v)*inv_se;
    e0 -= pp*logf(pp + 1e-8f);
    float dv = v-ms; e1 += dv*dv;
  }
#pragma unroll
  for(int o=1;o<64;o<<=1){ e0 += __shfl_xor(e0,o,64); e1 += __shfl_xor(e1,o,64); }

  if(lane==0){
    o_te[i]  = sqi - pot/(degf + 1e-8f);
    o_ent[i] = e0;
    o_sc[i]  = 0.5f*degf/(float)(NN-1) + 0.5f*eni/sqrtf(*max_sq);
    o_if[i]  = e1/(degf-1.0f);
    o_st[i]  = 1.0f/(1.0f + varm);
    o_cv[i]  = 1.0f - (s2 - ssq)/(degf*(degf-1.0f));
  }
}

// ======== 5-NN phase A: split-f16 MFMA Gram + u64 top-5 ========
__global__ __launch_bounds__(256, 4) void k_knng(
    const _Float16* __restrict__ xh, const _Float16* __restrict__ xl,
    const float* __restrict__ sq, u64* __restrict__ cand)
{
  const int w = threadIdx.x>>6, lane = threadIdx.x&63;
  const int split = blockIdx.x & 15;
  const int strip = (blockIdx.x >> 4)*4 + w;
  const int ibase = strip*16, j0 = split*256;
  const int col = lane & 15, kg = lane >> 4;
  const int vo = col*DD + kg*8;

  const _Float16* pih = xh + (size_t)ibase*DD + vo;
  const _Float16* pil = xl + (size_t)ibase*DD + vo;
  const half8 Ih0 = *(const half8*)(pih);
  const half8 Ih1 = *(const half8*)(pih+32);
  const half8 Il0 = *(const half8*)(pil);
  const half8 Il1 = *(const half8*)(pil+32);

  const _Float16* pjh = xh + (size_t)j0*DD + vo;
  const _Float16* pjl = xl + (size_t)j0*DD + vo;

  u64 b0[5], b1[5], b2[5], b3[5];
#pragma unroll
  for(int k=0;k<5;k++){ b0[k]=~0ULL; b1[k]=~0ULL; b2[k]=~0ULL; b3[k]=~0ULL; }

  for(int jt=0; jt<16; jt+=2){
    const _Float16* pah = pjh + jt*16*DD;
    const _Float16* pal = pjl + jt*16*DD;
    half8 Jh0a = *(const half8*)(pah);
    half8 Jh1a = *(const half8*)(pah+32);
    half8 Jl0a = *(const half8*)(pal);
    half8 Jl1a = *(const half8*)(pal+32);
    half8 Jh0b = *(const half8*)(pah+16*DD);
    half8 Jh1b = *(const half8*)(pah+16*DD+32);
    half8 Jl0b = *(const half8*)(pal+16*DD);
    half8 Jl1b = *(const half8*)(pal+16*DD+32);
    const int ja = j0 + jt*16 + col, jb = ja + 16;
    const float sqa = sq[ja], sqb = sq[jb];

    const f32x4 z = {0.f,0.f,0.f,0.f};
    f32x4 a1 = __builtin_amdgcn_mfma_f32_16x16x32_f16(Ih0, Jh0a, z, 0,0,0);
    f32x4 c1 = __builtin_amdgcn_mfma_f32_16x16x32_f16(Ih0, Jh0b, z, 0,0,0);
    f32x4 a2 = __builtin_amdgcn_mfma_f32_16x16x32_f16(Il0, Jh0a, z, 0,0,0);
    f32x4 c2 = __builtin_amdgcn_mfma_f32_16x16x32_f16(Il0, Jh0b, z, 0,0,0);
    a1 = __builtin_amdgcn_mfma_f32_16x16x32_f16(Ih1, Jh1a, a1, 0,0,0);
    c1 = __builtin_amdgcn_mfma_f32_16x16x32_f16(Ih1, Jh1b, c1, 0,0,0);
    a2 = __builtin_amdgcn_mfma_f32_16x16x32_f16(Il1, Jh1a, a2, 0,0,0);
    c2 = __builtin_amdgcn_mfma_f32_16x16x32_f16(Il1, Jh1b, c2, 0,0,0);
    a1 = __builtin_amdgcn_mfma_f32_16x16x32_f16(Ih0, Jl0a, a1, 0,0,0);
    c1 = __builtin_amdgcn_mfma_f32_16x16x32_f16(Ih0, Jl0b, c1, 0,0,0);
    a2 = __builtin_amdgcn_mfma_f32_16x16x32_f16(Ih1, Jl1a, a2, 0,0,0);
    c2 = __builtin_amdgcn_mfma_f32_16x16x32_f16(Ih1, Jl1b, c2, 0,0,0);

    const int base = ibase + kg*4;
#pragma unroll
    for(int r=0;r<4;r++){
      const int irow = base + r;
      u64 ka = packkey(fmaf(-2.0f, a1[r]+a2[r], sqa), ja);
      ka = (ja==irow) ? ~0ULL : ka;
      u64 kb = packkey(fmaf(-2.0f, c1[r]+c2[r], sqb), jb);
      kb = (jb==irow) ? ~0ULL : kb;
      if(r==0){ ins5u(ka,b0); ins5u(kb,b0); }
      else if(r==1){ ins5u(ka,b1); ins5u(kb,b1); }
      else if(r==2){ ins5u(ka,b2); ins5u(kb,b2); }
      else { ins5u(ka,b3); ins5u(kb,b3); }
    }
  }

  merge16(b0); merge16(b1); merge16(b2); merge16(b3);

  const int base = ibase + kg*4;
#pragma unroll
  for(int k=0;k<5;k++){
    if(col==k){
      cand[((size_t)(base+0)*16 + split)*5 + k] = b0[k];
      cand[((size_t)(base+1)*16 + split)*5 + k] = b1[k];
      cand[((size_t)(base+2)*16 + split)*5 + k] = b2[k];
      cand[((size_t)(base+3)*16 + split)*5 + k] = b3[k];
    }
  }
}

// ======== 5-NN phase B: merge 16x5 u64 candidates per row + epilogue ========
__global__ __launch_bounds__(256) void k_nnsel(
    const float* __restrict__ x, const u64* __restrict__ cand,
    const float* __restrict__ msum, float* __restrict__ o_eq)
{
  const int w = threadIdx.x>>6, l = threadIdx.x&63;
  const int i = blockIdx.x*4 + w;
  const u64* cr = cand + (size_t)i*80;
  u64 c0 = cr[l];
  u64 c1 = (l < 16) ? cr[64+l] : ~0ULL;

  int sel[5];
#pragma unroll
  for(int k=0;k<5;k++){
    u64 d = umin64(c0,c1);
#pragma unroll
    for(int o=1;o<64;o<<=1) d = umin64(d, sx64(d,o));
    sel[k] = (int)(unsigned)(d & 0xffffffffULL);
    if(c0==d) c0=~0ULL; else if(c1==d) c1=~0ULL;
  }

  float smv=0.f;
#pragma unroll
  for(int k=0;k<5;k++) smv += x[(size_t)sel[k]*DD + l];
  float xiv = x[(size_t)i*DD + l];
  float lv = xiv - smv*0.2f;
  float gv = xiv - msum[l]*(1.0f/NN);
  float pl = lv*lv, pg = gv*gv;
#pragma unroll
  for(int o=1;o<64;o<<=1){ pl += __shfl_xor(pl,o,64); pg += __shfl_xor(pg,o,64); }
  if(l==0) o_eq[i] = 0.6f*sqrtf(pg) + 0.4f*sqrtf(pl);
}

extern "C" void kernel_launch(void* const* d_in, const int* in_sizes, int n_in,
                              void* d_out, int out_size, void* d_ws, size_t ws_size,
                              hipStream_t stream) {
  const float* x = (const float*)d_in[0];
  const float* A = (const float*)d_in[1];
  float* out = (float*)d_out;
  float* ws  = (float*)d_ws;
  // ws layout (floats): sq[4096] | msum[64] | max_sq(+pad) | xh | xl | cand(u64)
  float*     sq     = ws;
  float*     msum   = ws + 4096;
  float*     max_sq = ws + 4160;
  _Float16*  xh     = (_Float16*)(ws + 4224);     // 262144 halves
  _Float16*  xl     = (_Float16*)(ws + 135296);   // 262144 halves
  u64*       cand   = (u64*)(ws + 266368);        // 4096*16*5 u64

  k_init<<<1, 128, 0, stream>>>(msum, max_sq);
  k_prec<<<NN/16, 256, 0, stream>>>(x, sq, max_sq, xh, xl, msum);
  k_knng<<<NN/4, 256, 0, stream>>>(xh, xl, sq, cand);
  k_sparse<<<NN/4, 256, 0, stream>>>(x, A, sq, max_sq,
                                     out, out+NN, out+3*NN, out+4*NN, out+5*NN, out+6*NN);
  k_nnsel<<<NN/4, 256, 0, stream>>>(x, cand, msum, out+2*NN);
}

// Round 8
// 121.286 us; speedup vs baseline: 3.3474x; 1.1950x over previous
//
#include <hip/hip_runtime.h>
#include <math.h>

#define NN 4096
#define DD 64
#define NSPLIT 32
#define JW 128

typedef _Float16 half8 __attribute__((ext_vector_type(8)));
typedef float f32x4 __attribute__((ext_vector_type(4)));
typedef unsigned long long u64;

__device__ __forceinline__ float wsum(float v){
#pragma unroll
  for(int o=1;o<64;o<<=1) v += __shfl_xor(v,o,64);
  return v;
}
__device__ __forceinline__ u64 sx64(u64 v, int o){
  unsigned lo = (unsigned)v, hi = (unsigned)(v>>32);
  lo = (unsigned)__shfl_xor((int)lo, o, 64);
  hi = (unsigned)__shfl_xor((int)hi, o, 64);
  return ((u64)hi<<32)|lo;
}
__device__ __forceinline__ u64 umin64(u64 a, u64 b){ return a<b?a:b; }
__device__ __forceinline__ u64 umax64(u64 a, u64 b){ return a<b?b:a; }

__device__ __forceinline__ u64 packkey(float m, int j){
  unsigned u = __float_as_uint(m);
  u ^= (unsigned)((int)u>>31) | 0x80000000u;
  return ((u64)u<<32) | (unsigned)j;
}

// branchless sorted-5 insert on u64 keys
__device__ __forceinline__ void ins5u(u64 k, u64 b[5]){
  bool c0=k<b[0], c1=k<b[1], c2=k<b[2], c3=k<b[3], c4=k<b[4];
  b[4] = c3 ? b[3] : (c4 ? k : b[4]);
  b[3] = c2 ? b[2] : (c3 ? k : b[3]);
  b[2] = c1 ? b[1] : (c2 ? k : b[2]);
  b[1] = c0 ? b[0] : (c1 ? k : b[1]);
  b[0] = c0 ? k : b[0];
}

// one butterfly merge stage: sorted-5 + partner's sorted-5 -> sorted-5
__device__ __forceinline__ void mergeStage(u64 b[5], int st){
  u64 p0=sx64(b[0],st),p1=sx64(b[1],st),p2=sx64(b[2],st),p3=sx64(b[3],st),p4=sx64(b[4],st);
  u64 o0=umin64(b[0],p0);
  u64 o1=umin64(umin64(b[1],p1), umax64(b[0],p0));
  u64 o2=umin64(umin64(b[2],p2), umin64(umax64(b[0],p1),umax64(b[1],p0)));
  u64 o3=umin64(umin64(b[3],p3), umin64(umax64(b[0],p2), umin64(umax64(b[1],p1),umax64(b[2],p0))));
  u64 o4=umin64(umin64(b[4],p4), umin64(umin64(umax64(b[0],p3),umax64(b[1],p2)),
                                        umin64(umax64(b[2],p1),umax64(b[3],p0))));
  b[0]=o0;b[1]=o1;b[2]=o2;b[3]=o3;b[4]=o4;
}

// ---- reset accumulators (ws not re-poisoned between replays) ----
__global__ void k_init(float* msum, float* max_sq){
  int t = threadIdx.x;
  if(t < 64) msum[t] = 0.f;
  if(t == 64) *(int*)max_sq = 0;
}

// ---- fused: sq=||x||^2, split-f16 hi/lo, global max sq, column sums ----
__global__ __launch_bounds__(256) void k_prec(const float* __restrict__ x,
                      float* __restrict__ sq, float* __restrict__ max_sq,
                      _Float16* __restrict__ xh, _Float16* __restrict__ xl,
                      float* __restrict__ msum){
  __shared__ float part[4][64];
  const int w = threadIdx.x>>6, lane = threadIdx.x&63;
  const int n0 = blockIdx.x*16 + w*4;
  float v0 = x[(size_t)(n0+0)*DD + lane];
  float v1 = x[(size_t)(n0+1)*DD + lane];
  float v2 = x[(size_t)(n0+2)*DD + lane];
  float v3 = x[(size_t)(n0+3)*DD + lane];
  float s0=v0*v0, s1=v1*v1, s2=v2*v2, s3=v3*v3;
#pragma unroll
  for(int o=1;o<64;o<<=1){
    s0 += __shfl_xor(s0,o,64); s1 += __shfl_xor(s1,o,64);
    s2 += __shfl_xor(s2,o,64); s3 += __shfl_xor(s3,o,64);
  }
  float vv[4] = {v0,v1,v2,v3};
  float ss[4] = {s0,s1,s2,s3};
#pragma unroll
  for(int q=0;q<4;q++){
    float v = vv[q];
    _Float16 h = (_Float16)v;
    _Float16 l = (_Float16)(v - (float)h);
    xh[(size_t)(n0+q)*DD+lane] = h;
    xl[(size_t)(n0+q)*DD+lane] = l;
    if(lane==0){ sq[n0+q]=ss[q]; atomicMax((int*)max_sq, __float_as_int(ss[q])); }
  }
  part[w][lane] = v0+v1+v2+v3; __syncthreads();
  if(w==0) atomicAdd(&msum[lane], part[0][lane]+part[1][lane]+part[2][lane]+part[3][lane]);
}

// ======== MEGA: sparse per-node pass (1/3 of blocks) + MFMA kNN Gram (2/3) ========
__global__ __launch_bounds__(256) void k_mega(
    const float* __restrict__ x, const float* __restrict__ A,
    const float* __restrict__ sq, const float* __restrict__ max_sq,
    const _Float16* __restrict__ xh, const _Float16* __restrict__ xl,
    u64* __restrict__ cand,
    float* __restrict__ o_te, float* __restrict__ o_ent, float* __restrict__ o_sc,
    float* __restrict__ o_if, float* __restrict__ o_st, float* __restrict__ o_cv)
{
  __shared__ int   nbr[4][128];
  __shared__ float Sval[4][128];
  const int bid = blockIdx.x;
  const int w = threadIdx.x>>6, lane = threadIdx.x&63;

  if(bid % 3 == 0){
    // ================= sparse branch: wave per node =================
    const int i = (bid/3)*4 + w;
    const float xid = x[(size_t)i*DD + lane];
    const float sqi = sq[i];
    const float eni = sqrtf(sqi);
    const float4* A4 = (const float4*)(A + (size_t)i*NN);

    float4 av[16];
#pragma unroll
    for(int q=0;q<16;q++) av[q] = A4[lane + 64*q];
    int c = 0;
#pragma unroll
    for(int q=0;q<16;q++)
      c += (av[q].x>0.f)+(av[q].y>0.f)+(av[q].z>0.f)+(av[q].w>0.f);
    int sc = c;
#pragma unroll
    for(int o=1;o<64;o<<=1){ int v=__shfl_up(sc,o,64); if(lane>=o) sc+=v; }
    const int deg = __shfl(sc, 63, 64);
    int off = sc - c;
#pragma unroll
    for(int q=0;q<16;q++){
      int jb = 4*(lane + 64*q);
      if(av[q].x>0.f){ if(off<128) nbr[w][off]=jb+0; off++; }
      if(av[q].y>0.f){ if(off<128) nbr[w][off]=jb+1; off++; }
      if(av[q].z>0.f){ if(off<128) nbr[w][off]=jb+2; off++; }
      if(av[q].w>0.f){ if(off<128) nbr[w][off]=jb+3; off++; }
    }

    const float degf = (float)deg;
    const int dmax = min(deg, 128);
    float nb_d=0.f, ex2_d=0.f, s_d=0.f, ssq=0.f;

    for(int c0=0; c0<dmax; c0+=8){
      int jq[8]; float aq[8], qq[8];
#pragma unroll
      for(int q=0;q<8;q++) jq[q] = nbr[w][min(c0+q, dmax-1)];
#pragma unroll
      for(int q=0;q<8;q++) aq[q] = x[(size_t)jq[q]*DD + lane];
#pragma unroll
      for(int q=0;q<8;q++) qq[q] = sq[jq[q]];
      float p[8];
#pragma unroll
      for(int q=0;q<8;q++) p[q] = xid*aq[q];
#pragma unroll
      for(int o=1;o<64;o<<=1){
#pragma unroll
        for(int q=0;q<8;q++) p[q] += __shfl_xor(p[q],o,64);
      }
#pragma unroll
      for(int q=0;q<8;q++){
        const bool valid = (c0+q) < deg;
        float c2 = fmaxf(sqi + qq[q] - 2.0f*p[q], 1e-12f);
        float inv = 1.0f/fmaxf(sqrtf(c2), 1e-8f);
        nb_d  += valid ? aq[q] : 0.f;
        ex2_d += valid ? aq[q]*aq[q] : 0.f;
        s_d   += valid ? (aq[q]-xid)*inv : 0.f;
        ssq   += valid ? c2*inv*inv : 0.f;
        if(valid && lane==q) Sval[w][c0+q] = p[q]/(eni*sqrtf(qq[q]));
      }
    }

    float t0 = xid*nb_d;
    float m1 = nb_d/degf;
    float t1 = (ex2_d - degf*m1*m1)/(degf-1.0f);
    float t2 = s_d*s_d;
    float t3 = 0.f, t4 = 0.f;
    for(int s=lane; s<dmax; s+=64){ float v=Sval[w][s]; t3 += expf(v); t4 += v; }
#pragma unroll
    for(int o=1;o<64;o<<=1){
      t0 += __shfl_xor(t0,o,64); t1 += __shfl_xor(t1,o,64); t2 += __shfl_xor(t2,o,64);
      t3 += __shfl_xor(t3,o,64); t4 += __shfl_xor(t4,o,64);
    }
    const float pot = t0, varm = t1*(1.0f/DD), s2 = t2, se = t3, ms = t4/degf;

    float e0=0.f, e1=0.f;
    const float inv_se = 1.0f/se;
    for(int s=lane; s<dmax; s+=64){
      float v = Sval[w][s];
      float pp = expf(v)*inv_se;
      e0 -= pp*logf(pp + 1e-8f);
      float dv = v-ms; e1 += dv*dv;
    }
#pragma unroll
    for(int o=1;o<64;o<<=1){ e0 += __shfl_xor(e0,o,64); e1 += __shfl_xor(e1,o,64); }

    if(lane==0){
      o_te[i]  = sqi - pot/(degf + 1e-8f);
      o_ent[i] = e0;
      o_sc[i]  = 0.5f*degf/(float)(NN-1) + 0.5f*eni/sqrtf(*max_sq);
      o_if[i]  = e1/(degf-1.0f);
      o_st[i]  = 1.0f/(1.0f + varm);
      o_cv[i]  = 1.0f - (s2 - ssq)/(degf*(degf-1.0f));
    }
  } else {
    // ================= knng branch: swapped-operand MFMA Gram =================
    const int kid = (bid/3)*2 + (bid%3) - 1;       // 0..2047
    const int split = kid & (NSPLIT-1);
    const int strip = (kid >> 5)*4 + w;            // 0..255
    const int ibase = strip*16, j0 = split*JW;
    const int col = lane & 15, kg = lane >> 4;
    const int vo = col*DD + kg*8;
    const int myi = ibase + col;

    const _Float16* pih = xh + (size_t)ibase*DD + vo;
    const _Float16* pil = xl + (size_t)ibase*DD + vo;
    const half8 Ih0 = *(const half8*)(pih);
    const half8 Ih1 = *(const half8*)(pih+32);
    const half8 Il0 = *(const half8*)(pil);
    const half8 Il1 = *(const half8*)(pil+32);

    const _Float16* pjh = xh + (size_t)j0*DD + vo;
    const _Float16* pjl = xl + (size_t)j0*DD + vo;

    u64 b[5];
#pragma unroll
    for(int k=0;k<5;k++) b[k]=~0ULL;

    for(int jt=0; jt<8; jt+=2){
      const _Float16* pah = pjh + jt*16*DD;
      const _Float16* pal = pjl + jt*16*DD;
      half8 Jh0a = *(const half8*)(pah);
      half8 Jh1a = *(const half8*)(pah+32);
      half8 Jl0a = *(const half8*)(pal);
      half8 Jl1a = *(const half8*)(pal+32);
      half8 Jh0b = *(const half8*)(pah+16*DD);
      half8 Jh1b = *(const half8*)(pah+16*DD+32);
      half8 Jl0b = *(const half8*)(pal+16*DD);
      half8 Jl1b = *(const half8*)(pal+16*DD+32);
      const int ja0 = j0 + jt*16 + kg*4;           // j base for tile a, this lane's regs
      const int jb0 = ja0 + 16;
      float4 sqa4 = *(const float4*)(sq + ja0);
      float4 sqb4 = *(const float4*)(sq + jb0);
      float sqav[4] = {sqa4.x, sqa4.y, sqa4.z, sqa4.w};
      float sqbv[4] = {sqb4.x, sqb4.y, sqb4.z, sqb4.w};

      const f32x4 z = {0.f,0.f,0.f,0.f};
      // dot = J_h.I_h + J_l.I_h + J_h.I_l  (two k-halves each); acc row = j, col = i
      f32x4 a1 = __builtin_amdgcn_mfma_f32_16x16x32_f16(Jh0a, Ih0, z, 0,0,0);
      f32x4 c1 = __builtin_amdgcn_mfma_f32_16x16x32_f16(Jh0b, Ih0, z, 0,0,0);
      f32x4 a2 = __builtin_amdgcn_mfma_f32_16x16x32_f16(Jl0a, Ih0, z, 0,0,0);
      f32x4 c2 = __builtin_amdgcn_mfma_f32_16x16x32_f16(Jl0b, Ih0, z, 0,0,0);
      a1 = __builtin_amdgcn_mfma_f32_16x16x32_f16(Jh1a, Ih1, a1, 0,0,0);
      c1 = __builtin_amdgcn_mfma_f32_16x16x32_f16(Jh1b, Ih1, c1, 0,0,0);
      a2 = __builtin_amdgcn_mfma_f32_16x16x32_f16(Jl1a, Ih1, a2, 0,0,0);
      c2 = __builtin_amdgcn_mfma_f32_16x16x32_f16(Jl1b, Ih1, c2, 0,0,0);
      a1 = __builtin_amdgcn_mfma_f32_16x16x32_f16(Jh0a, Il0, a1, 0,0,0);
      c1 = __builtin_amdgcn_mfma_f32_16x16x32_f16(Jh0b, Il0, c1, 0,0,0);
      a1 = __builtin_amdgcn_mfma_f32_16x16x32_f16(Jh1a, Il1, a1, 0,0,0);
      c1 = __builtin_amdgcn_mfma_f32_16x16x32_f16(Jh1b, Il1, c1, 0,0,0);

#pragma unroll
      for(int r=0;r<4;r++){
        const int ja = ja0 + r;
        u64 ka = packkey(fmaf(-2.0f, a1[r]+a2[r], sqav[r]), ja);
        ka = (ja==myi) ? ~0ULL : ka;
        ins5u(ka, b);
      }
#pragma unroll
      for(int r=0;r<4;r++){
        const int jb = jb0 + r;
        u64 kb = packkey(fmaf(-2.0f, c1[r]+c2[r], sqbv[r]), jb);
        kb = (jb==myi) ? ~0ULL : kb;
        ins5u(kb, b);
      }
    }

    // merge the 4 kg-lanes sharing this col (lane bits 4,5)
    mergeStage(b, 16);
    mergeStage(b, 32);

    if(kg==0){
#pragma unroll
      for(int k=0;k<5;k++)
        cand[((size_t)myi*NSPLIT + split)*5 + k] = b[k];
    }
  }
}

// ======== 5-NN phase B: merge 32x5 u64 candidates per row + epilogue ========
__global__ __launch_bounds__(256) void k_nnsel(
    const float* __restrict__ x, const u64* __restrict__ cand,
    const float* __restrict__ msum, float* __restrict__ o_eq)
{
  const int w = threadIdx.x>>6, l = threadIdx.x&63;
  const int i = blockIdx.x*4 + w;
  const u64* cr = cand + (size_t)i*(NSPLIT*5);
  u64 c0 = cr[l];
  u64 c1 = cr[64+l];
  u64 c2 = (l < 32) ? cr[128+l] : ~0ULL;

  int sel[5];
#pragma unroll
  for(int k=0;k<5;k++){
    u64 d = umin64(c0, umin64(c1, c2));
#pragma unroll
    for(int o=1;o<64;o<<=1) d = umin64(d, sx64(d,o));
    sel[k] = (int)(unsigned)(d & 0xffffffffULL);
    if(c0==d) c0=~0ULL; else if(c1==d) c1=~0ULL; else if(c2==d) c2=~0ULL;
  }

  float smv=0.f;
#pragma unroll
  for(int k=0;k<5;k++) smv += x[(size_t)sel[k]*DD + l];
  float xiv = x[(size_t)i*DD + l];
  float lv = xiv - smv*0.2f;
  float gv = xiv - msum[l]*(1.0f/NN);
  float pl = lv*lv, pg = gv*gv;
#pragma unroll
  for(int o=1;o<64;o<<=1){ pl += __shfl_xor(pl,o,64); pg += __shfl_xor(pg,o,64); }
  if(l==0) o_eq[i] = 0.6f*sqrtf(pg) + 0.4f*sqrtf(pl);
}

extern "C" void kernel_launch(void* const* d_in, const int* in_sizes, int n_in,
                              void* d_out, int out_size, void* d_ws, size_t ws_size,
                              hipStream_t stream) {
  const float* x = (const float*)d_in[0];
  const float* A = (const float*)d_in[1];
  float* out = (float*)d_out;
  float* ws  = (float*)d_ws;
  // ws layout (floats): sq[4096] | msum[64] | max_sq(+pad) | xh | xl | cand(u64)
  float*     sq     = ws;
  float*     msum   = ws + 4096;
  float*     max_sq = ws + 4160;
  _Float16*  xh     = (_Float16*)(ws + 4224);     // 262144 halves
  _Float16*  xl     = (_Float16*)(ws + 135296);   // 262144 halves
  u64*       cand   = (u64*)(ws + 266368);        // 4096*32*5 u64 = 5.24MB

  k_init<<<1, 128, 0, stream>>>(msum, max_sq);
  k_prec<<<NN/16, 256, 0, stream>>>(x, sq, max_sq, xh, xl, msum);
  k_mega<<<3*NN/4, 256, 0, stream>>>(x, A, sq, max_sq, xh, xl, cand,
                                     out, out+NN, out+3*NN, out+4*NN, out+5*NN, out+6*NN);
  k_nnsel<<<NN/4, 256, 0, stream>>>(x, cand, msum, out+2*NN);
}

// Round 9
// 73.780 us; speedup vs baseline: 5.5027x; 1.6439x over previous
//
#include <hip/hip_runtime.h>
#include <math.h>

#define NN 4096
#define DD 64
#define NSPLIT 32
#define JW 128

typedef _Float16 half8 __attribute__((ext_vector_type(8)));
typedef float f32x4 __attribute__((ext_vector_type(4)));
typedef unsigned long long u64;

__device__ __forceinline__ float wsum(float v){
#pragma unroll
  for(int o=1;o<64;o<<=1) v += __shfl_xor(v,o,64);
  return v;
}
__device__ __forceinline__ u64 sx64(u64 v, int o){
  unsigned lo = (unsigned)v, hi = (unsigned)(v>>32);
  lo = (unsigned)__shfl_xor((int)lo, o, 64);
  hi = (unsigned)__shfl_xor((int)hi, o, 64);
  return ((u64)hi<<32)|lo;
}
__device__ __forceinline__ u64 umin64(u64 a, u64 b){ return a<b?a:b; }
__device__ __forceinline__ u64 umax64(u64 a, u64 b){ return a<b?b:a; }

__device__ __forceinline__ u64 packkey(float m, int j){
  unsigned u = __float_as_uint(m);
  u ^= (unsigned)((int)u>>31) | 0x80000000u;
  return ((u64)u<<32) | (unsigned)j;
}

// branchless sorted-5 insert on u64 keys
__device__ __forceinline__ void ins5u(u64 k, u64 b[5]){
  bool c0=k<b[0], c1=k<b[1], c2=k<b[2], c3=k<b[3], c4=k<b[4];
  b[4] = c3 ? b[3] : (c4 ? k : b[4]);
  b[3] = c2 ? b[2] : (c3 ? k : b[3]);
  b[2] = c1 ? b[1] : (c2 ? k : b[2]);
  b[1] = c0 ? b[0] : (c1 ? k : b[1]);
  b[0] = c0 ? k : b[0];
}

// butterfly merge stage across lanes: sorted-5 + partner sorted-5 -> sorted-5
__device__ __forceinline__ void mergeStage(u64 b[5], int st){
  u64 p0=sx64(b[0],st),p1=sx64(b[1],st),p2=sx64(b[2],st),p3=sx64(b[3],st),p4=sx64(b[4],st);
  u64 o0=umin64(b[0],p0);
  u64 o1=umin64(umin64(b[1],p1), umax64(b[0],p0));
  u64 o2=umin64(umin64(b[2],p2), umin64(umax64(b[0],p1),umax64(b[1],p0)));
  u64 o3=umin64(umin64(b[3],p3), umin64(umax64(b[0],p2), umin64(umax64(b[1],p1),umax64(b[2],p0))));
  u64 o4=umin64(umin64(b[4],p4), umin64(umin64(umax64(b[0],p3),umax64(b[1],p2)),
                                        umin64(umax64(b[2],p1),umax64(b[3],p0))));
  b[0]=o0;b[1]=o1;b[2]=o2;b[3]=o3;b[4]=o4;
}

// local merge of two sorted-5 lists -> sorted-5 (no shuffles)
__device__ __forceinline__ void mergeLocal(const u64 a[5], const u64 c[5], u64 b[5]){
  b[0]=umin64(a[0],c[0]);
  b[1]=umin64(umin64(a[1],c[1]), umax64(a[0],c[0]));
  b[2]=umin64(umin64(a[2],c[2]), umin64(umax64(a[0],c[1]),umax64(a[1],c[0])));
  b[3]=umin64(umin64(a[3],c[3]), umin64(umax64(a[0],c[2]), umin64(umax64(a[1],c[1]),umax64(a[2],c[0]))));
  b[4]=umin64(umin64(a[4],c[4]), umin64(umin64(umax64(a[0],c[3]),umax64(a[1],c[2])),
                                        umin64(umax64(a[2],c[1]),umax64(a[3],c[0]))));
}

// ---- fused pre: sq, split-f16 hi/lo, per-block partial colsum + max (NO atomics) ----
__global__ __launch_bounds__(256) void k_prec(const float* __restrict__ x,
                      float* __restrict__ sq,
                      _Float16* __restrict__ xh, _Float16* __restrict__ xl,
                      float* __restrict__ msum_part, float* __restrict__ maxsq_part){
  __shared__ float part[4][64];
  __shared__ float mxp[4];
  const int w = threadIdx.x>>6, lane = threadIdx.x&63;
  const int n0 = blockIdx.x*16 + w*4;
  float v0 = x[(size_t)(n0+0)*DD + lane];
  float v1 = x[(size_t)(n0+1)*DD + lane];
  float v2 = x[(size_t)(n0+2)*DD + lane];
  float v3 = x[(size_t)(n0+3)*DD + lane];
  float s0=v0*v0, s1=v1*v1, s2=v2*v2, s3=v3*v3;
#pragma unroll
  for(int o=1;o<64;o<<=1){
    s0 += __shfl_xor(s0,o,64); s1 += __shfl_xor(s1,o,64);
    s2 += __shfl_xor(s2,o,64); s3 += __shfl_xor(s3,o,64);
  }
  float vv[4] = {v0,v1,v2,v3};
  float ss[4] = {s0,s1,s2,s3};
#pragma unroll
  for(int q=0;q<4;q++){
    float v = vv[q];
    _Float16 h = (_Float16)v;
    _Float16 l = (_Float16)(v - (float)h);
    xh[(size_t)(n0+q)*DD+lane] = h;
    xl[(size_t)(n0+q)*DD+lane] = l;
    if(lane==0) sq[n0+q]=ss[q];
  }
  if(lane==0) mxp[w] = fmaxf(fmaxf(s0,s1), fmaxf(s2,s3));
  part[w][lane] = v0+v1+v2+v3; __syncthreads();
  if(w==0){
    msum_part[blockIdx.x*64 + lane] = part[0][lane]+part[1][lane]+part[2][lane]+part[3][lane];
    if(lane==0) maxsq_part[blockIdx.x] = fmaxf(fmaxf(mxp[0],mxp[1]), fmaxf(mxp[2],mxp[3]));
  }
}

__device__ __forceinline__ void procTile(const half8 J[4], float4 SQV, int jb0, int myi,
    half8 Ih0, half8 Ih1, half8 Il0, half8 Il1, u64 b[5]){
  const f32x4 z = {0.f,0.f,0.f,0.f};
  f32x4 a1 = __builtin_amdgcn_mfma_f32_16x16x32_f16(J[0], Ih0, z, 0,0,0);
  f32x4 a2 = __builtin_amdgcn_mfma_f32_16x16x32_f16(J[2], Ih0, z, 0,0,0);
  a1 = __builtin_amdgcn_mfma_f32_16x16x32_f16(J[1], Ih1, a1, 0,0,0);
  a2 = __builtin_amdgcn_mfma_f32_16x16x32_f16(J[3], Ih1, a2, 0,0,0);
  a1 = __builtin_amdgcn_mfma_f32_16x16x32_f16(J[0], Il0, a1, 0,0,0);
  a1 = __builtin_amdgcn_mfma_f32_16x16x32_f16(J[1], Il1, a1, 0,0,0);
  float sqv[4] = {SQV.x,SQV.y,SQV.z,SQV.w};
#pragma unroll
  for(int r=0;r<4;r++){
    u64 kk = packkey(fmaf(-2.0f, a1[r]+a2[r], sqv[r]), jb0+r);
    kk = (jb0+r==myi) ? ~0ULL : kk;
    ins5u(kk, b);
  }
}

// ======== MEGA: bid0 = stats reduce; then 1/3 sparse, 2/3 MFMA kNN ========
__global__ __launch_bounds__(256, 4) void k_mega(
    const float* __restrict__ x, const float* __restrict__ A,
    const float* __restrict__ sq,
    const _Float16* __restrict__ xh, const _Float16* __restrict__ xl,
    u64* __restrict__ cand,
    const float* __restrict__ msum_part, const float* __restrict__ maxsq_part,
    float* __restrict__ msum, float* __restrict__ max_sq, float* __restrict__ deg_out,
    float* __restrict__ o_te, float* __restrict__ o_ent,
    float* __restrict__ o_if, float* __restrict__ o_st, float* __restrict__ o_cv)
{
  __shared__ int   nbr[4][128];
  __shared__ float Sval[4][128];
  __shared__ float rr[4][64];
  __shared__ float rm[4];
  const int bid = blockIdx.x;
  const int w = threadIdx.x>>6, lane = threadIdx.x&63;

  if(bid == 0){
    // reduce partials -> msum, max_sq
    float s = 0.f;
    for(int p=w; p<256; p+=4) s += msum_part[p*64 + lane];
    rr[w][lane] = s;
    float m = maxsq_part[w*64 + lane];
#pragma unroll
    for(int o=1;o<64;o<<=1) m = fmaxf(m, __shfl_xor(m,o,64));
    if(lane==0) rm[w] = m;
    __syncthreads();
    if(w==0){
      msum[lane] = rr[0][lane]+rr[1][lane]+rr[2][lane]+rr[3][lane];
      if(lane==0) max_sq[0] = fmaxf(fmaxf(rm[0],rm[1]), fmaxf(rm[2],rm[3]));
    }
    return;
  }

  const int t = bid - 1;
  if(t % 3 == 0){
    // ================= sparse branch: wave per node =================
    const int i = (t/3)*4 + w;
    const float xid = x[(size_t)i*DD + lane];
    const float sqi = sq[i];
    const float eni = sqrtf(sqi);
    const float4* A4 = (const float4*)(A + (size_t)i*NN);

    float4 av[16];
#pragma unroll
    for(int q=0;q<16;q++) av[q] = A4[lane + 64*q];
    int c = 0;
#pragma unroll
    for(int q=0;q<16;q++)
      c += (av[q].x>0.f)+(av[q].y>0.f)+(av[q].z>0.f)+(av[q].w>0.f);
    int sc = c;
#pragma unroll
    for(int o=1;o<64;o<<=1){ int v=__shfl_up(sc,o,64); if(lane>=o) sc+=v; }
    const int deg = __shfl(sc, 63, 64);
    int off = sc - c;
#pragma unroll
    for(int q=0;q<16;q++){
      int jb = 4*(lane + 64*q);
      if(av[q].x>0.f){ if(off<128) nbr[w][off]=jb+0; off++; }
      if(av[q].y>0.f){ if(off<128) nbr[w][off]=jb+1; off++; }
      if(av[q].z>0.f){ if(off<128) nbr[w][off]=jb+2; off++; }
      if(av[q].w>0.f){ if(off<128) nbr[w][off]=jb+3; off++; }
    }

    const float degf = (float)deg;
    const int dmax = min(deg, 128);
    float nb_d=0.f, ex2_d=0.f, s_d=0.f, ssq=0.f;

    for(int c0=0; c0<dmax; c0+=8){
      int jq[8]; float aq[8], qq[8];
#pragma unroll
      for(int q=0;q<8;q++) jq[q] = nbr[w][min(c0+q, dmax-1)];
#pragma unroll
      for(int q=0;q<8;q++) aq[q] = x[(size_t)jq[q]*DD + lane];
#pragma unroll
      for(int q=0;q<8;q++) qq[q] = sq[jq[q]];
      float p[8];
#pragma unroll
      for(int q=0;q<8;q++) p[q] = xid*aq[q];
#pragma unroll
      for(int o=1;o<64;o<<=1){
#pragma unroll
        for(int q=0;q<8;q++) p[q] += __shfl_xor(p[q],o,64);
      }
#pragma unroll
      for(int q=0;q<8;q++){
        const bool valid = (c0+q) < deg;
        float c2 = fmaxf(sqi + qq[q] - 2.0f*p[q], 1e-12f);
        float inv = 1.0f/fmaxf(sqrtf(c2), 1e-8f);
        nb_d  += valid ? aq[q] : 0.f;
        ex2_d += valid ? aq[q]*aq[q] : 0.f;
        s_d   += valid ? (aq[q]-xid)*inv : 0.f;
        ssq   += valid ? c2*inv*inv : 0.f;
        if(valid && lane==q) Sval[w][c0+q] = p[q]/(eni*sqrtf(qq[q]));
      }
    }

    float t0 = xid*nb_d;
    float m1 = nb_d/degf;
    float t1 = (ex2_d - degf*m1*m1)/(degf-1.0f);
    float t2 = s_d*s_d;
    float t3 = 0.f, t4 = 0.f;
    for(int s=lane; s<dmax; s+=64){ float v=Sval[w][s]; t3 += expf(v); t4 += v; }
#pragma unroll
    for(int o=1;o<64;o<<=1){
      t0 += __shfl_xor(t0,o,64); t1 += __shfl_xor(t1,o,64); t2 += __shfl_xor(t2,o,64);
      t3 += __shfl_xor(t3,o,64); t4 += __shfl_xor(t4,o,64);
    }
    const float pot = t0, varm = t1*(1.0f/DD), s2 = t2, se = t3, ms = t4/degf;

    float e0=0.f, e1=0.f;
    const float inv_se = 1.0f/se;
    for(int s=lane; s<dmax; s+=64){
      float v = Sval[w][s];
      float pp = expf(v)*inv_se;
      e0 -= pp*logf(pp + 1e-8f);
      float dv = v-ms; e1 += dv*dv;
    }
#pragma unroll
    for(int o=1;o<64;o<<=1){ e0 += __shfl_xor(e0,o,64); e1 += __shfl_xor(e1,o,64); }

    if(lane==0){
      o_te[i]  = sqi - pot/(degf + 1e-8f);
      o_ent[i] = e0;
      o_if[i]  = e1/(degf-1.0f);
      o_st[i]  = 1.0f/(1.0f + varm);
      o_cv[i]  = 1.0f - (s2 - ssq)/(degf*(degf-1.0f));
      deg_out[i] = degf;
    }
  } else {
    // ================= knng branch: pipelined swapped-operand MFMA Gram =================
    const int kid = (t/3)*2 + (t%3) - 1;           // 0..2047
    const int split = kid & (NSPLIT-1);
    const int strip = (kid >> 5)*4 + w;            // 0..255
    const int ibase = strip*16, j0 = split*JW;
    const int col = lane & 15, kg = lane >> 4;
    const int vo = col*DD + kg*8;
    const int myi = ibase + col;

    const _Float16* pih = xh + (size_t)ibase*DD + vo;
    const _Float16* pil = xl + (size_t)ibase*DD + vo;
    const half8 Ih0 = *(const half8*)(pih);
    const half8 Ih1 = *(const half8*)(pih+32);
    const half8 Il0 = *(const half8*)(pil);
    const half8 Il1 = *(const half8*)(pil+32);

    const _Float16* pjh = xh + (size_t)j0*DD + vo;
    const _Float16* pjl = xl + (size_t)j0*DD + vo;

#define LDT(J, SQ, T) { \
    const _Float16* ph_ = pjh + (T)*16*DD; \
    const _Float16* pl_ = pjl + (T)*16*DD; \
    J[0]=*(const half8*)ph_; J[1]=*(const half8*)(ph_+32); \
    J[2]=*(const half8*)pl_; J[3]=*(const half8*)(pl_+32); \
    SQ = *(const float4*)(sq + j0 + (T)*16 + kg*4); }

    u64 bA[5], bB[5];
#pragma unroll
    for(int k=0;k<5;k++){ bA[k]=~0ULL; bB[k]=~0ULL; }

    half8 JA[4]; float4 sqA;
    half8 JB[4]; float4 sqB;
    LDT(JA, sqA, 0);
    LDT(JB, sqB, 1);

#pragma unroll
    for(int tt=0; tt<8; tt+=2){
      procTile(JA, sqA, j0 + tt*16 + kg*4, myi, Ih0, Ih1, Il0, Il1, bA);
      if(tt+2<8) LDT(JA, sqA, tt+2);
      procTile(JB, sqB, j0 + (tt+1)*16 + kg*4, myi, Ih0, Ih1, Il0, Il1, bB);
      if(tt+3<8) LDT(JB, sqB, tt+3);
    }
#undef LDT

    u64 b[5];
    mergeLocal(bA, bB, b);
    mergeStage(b, 16);
    mergeStage(b, 32);

    if(kg==0){
#pragma unroll
      for(int k=0;k<5;k++)
        cand[((size_t)myi*NSPLIT + split)*5 + k] = b[k];
    }
  }
}

// ======== phase B: merge 32x5 u64 candidates per row + epilogue + o_sc ========
__global__ __launch_bounds__(256) void k_nnsel(
    const float* __restrict__ x, const u64* __restrict__ cand,
    const float* __restrict__ msum, const float* __restrict__ max_sq,
    const float* __restrict__ deg, const float* __restrict__ sq,
    float* __restrict__ o_eq, float* __restrict__ o_sc)
{
  const int w = threadIdx.x>>6, l = threadIdx.x&63;
  const int i = blockIdx.x*4 + w;
  const u64* cr = cand + (size_t)i*(NSPLIT*5);
  u64 c0 = cr[l];
  u64 c1 = cr[64+l];
  u64 c2 = (l < 32) ? cr[128+l] : ~0ULL;

  int sel[5];
#pragma unroll
  for(int k=0;k<5;k++){
    u64 d = umin64(c0, umin64(c1, c2));
#pragma unroll
    for(int o=1;o<64;o<<=1) d = umin64(d, sx64(d,o));
    sel[k] = (int)(unsigned)(d & 0xffffffffULL);
    if(c0==d) c0=~0ULL; else if(c1==d) c1=~0ULL; else if(c2==d) c2=~0ULL;
  }

  float smv=0.f;
#pragma unroll
  for(int k=0;k<5;k++) smv += x[(size_t)sel[k]*DD + l];
  float xiv = x[(size_t)i*DD + l];
  float lv = xiv - smv*0.2f;
  float gv = xiv - msum[l]*(1.0f/NN);
  float pl = lv*lv, pg = gv*gv;
#pragma unroll
  for(int o=1;o<64;o<<=1){ pl += __shfl_xor(pl,o,64); pg += __shfl_xor(pg,o,64); }
  if(l==0){
    o_eq[i] = 0.6f*sqrtf(pg) + 0.4f*sqrtf(pl);
    o_sc[i] = 0.5f*deg[i]/(float)(NN-1) + 0.5f*sqrtf(sq[i])/sqrtf(max_sq[0]);
  }
}

extern "C" void kernel_launch(void* const* d_in, const int* in_sizes, int n_in,
                              void* d_out, int out_size, void* d_ws, size_t ws_size,
                              hipStream_t stream) {
  const float* x = (const float*)d_in[0];
  const float* A = (const float*)d_in[1];
  float* out = (float*)d_out;
  float* ws  = (float*)d_ws;
  // ws layout (float offsets)
  float*     sq        = ws;                        // 0..4096
  float*     msum      = ws + 4096;                 // 64
  float*     max_sq    = ws + 4160;                 // 1
  float*     deg       = ws + 4224;                 // 4096
  float*     msum_part = ws + 8320;                 // 256*64
  float*     maxsq_part= ws + 24704;                // 256
  _Float16*  xh        = (_Float16*)(ws + 24960);   // 262144 halves
  _Float16*  xl        = (_Float16*)(ws + 156032);  // 262144 halves
  u64*       cand      = (u64*)(ws + 287104);       // 4096*32*5 u64

  k_prec<<<NN/16, 256, 0, stream>>>(x, sq, xh, xl, msum_part, maxsq_part);
  k_mega<<<3*NN/4 + 1, 256, 0, stream>>>(x, A, sq, xh, xl, cand,
                                         msum_part, maxsq_part, msum, max_sq, deg,
                                         out, out+NN, out+4*NN, out+5*NN, out+6*NN);
  k_nnsel<<<NN/4, 256, 0, stream>>>(x, cand, msum, max_sq, deg, sq,
                                    out+2*NN, out+3*NN);
}

// Round 11
// 71.704 us; speedup vs baseline: 5.6620x; 1.0289x over previous
//
#include <hip/hip_runtime.h>
#include <math.h>

#define NN 4096
#define DD 64
#define NSPLIT 64
#define JW 64

typedef _Float16 half8 __attribute__((ext_vector_type(8)));
typedef float f32x4 __attribute__((ext_vector_type(4)));

__device__ __forceinline__ unsigned sxu(unsigned v, int o){
  return (unsigned)__shfl_xor((int)v, o, 64);
}
__device__ __forceinline__ unsigned umn(unsigned a, unsigned b){ return a<b?a:b; }
__device__ __forceinline__ unsigned umx(unsigned a, unsigned b){ return a<b?b:a; }

// key = (quantized m << 12) | j ; m=sqj-2dot, q=(m+256)*2048 clamped to 20 bits
__device__ __forceinline__ unsigned packkey32(float m, int j){
  float q = fmaf(m, 2048.f, 524288.f);
  q = fminf(fmaxf(q, 0.f), 1048575.f);
  return (((unsigned)q) << 12) | (unsigned)j;
}

// branchless sorted-5 insert on u32 keys
__device__ __forceinline__ void ins5u(unsigned k, unsigned b[5]){
  bool c0=k<b[0], c1=k<b[1], c2=k<b[2], c3=k<b[3], c4=k<b[4];
  b[4] = c3 ? b[3] : (c4 ? k : b[4]);
  b[3] = c2 ? b[2] : (c3 ? k : b[3]);
  b[2] = c1 ? b[1] : (c2 ? k : b[2]);
  b[1] = c0 ? b[0] : (c1 ? k : b[1]);
  b[0] = c0 ? k : b[0];
}

// butterfly merge stage across lanes: sorted-5 + partner sorted-5 -> sorted-5
__device__ __forceinline__ void mergeStage32(unsigned b[5], int st){
  unsigned p0=sxu(b[0],st),p1=sxu(b[1],st),p2=sxu(b[2],st),p3=sxu(b[3],st),p4=sxu(b[4],st);
  unsigned o0=umn(b[0],p0);
  unsigned o1=umn(umn(b[1],p1), umx(b[0],p0));
  unsigned o2=umn(umn(b[2],p2), umn(umx(b[0],p1),umx(b[1],p0)));
  unsigned o3=umn(umn(b[3],p3), umn(umx(b[0],p2), umn(umx(b[1],p1),umx(b[2],p0))));
  unsigned o4=umn(umn(b[4],p4), umn(umn(umx(b[0],p3),umx(b[1],p2)),
                                    umn(umx(b[2],p1),umx(b[3],p0))));
  b[0]=o0;b[1]=o1;b[2]=o2;b[3]=o3;b[4]=o4;
}

// local merge of two sorted-5 lists -> sorted-5
__device__ __forceinline__ void mergeLocal32(const unsigned a[5], const unsigned c[5], unsigned b[5]){
  b[0]=umn(a[0],c[0]);
  b[1]=umn(umn(a[1],c[1]), umx(a[0],c[0]));
  b[2]=umn(umn(a[2],c[2]), umn(umx(a[0],c[1]),umx(a[1],c[0])));
  b[3]=umn(umn(a[3],c[3]), umn(umx(a[0],c[2]), umn(umx(a[1],c[1]),umx(a[2],c[0]))));
  b[4]=umn(umn(a[4],c[4]), umn(umn(umx(a[0],c[3]),umx(a[1],c[2])),
                               umn(umx(a[2],c[1]),umx(a[3],c[0]))));
}

// ---- fused pre: sq, split-f16 hi/lo, per-block partial colsum + max (NO atomics) ----
__global__ __launch_bounds__(256) void k_prec(const float* __restrict__ x,
                      float* __restrict__ sq,
                      _Float16* __restrict__ xh, _Float16* __restrict__ xl,
                      float* __restrict__ msum_part, float* __restrict__ maxsq_part){
  __shared__ float part[4][64];
  __shared__ float mxp[4];
  const int w = threadIdx.x>>6, lane = threadIdx.x&63;
  const int n0 = blockIdx.x*16 + w*4;
  float v0 = x[(size_t)(n0+0)*DD + lane];
  float v1 = x[(size_t)(n0+1)*DD + lane];
  float v2 = x[(size_t)(n0+2)*DD + lane];
  float v3 = x[(size_t)(n0+3)*DD + lane];
  float s0=v0*v0, s1=v1*v1, s2=v2*v2, s3=v3*v3;
#pragma unroll
  for(int o=1;o<64;o<<=1){
    s0 += __shfl_xor(s0,o,64); s1 += __shfl_xor(s1,o,64);
    s2 += __shfl_xor(s2,o,64); s3 += __shfl_xor(s3,o,64);
  }
  float vv[4] = {v0,v1,v2,v3};
  float ss[4] = {s0,s1,s2,s3};
#pragma unroll
  for(int q=0;q<4;q++){
    float v = vv[q];
    _Float16 h = (_Float16)v;
    _Float16 l = (_Float16)(v - (float)h);
    xh[(size_t)(n0+q)*DD+lane] = h;
    xl[(size_t)(n0+q)*DD+lane] = l;
    if(lane==0) sq[n0+q]=ss[q];
  }
  if(lane==0) mxp[w] = fmaxf(fmaxf(s0,s1), fmaxf(s2,s3));
  part[w][lane] = v0+v1+v2+v3; __syncthreads();
  if(w==0){
    msum_part[blockIdx.x*64 + lane] = part[0][lane]+part[1][lane]+part[2][lane]+part[3][lane];
    if(lane==0) maxsq_part[blockIdx.x] = fmaxf(fmaxf(mxp[0],mxp[1]), fmaxf(mxp[2],mxp[3]));
  }
}

__device__ __forceinline__ void procTile(const half8 J[4], float4 SQV, int jb0, int myi,
    half8 Ih0, half8 Ih1, half8 Il0, half8 Il1, unsigned b[5]){
  const f32x4 z = {0.f,0.f,0.f,0.f};
  f32x4 a1 = __builtin_amdgcn_mfma_f32_16x16x32_f16(J[0], Ih0, z, 0,0,0);
  f32x4 a2 = __builtin_amdgcn_mfma_f32_16x16x32_f16(J[2], Ih0, z, 0,0,0);
  a1 = __builtin_amdgcn_mfma_f32_16x16x32_f16(J[1], Ih1, a1, 0,0,0);
  a2 = __builtin_amdgcn_mfma_f32_16x16x32_f16(J[3], Ih1, a2, 0,0,0);
  a1 = __builtin_amdgcn_mfma_f32_16x16x32_f16(J[0], Il0, a1, 0,0,0);
  a1 = __builtin_amdgcn_mfma_f32_16x16x32_f16(J[1], Il1, a1, 0,0,0);
  float sqv[4] = {SQV.x,SQV.y,SQV.z,SQV.w};
#pragma unroll
  for(int r=0;r<4;r++){
    unsigned kk = packkey32(fmaf(-2.0f, a1[r]+a2[r], sqv[r]), jb0+r);
    kk = (jb0+r==myi) ? 0xFFFFFFFFu : kk;
    ins5u(kk, b);
  }
}

// ======== MEGA: bid0 = stats reduce; then 1/5 sparse, 4/5 MFMA kNN ========
__global__ __launch_bounds__(256, 4) void k_mega(
    const float* __restrict__ x, const float* __restrict__ A,
    const float* __restrict__ sq,
    const _Float16* __restrict__ xh, const _Float16* __restrict__ xl,
    unsigned* __restrict__ cand,
    const float* __restrict__ msum_part, const float* __restrict__ maxsq_part,
    float* __restrict__ msum, float* __restrict__ max_sq, float* __restrict__ deg_out,
    float* __restrict__ o_te, float* __restrict__ o_ent,
    float* __restrict__ o_if, float* __restrict__ o_st, float* __restrict__ o_cv)
{
  __shared__ int   nbr[4][128];
  __shared__ float Sval[4][128];
  __shared__ float rr[4][64];
  __shared__ float rm[4];
  const int bid = blockIdx.x;
  const int w = threadIdx.x>>6, lane = threadIdx.x&63;

  if(bid == 0){
    float s = 0.f;
    for(int p=w; p<256; p+=4) s += msum_part[p*64 + lane];
    rr[w][lane] = s;
    float m = maxsq_part[w*64 + lane];
#pragma unroll
    for(int o=1;o<64;o<<=1) m = fmaxf(m, __shfl_xor(m,o,64));
    if(lane==0) rm[w] = m;
    __syncthreads();
    if(w==0){
      msum[lane] = rr[0][lane]+rr[1][lane]+rr[2][lane]+rr[3][lane];
      if(lane==0) max_sq[0] = fmaxf(fmaxf(rm[0],rm[1]), fmaxf(rm[2],rm[3]));
    }
    return;
  }

  const int t = bid - 1;
  if(t % 5 == 0){
    // ================= sparse branch: wave per node =================
    const int i = (t/5)*4 + w;
    const float xid = x[(size_t)i*DD + lane];
    const float sqi = sq[i];
    const float eni = sqrtf(sqi);
    const float4* A4 = (const float4*)(A + (size_t)i*NN);

    float4 av[16];
#pragma unroll
    for(int q=0;q<16;q++) av[q] = A4[lane + 64*q];
    int c = 0;
#pragma unroll
    for(int q=0;q<16;q++)
      c += (av[q].x>0.f)+(av[q].y>0.f)+(av[q].z>0.f)+(av[q].w>0.f);
    int sc = c;
#pragma unroll
    for(int o=1;o<64;o<<=1){ int v=__shfl_up(sc,o,64); if(lane>=o) sc+=v; }
    const int deg = __shfl(sc, 63, 64);
    int off = sc - c;
#pragma unroll
    for(int q=0;q<16;q++){
      int jb = 4*(lane + 64*q);
      if(av[q].x>0.f){ if(off<128) nbr[w][off]=jb+0; off++; }
      if(av[q].y>0.f){ if(off<128) nbr[w][off]=jb+1; off++; }
      if(av[q].z>0.f){ if(off<128) nbr[w][off]=jb+2; off++; }
      if(av[q].w>0.f){ if(off<128) nbr[w][off]=jb+3; off++; }
    }

    const float degf = (float)deg;
    const int dmax = min(deg, 128);
    float nb_d=0.f, ex2_d=0.f, s_d=0.f, ssq=0.f;

    for(int c0=0; c0<dmax; c0+=8){
      int jq[8]; float aq[8], qq[8];
#pragma unroll
      for(int q=0;q<8;q++) jq[q] = nbr[w][min(c0+q, dmax-1)];
#pragma unroll
      for(int q=0;q<8;q++) aq[q] = x[(size_t)jq[q]*DD + lane];
#pragma unroll
      for(int q=0;q<8;q++) qq[q] = sq[jq[q]];
      float p[8];
#pragma unroll
      for(int q=0;q<8;q++) p[q] = xid*aq[q];
#pragma unroll
      for(int o=1;o<64;o<<=1){
#pragma unroll
        for(int q=0;q<8;q++) p[q] += __shfl_xor(p[q],o,64);
      }
#pragma unroll
      for(int q=0;q<8;q++){
        const bool valid = (c0+q) < deg;
        float c2 = fmaxf(sqi + qq[q] - 2.0f*p[q], 1e-12f);
        float inv = 1.0f/fmaxf(sqrtf(c2), 1e-8f);
        nb_d  += valid ? aq[q] : 0.f;
        ex2_d += valid ? aq[q]*aq[q] : 0.f;
        s_d   += valid ? (aq[q]-xid)*inv : 0.f;
        ssq   += valid ? c2*inv*inv : 0.f;
        if(valid && lane==q) Sval[w][c0+q] = p[q]/(eni*sqrtf(qq[q]));
      }
    }

    float t0 = xid*nb_d;
    float m1 = nb_d/degf;
    float t1 = (ex2_d - degf*m1*m1)/(degf-1.0f);
    float t2 = s_d*s_d;
    float t3 = 0.f, t4 = 0.f;
    for(int s=lane; s<dmax; s+=64){ float v=Sval[w][s]; t3 += expf(v); t4 += v; }
#pragma unroll
    for(int o=1;o<64;o<<=1){
      t0 += __shfl_xor(t0,o,64); t1 += __shfl_xor(t1,o,64); t2 += __shfl_xor(t2,o,64);
      t3 += __shfl_xor(t3,o,64); t4 += __shfl_xor(t4,o,64);
    }
    const float pot = t0, varm = t1*(1.0f/DD), s2 = t2, se = t3, ms = t4/degf;

    float e0=0.f, e1=0.f;
    const float inv_se = 1.0f/se;
    for(int s=lane; s<dmax; s+=64){
      float v = Sval[w][s];
      float pp = expf(v)*inv_se;
      e0 -= pp*logf(pp + 1e-8f);
      float dv = v-ms; e1 += dv*dv;
    }
#pragma unroll
    for(int o=1;o<64;o<<=1){ e0 += __shfl_xor(e0,o,64); e1 += __shfl_xor(e1,o,64); }

    if(lane==0){
      o_te[i]  = sqi - pot/(degf + 1e-8f);
      o_ent[i] = e0;
      o_if[i]  = e1/(degf-1.0f);
      o_st[i]  = 1.0f/(1.0f + varm);
      o_cv[i]  = 1.0f - (s2 - ssq)/(degf*(degf-1.0f));
      deg_out[i] = degf;
    }
  } else {
    // ================= knng branch: pipelined swapped-operand MFMA Gram =================
    const int kid = (t/5)*4 + (t%5) - 1;           // 0..4095
    const int split = kid & (NSPLIT-1);
    const int strip = (kid >> 6)*4 + w;            // 0..255
    const int ibase = strip*16, j0 = split*JW;
    const int col = lane & 15, kg = lane >> 4;
    const int vo = col*DD + kg*8;
    const int myi = ibase + col;

    const _Float16* pih = xh + (size_t)ibase*DD + vo;
    const _Float16* pil = xl + (size_t)ibase*DD + vo;
    const half8 Ih0 = *(const half8*)(pih);
    const half8 Ih1 = *(const half8*)(pih+32);
    const half8 Il0 = *(const half8*)(pil);
    const half8 Il1 = *(const half8*)(pil+32);

    const _Float16* pjh = xh + (size_t)j0*DD + vo;
    const _Float16* pjl = xl + (size_t)j0*DD + vo;

#define LDT(J, SQ, T) { \
    const _Float16* ph_ = pjh + (T)*16*DD; \
    const _Float16* pl_ = pjl + (T)*16*DD; \
    J[0]=*(const half8*)ph_; J[1]=*(const half8*)(ph_+32); \
    J[2]=*(const half8*)pl_; J[3]=*(const half8*)(pl_+32); \
    SQ = *(const float4*)(sq + j0 + (T)*16 + kg*4); }

    unsigned bA[5], bB[5];
#pragma unroll
    for(int k=0;k<5;k++){ bA[k]=0xFFFFFFFFu; bB[k]=0xFFFFFFFFu; }

    half8 JA[4]; float4 sqA;
    half8 JB[4]; float4 sqB;
    LDT(JA, sqA, 0);
    LDT(JB, sqB, 1);

    procTile(JA, sqA, j0 + 0*16 + kg*4, myi, Ih0, Ih1, Il0, Il1, bA);
    LDT(JA, sqA, 2);
    procTile(JB, sqB, j0 + 1*16 + kg*4, myi, Ih0, Ih1, Il0, Il1, bB);
    LDT(JB, sqB, 3);
    procTile(JA, sqA, j0 + 2*16 + kg*4, myi, Ih0, Ih1, Il0, Il1, bA);
    procTile(JB, sqB, j0 + 3*16 + kg*4, myi, Ih0, Ih1, Il0, Il1, bB);
#undef LDT

    unsigned b[5];
    mergeLocal32(bA, bB, b);
    mergeStage32(b, 16);
    mergeStage32(b, 32);

    if(kg==0){
#pragma unroll
      for(int k=0;k<5;k++)
        cand[((size_t)myi*NSPLIT + split)*5 + k] = b[k];
    }
  }
}

// ======== phase B: merge 64x5 u32 candidates per row + epilogue + o_sc ========
__global__ __launch_bounds__(256) void k_nnsel(
    const float* __restrict__ x, const unsigned* __restrict__ cand,
    const float* __restrict__ msum, const float* __restrict__ max_sq,
    const float* __restrict__ deg, const float* __restrict__ sq,
    float* __restrict__ o_eq, float* __restrict__ o_sc)
{
  const int w = threadIdx.x>>6, l = threadIdx.x&63;
  const int i = blockIdx.x*4 + w;
  const unsigned* cr = cand + (size_t)i*(NSPLIT*5);
  unsigned c0 = cr[l], c1 = cr[64+l], c2 = cr[128+l], c3 = cr[192+l], c4 = cr[256+l];

  int sel[5];
#pragma unroll
  for(int k=0;k<5;k++){
    unsigned d = umn(umn(umn(c0,c1),umn(c2,c3)),c4);
#pragma unroll
    for(int o=1;o<64;o<<=1) d = umn(d, sxu(d,o));
    sel[k] = (int)(d & 0xFFFu);
    if(c0==d) c0=0xFFFFFFFFu;
    else if(c1==d) c1=0xFFFFFFFFu;
    else if(c2==d) c2=0xFFFFFFFFu;
    else if(c3==d) c3=0xFFFFFFFFu;
    else if(c4==d) c4=0xFFFFFFFFu;
  }

  float smv=0.f;
#pragma unroll
  for(int k=0;k<5;k++) smv += x[(size_t)sel[k]*DD + l];
  float xiv = x[(size_t)i*DD + l];
  float lv = xiv - smv*0.2f;
  float gv = xiv - msum[l]*(1.0f/NN);
  float pl = lv*lv, pg = gv*gv;
#pragma unroll
  for(int o=1;o<64;o<<=1){ pl += __shfl_xor(pl,o,64); pg += __shfl_xor(pg,o,64); }
  if(l==0){
    o_eq[i] = 0.6f*sqrtf(pg) + 0.4f*sqrtf(pl);
    o_sc[i] = 0.5f*deg[i]/(float)(NN-1) + 0.5f*sqrtf(sq[i])/sqrtf(max_sq[0]);
  }
}

extern "C" void kernel_launch(void* const* d_in, const int* in_sizes, int n_in,
                              void* d_out, int out_size, void* d_ws, size_t ws_size,
                              hipStream_t stream) {
  const float* x = (const float*)d_in[0];
  const float* A = (const float*)d_in[1];
  float* out = (float*)d_out;
  float* ws  = (float*)d_ws;
  // ws layout (float offsets)
  float*     sq        = ws;                        // 0..4096
  float*     msum      = ws + 4096;                 // 64
  float*     max_sq    = ws + 4160;                 // 1 (pad to 4224)
  float*     deg       = ws + 4224;                 // 4096
  float*     msum_part = ws + 8320;                 // 256*64
  float*     maxsq_part= ws + 24704;                // 256
  _Float16*  xh        = (_Float16*)(ws + 24960);   // 262144 halves
  _Float16*  xl        = (_Float16*)(ws + 156032);  // 262144 halves
  unsigned*  cand      = (unsigned*)(ws + 287104);  // 4096*64*5 u32

  k_prec<<<NN/16, 256, 0, stream>>>(x, sq, xh, xl, msum_part, maxsq_part);
  // sparse: NN/4 = 1024 blocks (1:4 interleave) + knng: 256 strips/4 * 64 splits
  //         = 4096 blocks + 1 reducer  =>  5*NN/4 + 1 = 5121 blocks
  k_mega<<<5*NN/4 + 1, 256, 0, stream>>>(x, A, sq, xh, xl, cand,
                                         msum_part, maxsq_part, msum, max_sq, deg,
                                         out, out+NN, out+4*NN, out+5*NN, out+6*NN);
  k_nnsel<<<NN/4, 256, 0, stream>>>(x, cand, msum, max_sq, deg, sq,
                                    out+2*NN, out+3*NN);
}

// Round 13
// 58.813 us; speedup vs baseline: 6.9031x; 1.2192x over previous
//
#include <hip/hip_runtime.h>
#include <math.h>

#define NN 4096
#define DD 64
#define NSPLIT 64
#define JW 64

typedef _Float16 half8 __attribute__((ext_vector_type(8)));
typedef float f32x4 __attribute__((ext_vector_type(4)));

__device__ __forceinline__ unsigned sxu(unsigned v, int o){
  return (unsigned)__shfl_xor((int)v, o, 64);
}
__device__ __forceinline__ unsigned umn(unsigned a, unsigned b){ return a<b?a:b; }
__device__ __forceinline__ unsigned umx(unsigned a, unsigned b){ return a<b?b:a; }

// key = (quantized m << 12) | j ; m=sqj-2dot, q=(m+256)*2048 clamped to 20 bits
__device__ __forceinline__ unsigned packkey32(float m, int j){
  float q = fmaf(m, 2048.f, 524288.f);
  q = fminf(fmaxf(q, 0.f), 1048575.f);
  return (((unsigned)q) << 12) | (unsigned)j;
}

// branchless sorted-5 insert on u32 keys
__device__ __forceinline__ void ins5u(unsigned k, unsigned b[5]){
  bool c0=k<b[0], c1=k<b[1], c2=k<b[2], c3=k<b[3], c4=k<b[4];
  b[4] = c3 ? b[3] : (c4 ? k : b[4]);
  b[3] = c2 ? b[2] : (c3 ? k : b[3]);
  b[2] = c1 ? b[1] : (c2 ? k : b[2]);
  b[1] = c0 ? b[0] : (c1 ? k : b[1]);
  b[0] = c0 ? k : b[0];
}

// butterfly merge stage across lanes: sorted-5 + partner sorted-5 -> sorted-5
__device__ __forceinline__ void mergeStage32(unsigned b[5], int st){
  unsigned p0=sxu(b[0],st),p1=sxu(b[1],st),p2=sxu(b[2],st),p3=sxu(b[3],st),p4=sxu(b[4],st);
  unsigned o0=umn(b[0],p0);
  unsigned o1=umn(umn(b[1],p1), umx(b[0],p0));
  unsigned o2=umn(umn(b[2],p2), umn(umx(b[0],p1),umx(b[1],p0)));
  unsigned o3=umn(umn(b[3],p3), umn(umx(b[0],p2), umn(umx(b[1],p1),umx(b[2],p0))));
  unsigned o4=umn(umn(b[4],p4), umn(umn(umx(b[0],p3),umx(b[1],p2)),
                                    umn(umx(b[2],p1),umx(b[3],p0))));
  b[0]=o0;b[1]=o1;b[2]=o2;b[3]=o3;b[4]=o4;
}

// local merge of two sorted-5 lists -> sorted-5
__device__ __forceinline__ void mergeLocal32(const unsigned a[5], const unsigned c[5], unsigned b[5]){
  b[0]=umn(a[0],c[0]);
  b[1]=umn(umn(a[1],c[1]), umx(a[0],c[0]));
  b[2]=umn(umn(a[2],c[2]), umn(umx(a[0],c[1]),umx(a[1],c[0])));
  b[3]=umn(umn(a[3],c[3]), umn(umx(a[0],c[2]), umn(umx(a[1],c[1]),umx(a[2],c[0]))));
  b[4]=umn(umn(a[4],c[4]), umn(umn(umx(a[0],c[3]),umx(a[1],c[2])),
                               umn(umx(a[2],c[1]),umx(a[3],c[0]))));
}

// ---- fused pre: sq, split-f16 hi/lo, per-block partial colsum + max (NO atomics) ----
__global__ __launch_bounds__(256) void k_prec(const float* __restrict__ x,
                      float* __restrict__ sq,
                      _Float16* __restrict__ xh, _Float16* __restrict__ xl,
                      float* __restrict__ msum_part, float* __restrict__ maxsq_part){
  __shared__ float part[4][64];
  __shared__ float mxp[4];
  const int w = threadIdx.x>>6, lane = threadIdx.x&63;
  const int n0 = blockIdx.x*16 + w*4;
  float v0 = x[(size_t)(n0+0)*DD + lane];
  float v1 = x[(size_t)(n0+1)*DD + lane];
  float v2 = x[(size_t)(n0+2)*DD + lane];
  float v3 = x[(size_t)(n0+3)*DD + lane];
  float s0=v0*v0, s1=v1*v1, s2=v2*v2, s3=v3*v3;
#pragma unroll
  for(int o=1;o<64;o<<=1){
    s0 += __shfl_xor(s0,o,64); s1 += __shfl_xor(s1,o,64);
    s2 += __shfl_xor(s2,o,64); s3 += __shfl_xor(s3,o,64);
  }
  float vv[4] = {v0,v1,v2,v3};
  float ss[4] = {s0,s1,s2,s3};
#pragma unroll
  for(int q=0;q<4;q++){
    float v = vv[q];
    _Float16 h = (_Float16)v;
    _Float16 l = (_Float16)(v - (float)h);
    xh[(size_t)(n0+q)*DD+lane] = h;
    xl[(size_t)(n0+q)*DD+lane] = l;
    if(lane==0) sq[n0+q]=ss[q];
  }
  if(lane==0) mxp[w] = fmaxf(fmaxf(s0,s1), fmaxf(s2,s3));
  part[w][lane] = v0+v1+v2+v3; __syncthreads();
  if(w==0){
    msum_part[blockIdx.x*64 + lane] = part[0][lane]+part[1][lane]+part[2][lane]+part[3][lane];
    if(lane==0) maxsq_part[blockIdx.x] = fmaxf(fmaxf(mxp[0],mxp[1]), fmaxf(mxp[2],mxp[3]));
  }
}

// 6-MFMA split-f16 Gram for one 16x16 tile: returns row-dots for this lane
__device__ __forceinline__ f32x4 gram6(const half8 J[4],
    half8 Ih0, half8 Ih1, half8 Il0, half8 Il1){
  const f32x4 z = {0.f,0.f,0.f,0.f};
  f32x4 a1 = __builtin_amdgcn_mfma_f32_16x16x32_f16(J[0], Ih0, z, 0,0,0);
  f32x4 a2 = __builtin_amdgcn_mfma_f32_16x16x32_f16(J[2], Ih0, z, 0,0,0);
  a1 = __builtin_amdgcn_mfma_f32_16x16x32_f16(J[1], Ih1, a1, 0,0,0);
  a2 = __builtin_amdgcn_mfma_f32_16x16x32_f16(J[3], Ih1, a2, 0,0,0);
  a1 = __builtin_amdgcn_mfma_f32_16x16x32_f16(J[0], Il0, a1, 0,0,0);
  a1 = __builtin_amdgcn_mfma_f32_16x16x32_f16(J[1], Il1, a1, 0,0,0);
  return a1 + a2;
}

// ======== MEGA: bid0 = stats reduce; then 1/5 sparse, 4/5 MFMA kNN ========
__global__ __launch_bounds__(256, 4) void k_mega(
    const float* __restrict__ x, const float* __restrict__ A,
    const float* __restrict__ sq,
    const _Float16* __restrict__ xh, const _Float16* __restrict__ xl,
    unsigned* __restrict__ cand,
    const float* __restrict__ msum_part, const float* __restrict__ maxsq_part,
    float* __restrict__ msum, float* __restrict__ max_sq, float* __restrict__ deg_out,
    float* __restrict__ o_te, float* __restrict__ o_ent,
    float* __restrict__ o_if, float* __restrict__ o_st, float* __restrict__ o_cv)
{
  __shared__ int   nbr[4][128];
  __shared__ float Sval[4][128];
  __shared__ float rr[4][64];
  __shared__ float rm[4];
  __shared__ _Float16 jHi[512*8];   // 64 j-rows x 8 granules (16B), swizzled
  __shared__ _Float16 jLo[512*8];
  const int bid = blockIdx.x;
  const int tid = threadIdx.x;
  const int w = tid>>6, lane = tid&63;

  if(bid == 0){
    float s = 0.f;
    for(int p=w; p<256; p+=4) s += msum_part[p*64 + lane];
    rr[w][lane] = s;
    float m = maxsq_part[w*64 + lane];
#pragma unroll
    for(int o=1;o<64;o<<=1) m = fmaxf(m, __shfl_xor(m,o,64));
    if(lane==0) rm[w] = m;
    __syncthreads();
    if(w==0){
      msum[lane] = rr[0][lane]+rr[1][lane]+rr[2][lane]+rr[3][lane];
      if(lane==0) max_sq[0] = fmaxf(fmaxf(rm[0],rm[1]), fmaxf(rm[2],rm[3]));
    }
    return;
  }

  const int t = bid - 1;
  if(t % 5 == 0){
    // ================= sparse branch: wave per node, 4-chunk A scan =================
    const int i = (t/5)*4 + w;
    const float xid = x[(size_t)i*DD + lane];
    const float sqi = sq[i];
    const float eni = sqrtf(sqi);
    const float4* A4 = (const float4*)(A + (size_t)i*NN);

    int deg = 0;
    for(int ch=0; ch<4; ++ch){
      float4 av[4];
#pragma unroll
      for(int qq=0; qq<4; ++qq) av[qq] = A4[lane + 64*(ch*4+qq)];
      int c = 0;
#pragma unroll
      for(int qq=0; qq<4; ++qq)
        c += (av[qq].x>0.f)+(av[qq].y>0.f)+(av[qq].z>0.f)+(av[qq].w>0.f);
      int sc = c;
#pragma unroll
      for(int o=1;o<64;o<<=1){ int v=__shfl_up(sc,o,64); if(lane>=o) sc+=v; }
      int off = deg + sc - c;
#pragma unroll
      for(int qq=0; qq<4; ++qq){
        int jb = 4*(lane + 64*(ch*4+qq));
        if(av[qq].x>0.f){ if(off<128) nbr[w][off]=jb+0; off++; }
        if(av[qq].y>0.f){ if(off<128) nbr[w][off]=jb+1; off++; }
        if(av[qq].z>0.f){ if(off<128) nbr[w][off]=jb+2; off++; }
        if(av[qq].w>0.f){ if(off<128) nbr[w][off]=jb+3; off++; }
      }
      deg += __shfl(sc, 63, 64);
    }

    const float degf = (float)deg;
    const int dmax = min(deg, 128);
    float nb_d=0.f, ex2_d=0.f, s_d=0.f, ssq=0.f;

    for(int c0=0; c0<dmax; c0+=8){
      int jq[8]; float aq[8], qq[8];
#pragma unroll
      for(int q=0;q<8;q++) jq[q] = nbr[w][min(c0+q, dmax-1)];
#pragma unroll
      for(int q=0;q<8;q++) aq[q] = x[(size_t)jq[q]*DD + lane];
#pragma unroll
      for(int q=0;q<8;q++) qq[q] = sq[jq[q]];
      asm volatile("" :: "v"(aq[0]), "v"(aq[1]), "v"(aq[2]), "v"(aq[3]),
                         "v"(aq[4]), "v"(aq[5]), "v"(aq[6]), "v"(aq[7]));
      float p[8];
#pragma unroll
      for(int q=0;q<8;q++) p[q] = xid*aq[q];
#pragma unroll
      for(int o=1;o<64;o<<=1){
#pragma unroll
        for(int q=0;q<8;q++) p[q] += __shfl_xor(p[q],o,64);
      }
#pragma unroll
      for(int q=0;q<8;q++){
        const bool valid = (c0+q) < deg;
        float c2 = fmaxf(sqi + qq[q] - 2.0f*p[q], 1e-12f);
        float inv = 1.0f/fmaxf(sqrtf(c2), 1e-8f);
        nb_d  += valid ? aq[q] : 0.f;
        ex2_d += valid ? aq[q]*aq[q] : 0.f;
        s_d   += valid ? (aq[q]-xid)*inv : 0.f;
        ssq   += valid ? c2*inv*inv : 0.f;
        if(valid && lane==q) Sval[w][c0+q] = p[q]/(eni*sqrtf(qq[q]));
      }
    }

    float t0 = xid*nb_d;
    float m1 = nb_d/degf;
    float t1 = (ex2_d - degf*m1*m1)/(degf-1.0f);
    float t2 = s_d*s_d;
    float t3 = 0.f, t4 = 0.f;
    for(int s=lane; s<dmax; s+=64){ float v=Sval[w][s]; t3 += expf(v); t4 += v; }
#pragma unroll
    for(int o=1;o<64;o<<=1){
      t0 += __shfl_xor(t0,o,64); t1 += __shfl_xor(t1,o,64); t2 += __shfl_xor(t2,o,64);
      t3 += __shfl_xor(t3,o,64); t4 += __shfl_xor(t4,o,64);
    }
    const float pot = t0, varm = t1*(1.0f/DD), s2 = t2, se = t3, ms = t4/degf;

    float e0=0.f, e1=0.f;
    const float inv_se = 1.0f/se;
    for(int s=lane; s<dmax; s+=64){
      float v = Sval[w][s];
      float pp = expf(v)*inv_se;
      e0 -= pp*logf(pp + 1e-8f);
      float dv = v-ms; e1 += dv*dv;
    }
#pragma unroll
    for(int o=1;o<64;o<<=1){ e0 += __shfl_xor(e0,o,64); e1 += __shfl_xor(e1,o,64); }

    if(lane==0){
      o_te[i]  = sqi - pot/(degf + 1e-8f);
      o_ent[i] = e0;
      o_if[i]  = e1/(degf-1.0f);
      o_st[i]  = 1.0f/(1.0f + varm);
      o_cv[i]  = 1.0f - (s2 - ssq)/(degf*(degf-1.0f));
      deg_out[i] = degf;
    }
  } else {
    // ========== knng branch: LDS-staged J (async, swizzled) + 8 MFMA chains ==========
    const int kid = (t/5)*4 + (t%5) - 1;           // 0..4095
    const int split = kid & (NSPLIT-1);
    const int strip = (kid >> 6)*4 + w;            // 0..255
    const int ibase = strip*16, j0 = split*JW;
    const int col = lane & 15, kg = lane >> 4;
    const int vo = col*DD + kg*8;
    const int myi = ibase + col;

    // async-stage J hi/lo into LDS; dest linear in thread order (wave-uniform
    // base + lane*16), source pre-swizzled: granule g holds (row=g>>3,
    // chunk=(g&7)^(row&7)) so reads XOR the same way (bank-spread).
#pragma unroll
    for(int q=0;q<2;q++){
      int g = q*256 + tid;
      int r = g >> 3;
      int c = (g & 7) ^ (r & 7);
      const _Float16* srcH = xh + (size_t)(j0 + r)*DD + c*8;
      const _Float16* srcL = xl + (size_t)(j0 + r)*DD + c*8;
      __builtin_amdgcn_global_load_lds(
        (const __attribute__((address_space(1))) unsigned int*)srcH,
        (__attribute__((address_space(3))) unsigned int*)(jHi + g*8), 16, 0, 0);
      __builtin_amdgcn_global_load_lds(
        (const __attribute__((address_space(1))) unsigned int*)srcL,
        (__attribute__((address_space(3))) unsigned int*)(jLo + g*8), 16, 0, 0);
    }

    // I-fragments from global (overlap with async staging)
    const _Float16* pih = xh + (size_t)ibase*DD + vo;
    const _Float16* pil = xl + (size_t)ibase*DD + vo;
    const half8 Ih0 = *(const half8*)(pih);
    const half8 Ih1 = *(const half8*)(pih+32);
    const half8 Il0 = *(const half8*)(pil);
    const half8 Il1 = *(const half8*)(pil+32);

    const int jb0 = j0 + kg*4;
    float4 sq0 = *(const float4*)(sq + jb0);
    float4 sq1 = *(const float4*)(sq + jb0 + 16);
    float4 sq2 = *(const float4*)(sq + jb0 + 32);
    float4 sq3 = *(const float4*)(sq + jb0 + 48);

    __syncthreads();   // staging complete

    // read the 4 j-tiles from LDS (swizzled granules)
    half8 JT[4][4];
#pragma unroll
    for(int tt=0; tt<4; tt++){
      const int rl = tt*16 + col;
      const int sw = rl & 7;
      JT[tt][0] = *(const half8*)(jHi + (rl*8 + ( kg      ^ sw))*8);
      JT[tt][1] = *(const half8*)(jHi + (rl*8 + ((kg + 4) ^ sw))*8);
      JT[tt][2] = *(const half8*)(jLo + (rl*8 + ( kg      ^ sw))*8);
      JT[tt][3] = *(const half8*)(jLo + (rl*8 + ((kg + 4) ^ sw))*8);
    }

    f32x4 d0 = gram6(JT[0], Ih0, Ih1, Il0, Il1);
    f32x4 d1 = gram6(JT[1], Ih0, Ih1, Il0, Il1);
    f32x4 d2 = gram6(JT[2], Ih0, Ih1, Il0, Il1);
    f32x4 d3 = gram6(JT[3], Ih0, Ih1, Il0, Il1);

    unsigned bA[5], bB[5];
#pragma unroll
    for(int k=0;k<5;k++){ bA[k]=0xFFFFFFFFu; bB[k]=0xFFFFFFFFu; }

    {
      float s0v[4]={sq0.x,sq0.y,sq0.z,sq0.w};
      float s2v[4]={sq2.x,sq2.y,sq2.z,sq2.w};
#pragma unroll
      for(int r=0;r<4;r++){
        unsigned k0 = packkey32(fmaf(-2.0f, d0[r], s0v[r]), jb0+r);
        k0 = (jb0+r==myi) ? 0xFFFFFFFFu : k0;
        ins5u(k0, bA);
        unsigned k2 = packkey32(fmaf(-2.0f, d2[r], s2v[r]), jb0+32+r);
        k2 = (jb0+32+r==myi) ? 0xFFFFFFFFu : k2;
        ins5u(k2, bA);
      }
    }
    {
      float s1v[4]={sq1.x,sq1.y,sq1.z,sq1.w};
      float s3v[4]={sq3.x,sq3.y,sq3.z,sq3.w};
#pragma unroll
      for(int r=0;r<4;r++){
        unsigned k1 = packkey32(fmaf(-2.0f, d1[r], s1v[r]), jb0+16+r);
        k1 = (jb0+16+r==myi) ? 0xFFFFFFFFu : k1;
        ins5u(k1, bB);
        unsigned k3 = packkey32(fmaf(-2.0f, d3[r], s3v[r]), jb0+48+r);
        k3 = (jb0+48+r==myi) ? 0xFFFFFFFFu : k3;
        ins5u(k3, bB);
      }
    }

    unsigned b[5];
    mergeLocal32(bA, bB, b);
    mergeStage32(b, 16);
    mergeStage32(b, 32);

    if(kg==0){
#pragma unroll
      for(int k=0;k<5;k++)
        cand[((size_t)myi*NSPLIT + split)*5 + k] = b[k];
    }
  }
}

// ======== phase B: merge 64x5 u32 candidates per row + epilogue + o_sc ========
__global__ __launch_bounds__(256) void k_nnsel(
    const float* __restrict__ x, const unsigned* __restrict__ cand,
    const float* __restrict__ msum, const float* __restrict__ max_sq,
    const float* __restrict__ deg, const float* __restrict__ sq,
    float* __restrict__ o_eq, float* __restrict__ o_sc)
{
  const int w = threadIdx.x>>6, l = threadIdx.x&63;
  const int i = blockIdx.x*4 + w;
  const unsigned* cr = cand + (size_t)i*(NSPLIT*5);
  unsigned c0 = cr[l], c1 = cr[64+l], c2 = cr[128+l], c3 = cr[192+l], c4 = cr[256+l];

  int sel[5];
#pragma unroll
  for(int k=0;k<5;k++){
    unsigned d = umn(umn(umn(c0,c1),umn(c2,c3)),c4);
#pragma unroll
    for(int o=1;o<64;o<<=1) d = umn(d, sxu(d,o));
    sel[k] = (int)(d & 0xFFFu);
    if(c0==d) c0=0xFFFFFFFFu;
    else if(c1==d) c1=0xFFFFFFFFu;
    else if(c2==d) c2=0xFFFFFFFFu;
    else if(c3==d) c3=0xFFFFFFFFu;
    else if(c4==d) c4=0xFFFFFFFFu;
  }

  float smv=0.f;
#pragma unroll
  for(int k=0;k<5;k++) smv += x[(size_t)sel[k]*DD + l];
  float xiv = x[(size_t)i*DD + l];
  float lv = xiv - smv*0.2f;
  float gv = xiv - msum[l]*(1.0f/NN);
  float pl = lv*lv, pg = gv*gv;
#pragma unroll
  for(int o=1;o<64;o<<=1){ pl += __shfl_xor(pl,o,64); pg += __shfl_xor(pg,o,64); }
  if(l==0){
    o_eq[i] = 0.6f*sqrtf(pg) + 0.4f*sqrtf(pl);
    o_sc[i] = 0.5f*deg[i]/(float)(NN-1) + 0.5f*sqrtf(sq[i])/sqrtf(max_sq[0]);
  }
}

extern "C" void kernel_launch(void* const* d_in, const int* in_sizes, int n_in,
                              void* d_out, int out_size, void* d_ws, size_t ws_size,
                              hipStream_t stream) {
  const float* x = (const float*)d_in[0];
  const float* A = (const float*)d_in[1];
  float* out = (float*)d_out;
  float* ws  = (float*)d_ws;
  // ws layout (float offsets)
  float*     sq        = ws;                        // 0..4096
  float*     msum      = ws + 4096;                 // 64
  float*     max_sq    = ws + 4160;                 // 1 (pad to 4224)
  float*     deg       = ws + 4224;                 // 4096
  float*     msum_part = ws + 8320;                 // 256*64
  float*     maxsq_part= ws + 24704;                // 256
  _Float16*  xh        = (_Float16*)(ws + 24960);   // 262144 halves
  _Float16*  xl        = (_Float16*)(ws + 156032);  // 262144 halves
  unsigned*  cand      = (unsigned*)(ws + 287104);  // 4096*64*5 u32

  k_prec<<<NN/16, 256, 0, stream>>>(x, sq, xh, xl, msum_part, maxsq_part);
  // sparse: NN/4 = 1024 blocks (1:4 interleave) + knng: 4096 blocks + 1 reducer
  k_mega<<<5*NN/4 + 1, 256, 0, stream>>>(x, A, sq, xh, xl, cand,
                                         msum_part, maxsq_part, msum, max_sq, deg,
                                         out, out+NN, out+4*NN, out+5*NN, out+6*NN);
  k_nnsel<<<NN/4, 256, 0, stream>>>(x, cand, msum, max_sq, deg, sq,
                                    out+2*NN, out+3*NN);
}

// Round 14
// 56.974 us; speedup vs baseline: 7.1260x; 1.0323x over previous
//
#include <hip/hip_runtime.h>
#include <math.h>

#define NN 4096
#define DD 64
#define NSPLIT 16
#define JW 256

typedef _Float16 half8 __attribute__((ext_vector_type(8)));
typedef float f32x4 __attribute__((ext_vector_type(4)));

__device__ __forceinline__ unsigned sxu(unsigned v, int o){
  return (unsigned)__shfl_xor((int)v, o, 64);
}
__device__ __forceinline__ unsigned umn(unsigned a, unsigned b){ return a<b?a:b; }
__device__ __forceinline__ unsigned umx(unsigned a, unsigned b){ return a<b?b:a; }

// key = (quantized m << 12) | j ; m=sqj-2dot, q=(m+256)*2048 clamped to 20 bits
__device__ __forceinline__ unsigned packkey32(float m, int j){
  float q = fmaf(m, 2048.f, 524288.f);
  q = fminf(fmaxf(q, 0.f), 1048575.f);
  return (((unsigned)q) << 12) | (unsigned)j;
}

// branchless sorted-5 insert on u32 keys
__device__ __forceinline__ void ins5u(unsigned k, unsigned b[5]){
  bool c0=k<b[0], c1=k<b[1], c2=k<b[2], c3=k<b[3], c4=k<b[4];
  b[4] = c3 ? b[3] : (c4 ? k : b[4]);
  b[3] = c2 ? b[2] : (c3 ? k : b[3]);
  b[2] = c1 ? b[1] : (c2 ? k : b[2]);
  b[1] = c0 ? b[0] : (c1 ? k : b[1]);
  b[0] = c0 ? k : b[0];
}

// butterfly merge stage across lanes: sorted-5 + partner sorted-5 -> sorted-5
__device__ __forceinline__ void mergeStage32(unsigned b[5], int st){
  unsigned p0=sxu(b[0],st),p1=sxu(b[1],st),p2=sxu(b[2],st),p3=sxu(b[3],st),p4=sxu(b[4],st);
  unsigned o0=umn(b[0],p0);
  unsigned o1=umn(umn(b[1],p1), umx(b[0],p0));
  unsigned o2=umn(umn(b[2],p2), umn(umx(b[0],p1),umx(b[1],p0)));
  unsigned o3=umn(umn(b[3],p3), umn(umx(b[0],p2), umn(umx(b[1],p1),umx(b[2],p0))));
  unsigned o4=umn(umn(b[4],p4), umn(umn(umx(b[0],p3),umx(b[1],p2)),
                                    umn(umx(b[2],p1),umx(b[3],p0))));
  b[0]=o0;b[1]=o1;b[2]=o2;b[3]=o3;b[4]=o4;
}

// local merge of two sorted-5 lists -> sorted-5
__device__ __forceinline__ void mergeLocal32(const unsigned a[5], const unsigned c[5], unsigned b[5]){
  b[0]=umn(a[0],c[0]);
  b[1]=umn(umn(a[1],c[1]), umx(a[0],c[0]));
  b[2]=umn(umn(a[2],c[2]), umn(umx(a[0],c[1]),umx(a[1],c[0])));
  b[3]=umn(umn(a[3],c[3]), umn(umx(a[0],c[2]), umn(umx(a[1],c[1]),umx(a[2],c[0]))));
  b[4]=umn(umn(a[4],c[4]), umn(umn(umx(a[0],c[3]),umx(a[1],c[2])),
                               umn(umx(a[2],c[1]),umx(a[3],c[0]))));
}

// ---- fused pre: sq, split-f16 hi/lo, per-block partial colsum + max (NO atomics) ----
__global__ __launch_bounds__(256) void k_prec(const float* __restrict__ x,
                      float* __restrict__ sq,
                      _Float16* __restrict__ xh, _Float16* __restrict__ xl,
                      float* __restrict__ msum_part, float* __restrict__ maxsq_part){
  __shared__ float part[4][64];
  __shared__ float mxp[4];
  const int w = threadIdx.x>>6, lane = threadIdx.x&63;
  const int n0 = blockIdx.x*16 + w*4;
  float v0 = x[(size_t)(n0+0)*DD + lane];
  float v1 = x[(size_t)(n0+1)*DD + lane];
  float v2 = x[(size_t)(n0+2)*DD + lane];
  float v3 = x[(size_t)(n0+3)*DD + lane];
  float s0=v0*v0, s1=v1*v1, s2=v2*v2, s3=v3*v3;
#pragma unroll
  for(int o=1;o<64;o<<=1){
    s0 += __shfl_xor(s0,o,64); s1 += __shfl_xor(s1,o,64);
    s2 += __shfl_xor(s2,o,64); s3 += __shfl_xor(s3,o,64);
  }
  float vv[4] = {v0,v1,v2,v3};
  float ss[4] = {s0,s1,s2,s3};
#pragma unroll
  for(int q=0;q<4;q++){
    float v = vv[q];
    _Float16 h = (_Float16)v;
    _Float16 l = (_Float16)(v - (float)h);
    xh[(size_t)(n0+q)*DD+lane] = h;
    xl[(size_t)(n0+q)*DD+lane] = l;
    if(lane==0) sq[n0+q]=ss[q];
  }
  if(lane==0) mxp[w] = fmaxf(fmaxf(s0,s1), fmaxf(s2,s3));
  part[w][lane] = v0+v1+v2+v3; __syncthreads();
  if(w==0){
    msum_part[blockIdx.x*64 + lane] = part[0][lane]+part[1][lane]+part[2][lane]+part[3][lane];
    if(lane==0) maxsq_part[blockIdx.x] = fmaxf(fmaxf(mxp[0],mxp[1]), fmaxf(mxp[2],mxp[3]));
  }
}

// 6-MFMA split-f16 Gram for one 16x16 tile: returns row-dots for this lane
__device__ __forceinline__ f32x4 gram6(const half8 J[4],
    half8 Ih0, half8 Ih1, half8 Il0, half8 Il1){
  const f32x4 z = {0.f,0.f,0.f,0.f};
  f32x4 a1 = __builtin_amdgcn_mfma_f32_16x16x32_f16(J[0], Ih0, z, 0,0,0);
  f32x4 a2 = __builtin_amdgcn_mfma_f32_16x16x32_f16(J[2], Ih0, z, 0,0,0);
  a1 = __builtin_amdgcn_mfma_f32_16x16x32_f16(J[1], Ih1, a1, 0,0,0);
  a2 = __builtin_amdgcn_mfma_f32_16x16x32_f16(J[3], Ih1, a2, 0,0,0);
  a1 = __builtin_amdgcn_mfma_f32_16x16x32_f16(J[0], Il0, a1, 0,0,0);
  a1 = __builtin_amdgcn_mfma_f32_16x16x32_f16(J[1], Il1, a1, 0,0,0);
  return a1 + a2;
}

// ======== MEGA: bid0 = stats reduce; then 1/2 sparse, 1/2 MFMA kNN ========
__global__ __launch_bounds__(256, 4) void k_mega(
    const float* __restrict__ x, const float* __restrict__ A,
    const float* __restrict__ sq,
    const _Float16* __restrict__ xh, const _Float16* __restrict__ xl,
    unsigned* __restrict__ cand,
    const float* __restrict__ msum_part, const float* __restrict__ maxsq_part,
    float* __restrict__ msum, float* __restrict__ max_sq, float* __restrict__ deg_out,
    float* __restrict__ o_te, float* __restrict__ o_ent,
    float* __restrict__ o_if, float* __restrict__ o_st, float* __restrict__ o_cv)
{
  __shared__ int   nbr[4][128];
  __shared__ float Sval[4][128];
  __shared__ float rr[4][64];
  __shared__ float rm[4];
  __shared__ _Float16 jHi[2][512*8];   // dbuf: 64 j-rows x 8 granules, swizzled
  __shared__ _Float16 jLo[2][512*8];
  const int bid = blockIdx.x;
  const int tid = threadIdx.x;
  const int w = tid>>6, lane = tid&63;

  if(bid == 0){
    float s = 0.f;
    for(int p=w; p<256; p+=4) s += msum_part[p*64 + lane];
    rr[w][lane] = s;
    float m = maxsq_part[w*64 + lane];
#pragma unroll
    for(int o=1;o<64;o<<=1) m = fmaxf(m, __shfl_xor(m,o,64));
    if(lane==0) rm[w] = m;
    __syncthreads();
    if(w==0){
      msum[lane] = rr[0][lane]+rr[1][lane]+rr[2][lane]+rr[3][lane];
      if(lane==0) max_sq[0] = fmaxf(fmaxf(rm[0],rm[1]), fmaxf(rm[2],rm[3]));
    }
    return;
  }

  const int t = bid - 1;
  if((t & 1) == 0){
    // ================= sparse branch: wave per node, 4-chunk A scan =================
    const int i = (t>>1)*4 + w;
    const float xid = x[(size_t)i*DD + lane];
    const float sqi = sq[i];
    const float eni = sqrtf(sqi);
    const float4* A4 = (const float4*)(A + (size_t)i*NN);

    int deg = 0;
    for(int ch=0; ch<4; ++ch){
      float4 av[4];
#pragma unroll
      for(int qq=0; qq<4; ++qq) av[qq] = A4[lane + 64*(ch*4+qq)];
      int c = 0;
#pragma unroll
      for(int qq=0; qq<4; ++qq)
        c += (av[qq].x>0.f)+(av[qq].y>0.f)+(av[qq].z>0.f)+(av[qq].w>0.f);
      int sc = c;
#pragma unroll
      for(int o=1;o<64;o<<=1){ int v=__shfl_up(sc,o,64); if(lane>=o) sc+=v; }
      int off = deg + sc - c;
#pragma unroll
      for(int qq=0; qq<4; ++qq){
        int jb = 4*(lane + 64*(ch*4+qq));
        if(av[qq].x>0.f){ if(off<128) nbr[w][off]=jb+0; off++; }
        if(av[qq].y>0.f){ if(off<128) nbr[w][off]=jb+1; off++; }
        if(av[qq].z>0.f){ if(off<128) nbr[w][off]=jb+2; off++; }
        if(av[qq].w>0.f){ if(off<128) nbr[w][off]=jb+3; off++; }
      }
      deg += __shfl(sc, 63, 64);
    }

    const float degf = (float)deg;
    const int dmax = min(deg, 128);
    float nb_d=0.f, ex2_d=0.f, s_d=0.f, ssq=0.f;

    for(int c0=0; c0<dmax; c0+=8){
      int jq[8]; float aq[8], qq[8];
#pragma unroll
      for(int q=0;q<8;q++) jq[q] = nbr[w][min(c0+q, dmax-1)];
#pragma unroll
      for(int q=0;q<8;q++) aq[q] = x[(size_t)jq[q]*DD + lane];
#pragma unroll
      for(int q=0;q<8;q++) qq[q] = sq[jq[q]];
      asm volatile("" :: "v"(aq[0]), "v"(aq[1]), "v"(aq[2]), "v"(aq[3]),
                         "v"(aq[4]), "v"(aq[5]), "v"(aq[6]), "v"(aq[7]));
      float p[8];
#pragma unroll
      for(int q=0;q<8;q++) p[q] = xid*aq[q];
#pragma unroll
      for(int o=1;o<64;o<<=1){
#pragma unroll
        for(int q=0;q<8;q++) p[q] += __shfl_xor(p[q],o,64);
      }
#pragma unroll
      for(int q=0;q<8;q++){
        const bool valid = (c0+q) < deg;
        float c2 = fmaxf(sqi + qq[q] - 2.0f*p[q], 1e-12f);
        float inv = 1.0f/fmaxf(sqrtf(c2), 1e-8f);
        nb_d  += valid ? aq[q] : 0.f;
        ex2_d += valid ? aq[q]*aq[q] : 0.f;
        s_d   += valid ? (aq[q]-xid)*inv : 0.f;
        ssq   += valid ? c2*inv*inv : 0.f;
        if(valid && lane==q) Sval[w][c0+q] = p[q]/(eni*sqrtf(qq[q]));
      }
    }

    float t0 = xid*nb_d;
    float m1 = nb_d/degf;
    float t1 = (ex2_d - degf*m1*m1)/(degf-1.0f);
    float t2 = s_d*s_d;
    float t3 = 0.f, t4 = 0.f;
    for(int s=lane; s<dmax; s+=64){ float v=Sval[w][s]; t3 += expf(v); t4 += v; }
#pragma unroll
    for(int o=1;o<64;o<<=1){
      t0 += __shfl_xor(t0,o,64); t1 += __shfl_xor(t1,o,64); t2 += __shfl_xor(t2,o,64);
      t3 += __shfl_xor(t3,o,64); t4 += __shfl_xor(t4,o,64);
    }
    const float pot = t0, varm = t1*(1.0f/DD), s2 = t2, se = t3, ms = t4/degf;

    float e0=0.f, e1=0.f;
    const float inv_se = 1.0f/se;
    for(int s=lane; s<dmax; s+=64){
      float v = Sval[w][s];
      float pp = expf(v)*inv_se;
      e0 -= pp*logf(pp + 1e-8f);
      float dv = v-ms; e1 += dv*dv;
    }
#pragma unroll
    for(int o=1;o<64;o<<=1){ e0 += __shfl_xor(e0,o,64); e1 += __shfl_xor(e1,o,64); }

    if(lane==0){
      o_te[i]  = sqi - pot/(degf + 1e-8f);
      o_ent[i] = e0;
      o_if[i]  = e1/(degf-1.0f);
      o_st[i]  = 1.0f/(1.0f + varm);
      o_cv[i]  = 1.0f - (s2 - ssq)/(degf*(degf-1.0f));
      deg_out[i] = degf;
    }
  } else {
    // ========== knng branch: 256 j / block, 4 dbuf LDS chunks, 8 MFMA chains/chunk ==========
    const int kid = t >> 1;                        // 0..1023
    const int split = kid & (NSPLIT-1);            // 0..15
    const int strip = (kid >> 4)*4 + w;            // 0..255
    const int ibase = strip*16, j0 = split*JW;
    const int col = lane & 15, kg = lane >> 4;
    const int vo = col*DD + kg*8;
    const int myi = ibase + col;

    // stage chunk CH (64 j-rows) hi/lo into LDS buffer BUF; linear dest,
    // source pre-swizzled (granule g: row=g>>3, chunk=(g&7)^(row&7))
#define STAGE(BUF, CH) { \
    _Pragma("unroll") \
    for(int q_=0;q_<2;q_++){ \
      int g_ = q_*256 + tid; \
      int r_ = g_ >> 3; \
      int c_ = (g_ & 7) ^ (r_ & 7); \
      const _Float16* sH_ = xh + (size_t)(j0 + (CH)*64 + r_)*DD + c_*8; \
      const _Float16* sL_ = xl + (size_t)(j0 + (CH)*64 + r_)*DD + c_*8; \
      __builtin_amdgcn_global_load_lds( \
        (const __attribute__((address_space(1))) unsigned int*)sH_, \
        (__attribute__((address_space(3))) unsigned int*)(jHi[BUF] + g_*8), 16, 0, 0); \
      __builtin_amdgcn_global_load_lds( \
        (const __attribute__((address_space(1))) unsigned int*)sL_, \
        (__attribute__((address_space(3))) unsigned int*)(jLo[BUF] + g_*8), 16, 0, 0); \
    } }

    STAGE(0, 0);

    // I-fragments from global (overlap with async staging)
    const _Float16* pih = xh + (size_t)ibase*DD + vo;
    const _Float16* pil = xl + (size_t)ibase*DD + vo;
    const half8 Ih0 = *(const half8*)(pih);
    const half8 Ih1 = *(const half8*)(pih+32);
    const half8 Il0 = *(const half8*)(pil);
    const half8 Il1 = *(const half8*)(pil+32);

    unsigned bA[5], bB[5];
#pragma unroll
    for(int k=0;k<5;k++){ bA[k]=0xFFFFFFFFu; bB[k]=0xFFFFFFFFu; }

#pragma unroll
    for(int ch=0; ch<4; ch++){
      __syncthreads();                  // staging of chunk ch complete
      if(ch<3) STAGE((ch+1)&1, ch+1);   // prefetch next chunk into other buffer
      const _Float16* bh = jHi[ch&1];
      const _Float16* bl = jLo[ch&1];
      const int jb0 = j0 + ch*64 + kg*4;
      float4 sq0 = *(const float4*)(sq + jb0);
      float4 sq1 = *(const float4*)(sq + jb0 + 16);
      float4 sq2 = *(const float4*)(sq + jb0 + 32);
      float4 sq3 = *(const float4*)(sq + jb0 + 48);

      half8 JT[4];
#define TILE(TT, SQV, LIST) { \
      const int rl_ = (TT)*16 + col; \
      const int sw_ = rl_ & 7; \
      JT[0] = *(const half8*)(bh + (rl_*8 + ( kg      ^ sw_))*8); \
      JT[1] = *(const half8*)(bh + (rl_*8 + ((kg + 4) ^ sw_))*8); \
      JT[2] = *(const half8*)(bl + (rl_*8 + ( kg      ^ sw_))*8); \
      JT[3] = *(const half8*)(bl + (rl_*8 + ((kg + 4) ^ sw_))*8); \
      f32x4 d_ = gram6(JT, Ih0, Ih1, Il0, Il1); \
      float sv_[4] = {SQV.x, SQV.y, SQV.z, SQV.w}; \
      const int jt0_ = jb0 + (TT)*16; \
      _Pragma("unroll") \
      for(int r_=0;r_<4;r_++){ \
        unsigned kk_ = packkey32(fmaf(-2.0f, d_[r_], sv_[r_]), jt0_+r_); \
        kk_ = (jt0_+r_==myi) ? 0xFFFFFFFFu : kk_; \
        ins5u(kk_, LIST); \
      } }

      TILE(0, sq0, bA);
      TILE(1, sq1, bB);
      TILE(2, sq2, bA);
      TILE(3, sq3, bB);
#undef TILE
    }
#undef STAGE

    unsigned b[5];
    mergeLocal32(bA, bB, b);
    mergeStage32(b, 16);
    mergeStage32(b, 32);

    if(kg==0){
#pragma unroll
      for(int k=0;k<5;k++)
        cand[((size_t)myi*NSPLIT + split)*5 + k] = b[k];
    }
  }
}

// ======== phase B: merge 16x5 u32 candidates per row + epilogue + o_sc ========
__global__ __launch_bounds__(256) void k_nnsel(
    const float* __restrict__ x, const unsigned* __restrict__ cand,
    const float* __restrict__ msum, const float* __restrict__ max_sq,
    const float* __restrict__ deg, const float* __restrict__ sq,
    float* __restrict__ o_eq, float* __restrict__ o_sc)
{
  const int w = threadIdx.x>>6, l = threadIdx.x&63;
  const int i = blockIdx.x*4 + w;
  const unsigned* cr = cand + (size_t)i*(NSPLIT*5);   // 80 entries
  unsigned c0 = cr[l];
  unsigned c1 = (l < 16) ? cr[64+l] : 0xFFFFFFFFu;

  int sel[5];
#pragma unroll
  for(int k=0;k<5;k++){
    unsigned d = umn(c0,c1);
#pragma unroll
    for(int o=1;o<64;o<<=1) d = umn(d, sxu(d,o));
    sel[k] = (int)(d & 0xFFFu);
    if(c0==d) c0=0xFFFFFFFFu;
    else if(c1==d) c1=0xFFFFFFFFu;
  }

  float smv=0.f;
#pragma unroll
  for(int k=0;k<5;k++) smv += x[(size_t)sel[k]*DD + l];
  float xiv = x[(size_t)i*DD + l];
  float lv = xiv - smv*0.2f;
  float gv = xiv - msum[l]*(1.0f/NN);
  float pl = lv*lv, pg = gv*gv;
#pragma unroll
  for(int o=1;o<64;o<<=1){ pl += __shfl_xor(pl,o,64); pg += __shfl_xor(pg,o,64); }
  if(l==0){
    o_eq[i] = 0.6f*sqrtf(pg) + 0.4f*sqrtf(pl);
    o_sc[i] = 0.5f*deg[i]/(float)(NN-1) + 0.5f*sqrtf(sq[i])/sqrtf(max_sq[0]);
  }
}

extern "C" void kernel_launch(void* const* d_in, const int* in_sizes, int n_in,
                              void* d_out, int out_size, void* d_ws, size_t ws_size,
                              hipStream_t stream) {
  const float* x = (const float*)d_in[0];
  const float* A = (const float*)d_in[1];
  float* out = (float*)d_out;
  float* ws  = (float*)d_ws;
  // ws layout (float offsets)
  float*     sq        = ws;                        // 0..4096
  float*     msum      = ws + 4096;                 // 64
  float*     max_sq    = ws + 4160;                 // 1 (pad to 4224)
  float*     deg       = ws + 4224;                 // 4096
  float*     msum_part = ws + 8320;                 // 256*64
  float*     maxsq_part= ws + 24704;                // 256
  _Float16*  xh        = (_Float16*)(ws + 24960);   // 262144 halves
  _Float16*  xl        = (_Float16*)(ws + 156032);  // 262144 halves
  unsigned*  cand      = (unsigned*)(ws + 287104);  // 4096*16*5 u32

  k_prec<<<NN/16, 256, 0, stream>>>(x, sq, xh, xl, msum_part, maxsq_part);
  // sparse: t even -> i=(t/2)*4+w covers 0..4095 => 1024 blocks
  // knng:   t odd  -> kid=t/2 in 0..1023 (16 splits x 64 strip-groups)
  // total = 2048 + 1 reducer
  k_mega<<<NN/2 + 1, 256, 0, stream>>>(x, A, sq, xh, xl, cand,
                                       msum_part, maxsq_part, msum, max_sq, deg,
                                       out, out+NN, out+4*NN, out+5*NN, out+6*NN);
  k_nnsel<<<NN/4, 256, 0, stream>>>(x, cand, msum, max_sq, deg, sq,
                                    out+2*NN, out+3*NN);
}

// Round 15
// 56.785 us; speedup vs baseline: 7.1496x; 1.0033x over previous
//
#include <hip/hip_runtime.h>
#include <math.h>

#define NN 4096
#define DD 64
#define NSPLIT 16
#define JW 256

typedef _Float16 half8 __attribute__((ext_vector_type(8)));
typedef float f32x4 __attribute__((ext_vector_type(4)));

__device__ __forceinline__ unsigned sxu(unsigned v, int o){
  return (unsigned)__shfl_xor((int)v, o, 64);
}
__device__ __forceinline__ unsigned umn(unsigned a, unsigned b){ return a<b?a:b; }
__device__ __forceinline__ unsigned umx(unsigned a, unsigned b){ return a<b?b:a; }

// key = (quantized m << 12) | j ; m=sqj-2dot, q=(m+256)*2048 clamped to 20 bits
__device__ __forceinline__ unsigned packkey32(float m, int j){
  float q = fmaf(m, 2048.f, 524288.f);
  q = fminf(fmaxf(q, 0.f), 1048575.f);
  return (((unsigned)q) << 12) | (unsigned)j;
}

// branchless sorted-5 insert on u32 keys
__device__ __forceinline__ void ins5u(unsigned k, unsigned b[5]){
  bool c0=k<b[0], c1=k<b[1], c2=k<b[2], c3=k<b[3], c4=k<b[4];
  b[4] = c3 ? b[3] : (c4 ? k : b[4]);
  b[3] = c2 ? b[2] : (c3 ? k : b[3]);
  b[2] = c1 ? b[1] : (c2 ? k : b[2]);
  b[1] = c0 ? b[0] : (c1 ? k : b[1]);
  b[0] = c0 ? k : b[0];
}

// butterfly merge stage across lanes: sorted-5 + partner sorted-5 -> sorted-5
__device__ __forceinline__ void mergeStage32(unsigned b[5], int st){
  unsigned p0=sxu(b[0],st),p1=sxu(b[1],st),p2=sxu(b[2],st),p3=sxu(b[3],st),p4=sxu(b[4],st);
  unsigned o0=umn(b[0],p0);
  unsigned o1=umn(umn(b[1],p1), umx(b[0],p0));
  unsigned o2=umn(umn(b[2],p2), umn(umx(b[0],p1),umx(b[1],p0)));
  unsigned o3=umn(umn(b[3],p3), umn(umx(b[0],p2), umn(umx(b[1],p1),umx(b[2],p0))));
  unsigned o4=umn(umn(b[4],p4), umn(umn(umx(b[0],p3),umx(b[1],p2)),
                                    umn(umx(b[2],p1),umx(b[3],p0))));
  b[0]=o0;b[1]=o1;b[2]=o2;b[3]=o3;b[4]=o4;
}

// local merge of two sorted-5 lists -> sorted-5
__device__ __forceinline__ void mergeLocal32(const unsigned a[5], const unsigned c[5], unsigned b[5]){
  b[0]=umn(a[0],c[0]);
  b[1]=umn(umn(a[1],c[1]), umx(a[0],c[0]));
  b[2]=umn(umn(a[2],c[2]), umn(umx(a[0],c[1]),umx(a[1],c[0])));
  b[3]=umn(umn(a[3],c[3]), umn(umx(a[0],c[2]), umn(umx(a[1],c[1]),umx(a[2],c[0]))));
  b[4]=umn(umn(a[4],c[4]), umn(umn(umx(a[0],c[3]),umx(a[1],c[2])),
                               umn(umx(a[2],c[1]),umx(a[3],c[0]))));
}

// ---- fused pre: sq, split-f16 hi/lo, per-block partial colsum + max (NO atomics) ----
__global__ __launch_bounds__(256) void k_prec(const float* __restrict__ x,
                      float* __restrict__ sq,
                      _Float16* __restrict__ xh, _Float16* __restrict__ xl,
                      float* __restrict__ msum_part, float* __restrict__ maxsq_part){
  __shared__ float part[4][64];
  __shared__ float mxp[4];
  const int w = threadIdx.x>>6, lane = threadIdx.x&63;
  const int n0 = blockIdx.x*16 + w*4;
  float v0 = x[(size_t)(n0+0)*DD + lane];
  float v1 = x[(size_t)(n0+1)*DD + lane];
  float v2 = x[(size_t)(n0+2)*DD + lane];
  float v3 = x[(size_t)(n0+3)*DD + lane];
  float s0=v0*v0, s1=v1*v1, s2=v2*v2, s3=v3*v3;
#pragma unroll
  for(int o=1;o<64;o<<=1){
    s0 += __shfl_xor(s0,o,64); s1 += __shfl_xor(s1,o,64);
    s2 += __shfl_xor(s2,o,64); s3 += __shfl_xor(s3,o,64);
  }
  float vv[4] = {v0,v1,v2,v3};
  float ss[4] = {s0,s1,s2,s3};
#pragma unroll
  for(int q=0;q<4;q++){
    float v = vv[q];
    _Float16 h = (_Float16)v;
    _Float16 l = (_Float16)(v - (float)h);
    xh[(size_t)(n0+q)*DD+lane] = h;
    xl[(size_t)(n0+q)*DD+lane] = l;
    if(lane==0) sq[n0+q]=ss[q];
  }
  if(lane==0) mxp[w] = fmaxf(fmaxf(s0,s1), fmaxf(s2,s3));
  part[w][lane] = v0+v1+v2+v3; __syncthreads();
  if(w==0){
    msum_part[blockIdx.x*64 + lane] = part[0][lane]+part[1][lane]+part[2][lane]+part[3][lane];
    if(lane==0) maxsq_part[blockIdx.x] = fmaxf(fmaxf(mxp[0],mxp[1]), fmaxf(mxp[2],mxp[3]));
  }
}

// 6-MFMA split-f16 Gram for one 16x16 tile: returns row-dots for this lane
__device__ __forceinline__ f32x4 gram6(const half8 J[4],
    half8 Ih0, half8 Ih1, half8 Il0, half8 Il1){
  const f32x4 z = {0.f,0.f,0.f,0.f};
  f32x4 a1 = __builtin_amdgcn_mfma_f32_16x16x32_f16(J[0], Ih0, z, 0,0,0);
  f32x4 a2 = __builtin_amdgcn_mfma_f32_16x16x32_f16(J[2], Ih0, z, 0,0,0);
  a1 = __builtin_amdgcn_mfma_f32_16x16x32_f16(J[1], Ih1, a1, 0,0,0);
  a2 = __builtin_amdgcn_mfma_f32_16x16x32_f16(J[3], Ih1, a2, 0,0,0);
  a1 = __builtin_amdgcn_mfma_f32_16x16x32_f16(J[0], Il0, a1, 0,0,0);
  a1 = __builtin_amdgcn_mfma_f32_16x16x32_f16(J[1], Il1, a1, 0,0,0);
  return a1 + a2;
}

// ======== MEGA: bid0 = stats reduce; then 1/2 sparse, 1/2 MFMA kNN ========
__global__ __launch_bounds__(256, 4) void k_mega(
    const float* __restrict__ x, const float* __restrict__ A,
    const float* __restrict__ sq,
    const _Float16* __restrict__ xh, const _Float16* __restrict__ xl,
    unsigned* __restrict__ cand,
    const float* __restrict__ msum_part, const float* __restrict__ maxsq_part,
    float* __restrict__ msum, float* __restrict__ max_sq, float* __restrict__ deg_out,
    float* __restrict__ o_te, float* __restrict__ o_ent,
    float* __restrict__ o_if, float* __restrict__ o_st, float* __restrict__ o_cv)
{
  __shared__ int   nbr[4][128];
  __shared__ float Sval[4][128];
  __shared__ float rr[4][64];
  __shared__ float rm[4];
  __shared__ _Float16 jHi[512*8];   // single buffer: 64 j-rows x 8 granules, swizzled
  __shared__ _Float16 jLo[512*8];
  const int bid = blockIdx.x;
  const int tid = threadIdx.x;
  const int w = tid>>6, lane = tid&63;

  if(bid == 0){
    float s = 0.f;
    for(int p=w; p<256; p+=4) s += msum_part[p*64 + lane];
    rr[w][lane] = s;
    float m = maxsq_part[w*64 + lane];
#pragma unroll
    for(int o=1;o<64;o<<=1) m = fmaxf(m, __shfl_xor(m,o,64));
    if(lane==0) rm[w] = m;
    __syncthreads();
    if(w==0){
      msum[lane] = rr[0][lane]+rr[1][lane]+rr[2][lane]+rr[3][lane];
      if(lane==0) max_sq[0] = fmaxf(fmaxf(rm[0],rm[1]), fmaxf(rm[2],rm[3]));
    }
    return;
  }

  const int t = bid - 1;
  if((t & 1) == 0){
    // ================= sparse branch: wave per node, ballot compaction =================
    const int i = (t>>1)*4 + w;
    const float xid = x[(size_t)i*DD + lane];
    const float sqi = sq[i];
    const float eni = sqrtf(sqi);
    const float4* A4 = (const float4*)(A + (size_t)i*NN);
    const unsigned long long below = (1ull << lane) - 1ull;

    int base = 0;
#define COMPACT(VAL, JJ) { \
    bool p_ = (VAL) > 0.f; \
    unsigned long long m_ = __ballot(p_); \
    int ofs_ = base + (int)__popcll(m_ & below); \
    if(p_ && ofs_ < 128) nbr[w][ofs_] = (JJ); \
    base += (int)__popcll(m_); \
  }
    for(int ch=0; ch<4; ++ch){
      float4 av[4];
#pragma unroll
      for(int qq=0; qq<4; ++qq) av[qq] = A4[lane + 64*(ch*4+qq)];
#pragma unroll
      for(int qq=0; qq<4; ++qq){
        int jb = 4*(lane + 64*(ch*4+qq));
        COMPACT(av[qq].x, jb+0);
        COMPACT(av[qq].y, jb+1);
        COMPACT(av[qq].z, jb+2);
        COMPACT(av[qq].w, jb+3);
      }
    }
#undef COMPACT
    const int deg = base;

    const float degf = (float)deg;
    const int dmax = min(deg, 128);
    float nb_d=0.f, ex2_d=0.f, s_d=0.f, ssq=0.f;

    for(int c0=0; c0<dmax; c0+=8){
      int jq[8]; float aq[8], qq[8];
#pragma unroll
      for(int q=0;q<8;q++) jq[q] = nbr[w][min(c0+q, dmax-1)];
#pragma unroll
      for(int q=0;q<8;q++) aq[q] = x[(size_t)jq[q]*DD + lane];
#pragma unroll
      for(int q=0;q<8;q++) qq[q] = sq[jq[q]];
      asm volatile("" :: "v"(aq[0]), "v"(aq[1]), "v"(aq[2]), "v"(aq[3]),
                         "v"(aq[4]), "v"(aq[5]), "v"(aq[6]), "v"(aq[7]));
      float p[8];
#pragma unroll
      for(int q=0;q<8;q++) p[q] = xid*aq[q];
#pragma unroll
      for(int o=1;o<64;o<<=1){
#pragma unroll
        for(int q=0;q<8;q++) p[q] += __shfl_xor(p[q],o,64);
      }
#pragma unroll
      for(int q=0;q<8;q++){
        const bool valid = (c0+q) < deg;
        float c2 = fmaxf(sqi + qq[q] - 2.0f*p[q], 1e-12f);
        float inv = 1.0f/fmaxf(sqrtf(c2), 1e-8f);
        nb_d  += valid ? aq[q] : 0.f;
        ex2_d += valid ? aq[q]*aq[q] : 0.f;
        s_d   += valid ? (aq[q]-xid)*inv : 0.f;
        ssq   += valid ? c2*inv*inv : 0.f;
        if(valid && lane==q) Sval[w][c0+q] = p[q]/(eni*sqrtf(qq[q]));
      }
    }

    float t0 = xid*nb_d;
    float m1 = nb_d/degf;
    float t1 = (ex2_d - degf*m1*m1)/(degf-1.0f);
    float t2 = s_d*s_d;
    float t3 = 0.f, t4 = 0.f;
    for(int s=lane; s<dmax; s+=64){ float v=Sval[w][s]; t3 += expf(v); t4 += v; }
#pragma unroll
    for(int o=1;o<64;o<<=1){
      t0 += __shfl_xor(t0,o,64); t1 += __shfl_xor(t1,o,64); t2 += __shfl_xor(t2,o,64);
      t3 += __shfl_xor(t3,o,64); t4 += __shfl_xor(t4,o,64);
    }
    const float pot = t0, varm = t1*(1.0f/DD), s2 = t2, se = t3, ms = t4/degf;

    float e0=0.f, e1=0.f;
    const float inv_se = 1.0f/se;
    for(int s=lane; s<dmax; s+=64){
      float v = Sval[w][s];
      float pp = expf(v)*inv_se;
      e0 -= pp*logf(pp + 1e-8f);
      float dv = v-ms; e1 += dv*dv;
    }
#pragma unroll
    for(int o=1;o<64;o<<=1){ e0 += __shfl_xor(e0,o,64); e1 += __shfl_xor(e1,o,64); }

    if(lane==0){
      o_te[i]  = sqi - pot/(degf + 1e-8f);
      o_ent[i] = e0;
      o_if[i]  = e1/(degf-1.0f);
      o_st[i]  = 1.0f/(1.0f + varm);
      o_cv[i]  = 1.0f - (s2 - ssq)/(degf*(degf-1.0f));
      deg_out[i] = degf;
    }
  } else {
    // ========== knng branch: 256 j / block, 4 single-buffer LDS chunks ==========
    const int kid = t >> 1;                        // 0..1023
    const int split = kid & (NSPLIT-1);            // 0..15
    const int strip = (kid >> 4)*4 + w;            // 0..255
    const int ibase = strip*16, j0 = split*JW;
    const int col = lane & 15, kg = lane >> 4;
    const int vo = col*DD + kg*8;
    const int myi = ibase + col;

    // stage chunk CH (64 j-rows) hi/lo into LDS; linear dest,
    // source pre-swizzled (granule g: row=g>>3, chunk=(g&7)^(row&7))
#define STAGE(CH) { \
    _Pragma("unroll") \
    for(int q_=0;q_<2;q_++){ \
      int g_ = q_*256 + tid; \
      int r_ = g_ >> 3; \
      int c_ = (g_ & 7) ^ (r_ & 7); \
      const _Float16* sH_ = xh + (size_t)(j0 + (CH)*64 + r_)*DD + c_*8; \
      const _Float16* sL_ = xl + (size_t)(j0 + (CH)*64 + r_)*DD + c_*8; \
      __builtin_amdgcn_global_load_lds( \
        (const __attribute__((address_space(1))) unsigned int*)sH_, \
        (__attribute__((address_space(3))) unsigned int*)(jHi + g_*8), 16, 0, 0); \
      __builtin_amdgcn_global_load_lds( \
        (const __attribute__((address_space(1))) unsigned int*)sL_, \
        (__attribute__((address_space(3))) unsigned int*)(jLo + g_*8), 16, 0, 0); \
    } }

    // I-fragments from global
    const _Float16* pih = xh + (size_t)ibase*DD + vo;
    const _Float16* pil = xl + (size_t)ibase*DD + vo;
    const half8 Ih0 = *(const half8*)(pih);
    const half8 Ih1 = *(const half8*)(pih+32);
    const half8 Il0 = *(const half8*)(pil);
    const half8 Il1 = *(const half8*)(pil+32);

    unsigned bA[5], bB[5];
#pragma unroll
    for(int k=0;k<5;k++){ bA[k]=0xFFFFFFFFu; bB[k]=0xFFFFFFFFu; }

#pragma unroll
    for(int ch=0; ch<4; ch++){
      STAGE(ch);
      const int jb0 = j0 + ch*64 + kg*4;
      float4 sq0 = *(const float4*)(sq + jb0);
      float4 sq1 = *(const float4*)(sq + jb0 + 16);
      float4 sq2 = *(const float4*)(sq + jb0 + 32);
      float4 sq3 = *(const float4*)(sq + jb0 + 48);
      __syncthreads();                  // staging of chunk ch complete

      half8 JT[4];
#define TILE(TT, SQV, LIST) { \
      const int rl_ = (TT)*16 + col; \
      const int sw_ = rl_ & 7; \
      JT[0] = *(const half8*)(jHi + (rl_*8 + ( kg      ^ sw_))*8); \
      JT[1] = *(const half8*)(jHi + (rl_*8 + ((kg + 4) ^ sw_))*8); \
      JT[2] = *(const half8*)(jLo + (rl_*8 + ( kg      ^ sw_))*8); \
      JT[3] = *(const half8*)(jLo + (rl_*8 + ((kg + 4) ^ sw_))*8); \
      f32x4 d_ = gram6(JT, Ih0, Ih1, Il0, Il1); \
      float sv_[4] = {SQV.x, SQV.y, SQV.z, SQV.w}; \
      const int jt0_ = jb0 + (TT)*16; \
      _Pragma("unroll") \
      for(int r_=0;r_<4;r_++){ \
        unsigned kk_ = packkey32(fmaf(-2.0f, d_[r_], sv_[r_]), jt0_+r_); \
        kk_ = (jt0_+r_==myi) ? 0xFFFFFFFFu : kk_; \
        ins5u(kk_, LIST); \
      } }

      TILE(0, sq0, bA);
      TILE(1, sq1, bB);
      TILE(2, sq2, bA);
      TILE(3, sq3, bB);
#undef TILE
      __syncthreads();                  // all reads done before next STAGE
    }
#undef STAGE

    unsigned b[5];
    mergeLocal32(bA, bB, b);
    mergeStage32(b, 16);
    mergeStage32(b, 32);

    if(kg==0){
#pragma unroll
      for(int k=0;k<5;k++)
        cand[((size_t)myi*NSPLIT + split)*5 + k] = b[k];
    }
  }
}

// ======== phase B: merge 16x5 u32 candidates per row + epilogue + o_sc ========
__global__ __launch_bounds__(256) void k_nnsel(
    const float* __restrict__ x, const unsigned* __restrict__ cand,
    const float* __restrict__ msum, const float* __restrict__ max_sq,
    const float* __restrict__ deg, const float* __restrict__ sq,
    float* __restrict__ o_eq, float* __restrict__ o_sc)
{
  const int w = threadIdx.x>>6, l = threadIdx.x&63;
  const int i = blockIdx.x*4 + w;
  const unsigned* cr = cand + (size_t)i*(NSPLIT*5);   // 80 entries
  unsigned c0 = cr[l];
  unsigned c1 = (l < 16) ? cr[64+l] : 0xFFFFFFFFu;

  int sel[5];
#pragma unroll
  for(int k=0;k<5;k++){
    unsigned d = umn(c0,c1);
#pragma unroll
    for(int o=1;o<64;o<<=1) d = umn(d, sxu(d,o));
    sel[k] = (int)(d & 0xFFFu);
    if(c0==d) c0=0xFFFFFFFFu;
    else if(c1==d) c1=0xFFFFFFFFu;
  }

  float smv=0.f;
#pragma unroll
  for(int k=0;k<5;k++) smv += x[(size_t)sel[k]*DD + l];
  float xiv = x[(size_t)i*DD + l];
  float lv = xiv - smv*0.2f;
  float gv = xiv - msum[l]*(1.0f/NN);
  float pl = lv*lv, pg = gv*gv;
#pragma unroll
  for(int o=1;o<64;o<<=1){ pl += __shfl_xor(pl,o,64); pg += __shfl_xor(pg,o,64); }
  if(l==0){
    o_eq[i] = 0.6f*sqrtf(pg) + 0.4f*sqrtf(pl);
    o_sc[i] = 0.5f*deg[i]/(float)(NN-1) + 0.5f*sqrtf(sq[i])/sqrtf(max_sq[0]);
  }
}

extern "C" void kernel_launch(void* const* d_in, const int* in_sizes, int n_in,
                              void* d_out, int out_size, void* d_ws, size_t ws_size,
                              hipStream_t stream) {
  const float* x = (const float*)d_in[0];
  const float* A = (const float*)d_in[1];
  float* out = (float*)d_out;
  float* ws  = (float*)d_ws;
  // ws layout (float offsets)
  float*     sq        = ws;                        // 0..4096
  float*     msum      = ws + 4096;                 // 64
  float*     max_sq    = ws + 4160;                 // 1 (pad to 4224)
  float*     deg       = ws + 4224;                 // 4096
  float*     msum_part = ws + 8320;                 // 256*64
  float*     maxsq_part= ws + 24704;                // 256
  _Float16*  xh        = (_Float16*)(ws + 24960);   // 262144 halves
  _Float16*  xl        = (_Float16*)(ws + 156032);  // 262144 halves
  unsigned*  cand      = (unsigned*)(ws + 287104);  // 4096*16*5 u32

  k_prec<<<NN/16, 256, 0, stream>>>(x, sq, xh, xl, msum_part, maxsq_part);
  // sparse: t even -> i=(t/2)*4+w covers 0..4095 => 1024 blocks
  // knng:   t odd  -> kid=t/2 in 0..1023 (16 splits x 64 strip-groups)
  // total = 2048 + 1 reducer
  k_mega<<<NN/2 + 1, 256, 0, stream>>>(x, A, sq, xh, xl, cand,
                                       msum_part, maxsq_part, msum, max_sq, deg,
                                       out, out+NN, out+4*NN, out+5*NN, out+6*NN);
  k_nnsel<<<NN/4, 256, 0, stream>>>(x, cand, msum, max_sq, deg, sq,
                                    out+2*NN, out+3*NN);
}